// Round 1
// baseline (709.173 us; speedup 1.0000x reference)
//
#include <hip/hip_runtime.h>

// Problem constants
constexpr int BATCH = 8;
constexpr int NPT   = 8192;   // N points
constexpr int NSMP  = 2048;   // S sampled points
constexpr int D1C   = 128;    // skip feature channels
constexpr int D2C   = 256;    // sampled feature channels
constexpr int CIN   = 384;    // D1C + D2C
constexpr int C1    = 256;    // layer-1 out channels
constexpr int C2    = 128;    // layer-2 out channels
constexpr int BN_TOTAL = BATCH * NPT;  // 65536 rows

// GEMM tiling
constexpr int BM  = 64;
constexpr int BNT = 64;
constexpr int BK  = 32;

// ---------------------------------------------------------------------------
// Generic 32x32 tiled transpose: in [rows, cols] -> out [cols, rows], batched.
// All dims multiples of 32. block (32,8), grid (cols/32, rows/32, batch)
// ---------------------------------------------------------------------------
__global__ void transpose_k(const float* __restrict__ in, float* __restrict__ out,
                            int rows, int cols, long inBatch, long outBatch) {
  __shared__ float tile[32][33];
  const float* inb = in + (size_t)blockIdx.z * inBatch;
  float* outb = out + (size_t)blockIdx.z * outBatch;
  int c0 = blockIdx.x * 32;
  int r0 = blockIdx.y * 32;
  int tx = threadIdx.x, ty = threadIdx.y;
#pragma unroll
  for (int i = 0; i < 32; i += 8) {
    int r = r0 + ty + i;
    tile[ty + i][tx] = inb[(size_t)r * cols + c0 + tx];
  }
  __syncthreads();
#pragma unroll
  for (int i = 0; i < 32; i += 8) {
    int c = c0 + ty + i;
    outb[(size_t)c * rows + r0 + tx] = tile[tx][ty + i];
  }
}

// ---------------------------------------------------------------------------
// kNN: one thread per (b,n). Distances in fp64 (cancellation-free diff form)
// so top-3 ordering matches the fp64 numpy reference. Weights in fp64 too.
// block 256, grid BN_TOTAL/256. All threads of a block share batch b.
// ---------------------------------------------------------------------------
__global__ __launch_bounds__(256) void knn_kernel(
    const float* __restrict__ pos,    // [B,3,NPT]
    const float* __restrict__ spos,   // [B,3,NSMP]
    int* __restrict__ idx_out,        // [BN_TOTAL,3]
    float* __restrict__ wgt_out) {    // [BN_TOTAL,3]
  __shared__ float qs[3 * NSMP];  // 24 KB
  int gid = blockIdx.x * 256 + threadIdx.x;
  int b = gid >> 13;           // / NPT
  int n = gid & (NPT - 1);
  const float* qb = spos + (size_t)b * 3 * NSMP;
  for (int t = threadIdx.x; t < 3 * NSMP; t += 256) qs[t] = qb[t];
  __syncthreads();

  const float* pb = pos + (size_t)b * 3 * NPT;
  double px = (double)pb[n];
  double py = (double)pb[NPT + n];
  double pz = (double)pb[2 * NPT + n];

  double best0 = 1e300, best1 = 1e300, best2 = 1e300;
  int i0 = 0, i1 = 0, i2 = 0;
#pragma unroll 4
  for (int s = 0; s < NSMP; ++s) {
    double dx = px - (double)qs[s];
    double dy = py - (double)qs[NSMP + s];
    double dz = pz - (double)qs[2 * NSMP + s];
    double d = dx * dx + dy * dy + dz * dz;
    if (d < best2) {
      if (d < best1) {
        best2 = best1; i2 = i1;
        if (d < best0) { best1 = best0; i1 = i0; best0 = d; i0 = s; }
        else           { best1 = d; i1 = s; }
      } else { best2 = d; i2 = s; }
    }
  }
  double w0 = 1.0 / (best0 + 1e-8);
  double w1 = 1.0 / (best1 + 1e-8);
  double w2 = 1.0 / (best2 + 1e-8);
  double inv = 1.0 / (w0 + w1 + w2);
  size_t o = (size_t)gid * 3;
  idx_out[o + 0] = i0; idx_out[o + 1] = i1; idx_out[o + 2] = i2;
  wgt_out[o + 0] = (float)(w0 * inv);
  wgt_out[o + 1] = (float)(w1 * inv);
  wgt_out[o + 2] = (float)(w2 * inv);
}

// ---------------------------------------------------------------------------
// Interpolation gather: interp[p][c] = sum_k w_k * sfeatT[b, idx_k, c]
// block 256 (one channel per thread), grid BN_TOTAL. Coalesced via sfeatT.
// ---------------------------------------------------------------------------
__global__ __launch_bounds__(256) void interp_kernel(
    const float* __restrict__ sfeatT,  // [B, NSMP, D2C]
    const int* __restrict__ idx,       // [BN_TOTAL,3]
    const float* __restrict__ wgt,     // [BN_TOTAL,3]
    float* __restrict__ interp) {      // [BN_TOTAL, D2C]
  int p = blockIdx.x;
  int c = threadIdx.x;
  int b = p >> 13;
  size_t o = (size_t)p * 3;
  int i0 = idx[o], i1 = idx[o + 1], i2 = idx[o + 2];
  float w0 = wgt[o], w1 = wgt[o + 1], w2 = wgt[o + 2];
  const float* base = sfeatT + (size_t)b * NSMP * D2C;
  float v = w0 * base[(size_t)i0 * D2C + c]
          + w1 * base[(size_t)i1 * D2C + c]
          + w2 * base[(size_t)i2 * D2C + c];
  interp[(size_t)p * D2C + c] = v;
}

// ---------------------------------------------------------------------------
// GEMM1: Y1[r][o] = sum_k A[r][k] * W1[o][k] + b1[o]
// A[r][k] = (k<128) ? skip[b][k][n] : interp[r][k-128]
// 64x64 tile, BK=32, 256 threads (16x16, 4x4 micro-tile). fp32.
// grid (BN_TOTAL/BM, C1/BNT)
// ---------------------------------------------------------------------------
__global__ __launch_bounds__(256) void gemm1_kernel(
    const float* __restrict__ skip,    // [B, D1C, NPT]
    const float* __restrict__ interp,  // [BN_TOTAL, D2C]
    const float* __restrict__ W1T,     // [CIN, C1]
    const float* __restrict__ bias1,   // [C1]
    float* __restrict__ Y1) {          // [BN_TOTAL, C1]
  __shared__ float As[BK][BM + 4];
  __shared__ float Bs[BK][BNT];
  int tid = threadIdx.x;
  int tx = tid & 15, ty = tid >> 4;
  int row0 = blockIdx.x * BM;
  int col0 = blockIdx.y * BNT;
  int b  = row0 >> 13;
  int n0 = row0 & (NPT - 1);

  float acc[4][4];
#pragma unroll
  for (int j = 0; j < 4; j++) {
    float bj = bias1[col0 + tx * 4 + j];
#pragma unroll
    for (int i = 0; i < 4; i++) acc[i][j] = bj;
  }

  for (int k0 = 0; k0 < CIN; k0 += BK) {
    if (k0 < D1C) {
      // skip region: read along m (coalesced, since skip is [.,k,n])
      int m = tid & 63;
      int kk0 = tid >> 6;  // 0..3
#pragma unroll
      for (int u = 0; u < BK; u += 4) {
        int kk = kk0 + u;
        As[kk][m] = skip[((size_t)b * D1C + (k0 + kk)) * NPT + n0 + m];
      }
    } else {
      // interp region: row-major -> read along k (coalesced), LDS transpose
      int m = tid >> 2;   // 0..63
      int q = tid & 3;    // 0..3
#pragma unroll
      for (int it = 0; it < 2; it++) {
        int kk = q * 4 + it * 16;
        float4 v = *(const float4*)&interp[(size_t)(row0 + m) * D2C + (k0 - D1C) + kk];
        As[kk + 0][m] = v.x; As[kk + 1][m] = v.y;
        As[kk + 2][m] = v.z; As[kk + 3][m] = v.w;
      }
    }
    {
      int j4 = tid & 15;
      int kk0 = tid >> 4;  // 0..15
#pragma unroll
      for (int u = 0; u < 2; u++) {
        int kk = kk0 + u * 16;
        *(float4*)&Bs[kk][j4 * 4] = *(const float4*)&W1T[(size_t)(k0 + kk) * C1 + col0 + j4 * 4];
      }
    }
    __syncthreads();
#pragma unroll
    for (int kk = 0; kk < BK; kk++) {
      float a[4], bb[4];
#pragma unroll
      for (int i = 0; i < 4; i++) a[i] = As[kk][ty * 4 + i];
#pragma unroll
      for (int j = 0; j < 4; j++) bb[j] = Bs[kk][tx * 4 + j];
#pragma unroll
      for (int i = 0; i < 4; i++)
#pragma unroll
        for (int j = 0; j < 4; j++) acc[i][j] += a[i] * bb[j];
    }
    __syncthreads();
  }
#pragma unroll
  for (int i = 0; i < 4; i++) {
    float4 o4 = make_float4(acc[i][0], acc[i][1], acc[i][2], acc[i][3]);
    *(float4*)&Y1[(size_t)(row0 + ty * 4 + i) * C1 + col0 + tx * 4] = o4;
  }
}

// ---------------------------------------------------------------------------
// GEMM2: X2 = relu(Y1*scale1+shift1);  Y2 = X2 @ W2T + b2
// BN1+ReLU fused into A-staging. grid (BN_TOTAL/BM, C2/BNT)
// ---------------------------------------------------------------------------
__global__ __launch_bounds__(256) void gemm2_kernel(
    const float* __restrict__ Y1,      // [BN_TOTAL, C1]
    const float* __restrict__ scale1, const float* __restrict__ shift1,
    const float* __restrict__ W2T,     // [C1, C2]
    const float* __restrict__ bias2,   // [C2]
    float* __restrict__ Y2) {          // [BN_TOTAL, C2]
  __shared__ float As[BK][BM + 4];
  __shared__ float Bs[BK][BNT];
  int tid = threadIdx.x;
  int tx = tid & 15, ty = tid >> 4;
  int row0 = blockIdx.x * BM;
  int col0 = blockIdx.y * BNT;

  float acc[4][4];
#pragma unroll
  for (int j = 0; j < 4; j++) {
    float bj = bias2[col0 + tx * 4 + j];
#pragma unroll
    for (int i = 0; i < 4; i++) acc[i][j] = bj;
  }

  for (int k0 = 0; k0 < C1; k0 += BK) {
    int m = tid >> 2, q = tid & 3;
#pragma unroll
    for (int it = 0; it < 2; it++) {
      int kk = q * 4 + it * 16;
      int k = k0 + kk;
      float4 v  = *(const float4*)&Y1[(size_t)(row0 + m) * C1 + k];
      float4 sc = *(const float4*)&scale1[k];
      float4 sh = *(const float4*)&shift1[k];
      As[kk + 0][m] = fmaxf(fmaf(v.x, sc.x, sh.x), 0.f);
      As[kk + 1][m] = fmaxf(fmaf(v.y, sc.y, sh.y), 0.f);
      As[kk + 2][m] = fmaxf(fmaf(v.z, sc.z, sh.z), 0.f);
      As[kk + 3][m] = fmaxf(fmaf(v.w, sc.w, sh.w), 0.f);
    }
    int j4 = tid & 15, kk0 = tid >> 4;
#pragma unroll
    for (int u = 0; u < 2; u++) {
      int kk = kk0 + u * 16;
      *(float4*)&Bs[kk][j4 * 4] = *(const float4*)&W2T[(size_t)(k0 + kk) * C2 + col0 + j4 * 4];
    }
    __syncthreads();
#pragma unroll
    for (int kk = 0; kk < BK; kk++) {
      float a[4], bb[4];
#pragma unroll
      for (int i = 0; i < 4; i++) a[i] = As[kk][ty * 4 + i];
#pragma unroll
      for (int j = 0; j < 4; j++) bb[j] = Bs[kk][tx * 4 + j];
#pragma unroll
      for (int i = 0; i < 4; i++)
#pragma unroll
        for (int j = 0; j < 4; j++) acc[i][j] += a[i] * bb[j];
    }
    __syncthreads();
  }
#pragma unroll
  for (int i = 0; i < 4; i++) {
    float4 o4 = make_float4(acc[i][0], acc[i][1], acc[i][2], acc[i][3]);
    *(float4*)&Y2[(size_t)(row0 + ty * 4 + i) * C2 + col0 + tx * 4] = o4;
  }
}

// ---------------------------------------------------------------------------
// Per-channel sum / sumsq over rows. block = C threads, grid = rows/rowsPer.
// ---------------------------------------------------------------------------
__global__ void stats_kernel(const float* __restrict__ Y,
                             float* __restrict__ sum, float* __restrict__ sumsq,
                             int C, int rowsPer) {
  int c = threadIdx.x;
  size_t r0 = (size_t)blockIdx.x * rowsPer;
  float s = 0.f, s2 = 0.f;
  for (int r = 0; r < rowsPer; r++) {
    float v = Y[(r0 + r) * C + c];
    s += v;
    s2 += v * v;
  }
  atomicAdd(&sum[c], s);
  atomicAdd(&sumsq[c], s2);
}

__global__ void bn_coef_kernel(const float* __restrict__ sum, const float* __restrict__ sumsq,
                               const float* __restrict__ g, const float* __restrict__ beta,
                               float* __restrict__ scale, float* __restrict__ shift, int C) {
  int c = threadIdx.x + blockIdx.x * blockDim.x;
  if (c >= C) return;
  const float invBN = 1.0f / (float)BN_TOTAL;
  float m = sum[c] * invBN;
  float var = sumsq[c] * invBN - m * m;
  float sc = g[c] / sqrtf(var + 1e-5f);
  scale[c] = sc;
  shift[c] = beta[c] - m * sc;
}

// ---------------------------------------------------------------------------
// Final: out[b][c][n] = relu(Y2[b*NPT+n][c]*scale2[c]+shift2[c])  (transpose)
// block (32,8), grid (NPT/32, C2/32, BATCH)
// ---------------------------------------------------------------------------
__global__ void final_kernel(const float* __restrict__ Y2,
                             const float* __restrict__ scale, const float* __restrict__ shift,
                             float* __restrict__ out) {
  __shared__ float tile[32][33];
  int b = blockIdx.z;
  int n0 = blockIdx.x * 32;
  int c0 = blockIdx.y * 32;
  int tx = threadIdx.x, ty = threadIdx.y;
  float sc = scale[c0 + tx];
  float sh = shift[c0 + tx];
#pragma unroll
  for (int i = 0; i < 32; i += 8) {
    int n = n0 + ty + i;
    float v = Y2[((size_t)b * NPT + n) * C2 + c0 + tx];
    tile[ty + i][tx] = fmaxf(fmaf(v, sc, sh), 0.f);
  }
  __syncthreads();
#pragma unroll
  for (int i = 0; i < 32; i += 8) {
    int c = c0 + ty + i;
    out[((size_t)b * C2 + c) * NPT + n0 + tx] = tile[tx][ty + i];
  }
}

// ---------------------------------------------------------------------------
extern "C" void kernel_launch(void* const* d_in, const int* in_sizes, int n_in,
                              void* d_out, int out_size, void* d_ws, size_t ws_size,
                              hipStream_t stream) {
  (void)in_sizes; (void)n_in; (void)out_size; (void)ws_size;
  const float* pos   = (const float*)d_in[0];
  const float* spos  = (const float*)d_in[1];
  const float* skip  = (const float*)d_in[2];
  const float* sfeat = (const float*)d_in[3];
  const float* W1    = (const float*)d_in[4];
  const float* b1    = (const float*)d_in[5];
  const float* g1    = (const float*)d_in[6];
  const float* beta1 = (const float*)d_in[7];
  const float* W2    = (const float*)d_in[8];
  const float* b2    = (const float*)d_in[9];
  const float* g2    = (const float*)d_in[10];
  const float* beta2 = (const float*)d_in[11];
  float* out = (float*)d_out;

  // Workspace layout (floats). Total ~38.3M floats ~ 147 MB.
  float* ws = (float*)d_ws;
  size_t off = 0;
  float* sfeatT  = ws + off; off += (size_t)BATCH * NSMP * D2C;   // 4,194,304
  float* W1T     = ws + off; off += (size_t)CIN * C1;             //    98,304
  float* W2T     = ws + off; off += (size_t)C1 * C2;              //    32,768
  int*   knn_idx = (int*)(ws + off); off += (size_t)BN_TOTAL * 3; //   196,608
  float* knn_w   = ws + off; off += (size_t)BN_TOTAL * 3;         //   196,608
  float* interp  = ws + off; off += (size_t)BN_TOTAL * D2C;       // 16,777,216
  float* Y1      = ws + off; off += (size_t)BN_TOTAL * C1;        // 16,777,216
  float* Y2      = interp;  // alias: interp dead after GEMM1
  float* stats   = ws + off; // 1536 floats
  float* sum1 = stats, *sumsq1 = stats + 256;
  float* sum2 = stats + 512, *sumsq2 = stats + 640;
  float* scale1 = stats + 768,  *shift1 = stats + 1024;
  float* scale2 = stats + 1280, *shift2 = stats + 1408;

  hipMemsetAsync(stats, 0, 768 * sizeof(float), stream);

  dim3 tb(32, 8);
  // sfeat [B, D2C, NSMP] -> sfeatT [B, NSMP, D2C]
  transpose_k<<<dim3(NSMP / 32, D2C / 32, BATCH), tb, 0, stream>>>(
      sfeat, sfeatT, D2C, NSMP, (long)D2C * NSMP, (long)NSMP * D2C);
  // W1 [C1, CIN] -> W1T [CIN, C1]
  transpose_k<<<dim3(CIN / 32, C1 / 32, 1), tb, 0, stream>>>(W1, W1T, C1, CIN, 0, 0);
  // W2 [C2, C1] -> W2T [C1, C2]
  transpose_k<<<dim3(C1 / 32, C2 / 32, 1), tb, 0, stream>>>(W2, W2T, C2, C1, 0, 0);

  knn_kernel<<<BN_TOTAL / 256, 256, 0, stream>>>(pos, spos, knn_idx, knn_w);
  interp_kernel<<<BN_TOTAL, 256, 0, stream>>>(sfeatT, knn_idx, knn_w, interp);

  gemm1_kernel<<<dim3(BN_TOTAL / BM, C1 / BNT), 256, 0, stream>>>(skip, interp, W1T, b1, Y1);
  stats_kernel<<<256, C1, 0, stream>>>(Y1, sum1, sumsq1, C1, BN_TOTAL / 256);
  bn_coef_kernel<<<1, C1, 0, stream>>>(sum1, sumsq1, g1, beta1, scale1, shift1, C1);

  gemm2_kernel<<<dim3(BN_TOTAL / BM, C2 / BNT), 256, 0, stream>>>(Y1, scale1, shift1, W2T, b2, Y2);
  stats_kernel<<<256, C2, 0, stream>>>(Y2, sum2, sumsq2, C2, BN_TOTAL / 256);
  bn_coef_kernel<<<1, C2, 0, stream>>>(sum2, sumsq2, g2, beta2, scale2, shift2, C2);

  final_kernel<<<dim3(NPT / 32, C2 / 32, BATCH), tb, 0, stream>>>(Y2, scale2, shift2, out);
}

// Round 2
// 595.682 us; speedup vs baseline: 1.1905x; 1.1905x over previous
//
#include <hip/hip_runtime.h>

// Problem constants
constexpr int BATCH = 8;
constexpr int NPT   = 8192;   // N points
constexpr int NSMP  = 2048;   // S sampled points
constexpr int D1C   = 128;    // skip feature channels
constexpr int D2C   = 256;    // sampled feature channels
constexpr int CIN   = 384;    // D1C + D2C
constexpr int C1    = 256;    // layer-1 out channels
constexpr int C2    = 128;    // layer-2 out channels
constexpr int BN_TOTAL = BATCH * NPT;  // 65536 rows

// GEMM tiling
constexpr int BM  = 64;
constexpr int BNT = 64;
constexpr int BK  = 32;

// ---------------------------------------------------------------------------
// Generic 32x32 tiled transpose: in [rows, cols] -> out [cols, rows], batched.
// ---------------------------------------------------------------------------
__global__ void transpose_k(const float* __restrict__ in, float* __restrict__ out,
                            int rows, int cols, long inBatch, long outBatch) {
  __shared__ float tile[32][33];
  const float* inb = in + (size_t)blockIdx.z * inBatch;
  float* outb = out + (size_t)blockIdx.z * outBatch;
  int c0 = blockIdx.x * 32;
  int r0 = blockIdx.y * 32;
  int tx = threadIdx.x, ty = threadIdx.y;
#pragma unroll
  for (int i = 0; i < 32; i += 8) {
    int r = r0 + ty + i;
    tile[ty + i][tx] = inb[(size_t)r * cols + c0 + tx];
  }
  __syncthreads();
#pragma unroll
  for (int i = 0; i < 32; i += 8) {
    int c = c0 + ty + i;
    outb[(size_t)c * rows + r0 + tx] = tile[tx][ty + i];
  }
}

// ---------------------------------------------------------------------------
// Pack spos [B,3,NSMP] -> xyz-interleaved sposI [B,NSMP,3]
// ---------------------------------------------------------------------------
__global__ void pack_spos(const float* __restrict__ spos, float* __restrict__ sposI) {
  int g = blockIdx.x * 256 + threadIdx.x;  // B*NSMP = 16384
  int b = g >> 11, s = g & (NSMP - 1);
  const float* sp = spos + (size_t)b * 3 * NSMP;
  sposI[(size_t)g * 3 + 0] = sp[s];
  sposI[(size_t)g * 3 + 1] = sp[NSMP + s];
  sposI[(size_t)g * 3 + 2] = sp[2 * NSMP + s];
}

// ---------------------------------------------------------------------------
// Branchless insert of (d,s) into sorted top-4 (values) / top-3 (indices).
// Ties: incoming bubbles down => earlier (lower) sample index wins, matching
// jax.lax.top_k tie-breaking.
// ---------------------------------------------------------------------------
__device__ __forceinline__ void ins4(float d, int s,
                                     float& b0, float& b1, float& b2, float& b3,
                                     int& i0, int& i1, int& i2) {
  bool c0 = d < b0;
  float v1 = fmaxf(d, b0); b0 = fminf(d, b0);
  int   x1 = c0 ? i0 : s;  i0 = c0 ? s : i0;
  bool c1 = v1 < b1;
  float v2 = fmaxf(v1, b1); b1 = fminf(v1, b1);
  int   x2 = c1 ? i1 : x1; i1 = c1 ? x1 : i1;
  bool c2 = v2 < b2;
  float v3 = fmaxf(v2, b2); b2 = fminf(v2, b2);
  i2 = c2 ? x2 : i2;
  b3 = fminf(v3, b3);
}

// ---------------------------------------------------------------------------
// kNN: block = 256 threads = 4 waves, handles 64 points. Each wave scans a
// 512-sample segment in fp32 (branchless top-4); waves merged via LDS.
// Points whose 3rd/4th gap is within fp32 noise get flagged for exact fp64
// fallback. grid = BN_TOTAL/64 = 1024 blocks.
// ---------------------------------------------------------------------------
constexpr int SEG = NSMP / 4;  // 512

__global__ __launch_bounds__(256) void knn_kernel(
    const float* __restrict__ pos,    // [B,3,NPT]
    const float* __restrict__ sposI,  // [B,NSMP,3] interleaved
    int* __restrict__ idx_out,        // [BN_TOTAL,3]
    float* __restrict__ wgt_out,      // [BN_TOTAL,3]
    int* __restrict__ flag_list,      // capacity BN_TOTAL
    int* __restrict__ flag_count) {
  __shared__ float qs[3 * NSMP];   // 24 KB, xyz interleaved
  __shared__ float md[4][4][64];   // per-wave sorted top-4 values
  __shared__ int   mi[4][3][64];   // per-wave top-3 indices

  int tid = threadIdx.x;
  int wave = tid >> 6, lane = tid & 63;
  int blk = blockIdx.x;
  int b = blk >> 7;                        // 128 blocks per batch
  int n = ((blk & 127) << 6) + lane;       // point index within batch

  const float4* src = (const float4*)(sposI + (size_t)b * 3 * NSMP);
  float4* dst = (float4*)qs;
  for (int t = tid; t < 3 * NSMP / 4; t += 256) dst[t] = src[t];
  __syncthreads();

  const float* pb = pos + (size_t)b * 3 * NPT;
  float px = pb[n], py = pb[NPT + n], pz = pb[2 * NPT + n];

  const float INF = __builtin_inff();
  float b0 = INF, b1 = INF, b2 = INF, b3 = INF;
  int i0 = 0, i1 = 0, i2 = 0;

  const float4* q4 = (const float4*)qs;
  int s0 = wave * SEG;
  for (int t = 0; t < SEG; t += 4) {
    int s = s0 + t;
    int u = 3 * (s >> 2);
    float4 qa = q4[u], qb = q4[u + 1], qc = q4[u + 2];
    {
      float dx = px - qa.x, dy = py - qa.y, dz = pz - qa.z;
      float d = fmaf(dx, dx, fmaf(dy, dy, dz * dz));
      ins4(d, s + 0, b0, b1, b2, b3, i0, i1, i2);
    }
    {
      float dx = px - qa.w, dy = py - qb.x, dz = pz - qb.y;
      float d = fmaf(dx, dx, fmaf(dy, dy, dz * dz));
      ins4(d, s + 1, b0, b1, b2, b3, i0, i1, i2);
    }
    {
      float dx = px - qb.z, dy = py - qb.w, dz = pz - qc.x;
      float d = fmaf(dx, dx, fmaf(dy, dy, dz * dz));
      ins4(d, s + 2, b0, b1, b2, b3, i0, i1, i2);
    }
    {
      float dx = px - qc.y, dy = py - qc.z, dz = pz - qc.w;
      float d = fmaf(dx, dx, fmaf(dy, dy, dz * dz));
      ins4(d, s + 3, b0, b1, b2, b3, i0, i1, i2);
    }
  }

  md[wave][0][lane] = b0; md[wave][1][lane] = b1;
  md[wave][2][lane] = b2; md[wave][3][lane] = b3;
  mi[wave][0][lane] = i0; mi[wave][1][lane] = i1; mi[wave][2][lane] = i2;
  __syncthreads();

  if (tid < 64) {
    float B0 = INF, B1 = INF, B2 = INF, B3 = INF;
    int I0 = 0, I1 = 0, I2 = 0;
#pragma unroll
    for (int w = 0; w < 4; w++) {
#pragma unroll
      for (int sl = 0; sl < 3; sl++)
        ins4(md[w][sl][tid], mi[w][sl][tid], B0, B1, B2, B3, I0, I1, I2);
      // wave's 4th value can only contend for the global 4th slot
      ins4(md[w][3][tid], 0x7FFFFFFF, B0, B1, B2, B3, I0, I1, I2);
    }
    int p = blk * 64 + tid;  // global point id
    // certification: excluded samples have true d >= B3*(1-eps); kept top-3
    // have true d <= B2*(1+eps). eps ~4e-7 rel; margin 4e-6 = 10x safety.
    bool flag = (B3 - B2) < 4e-6f * (B3 + B2) + 1e-12f;
    if (flag) {
      int slot = atomicAdd(flag_count, 1);
      flag_list[slot] = p;
    }
    double w0 = 1.0 / ((double)B0 + 1e-8);
    double w1 = 1.0 / ((double)B1 + 1e-8);
    double w2 = 1.0 / ((double)B2 + 1e-8);
    double inv = 1.0 / (w0 + w1 + w2);
    size_t o = (size_t)p * 3;
    idx_out[o + 0] = I0; idx_out[o + 1] = I1; idx_out[o + 2] = I2;
    wgt_out[o + 0] = (float)(w0 * inv);
    wgt_out[o + 1] = (float)(w1 * inv);
    wgt_out[o + 2] = (float)(w2 * inv);
  }
}

// ---------------------------------------------------------------------------
// Exact fp64 fallback for flagged points (expected: a handful).
// grid 1024 x 64 covers full capacity; unflagged slots exit immediately.
// ---------------------------------------------------------------------------
__global__ __launch_bounds__(64) void knn_fallback(
    const float* __restrict__ pos, const float* __restrict__ sposI,
    const int* __restrict__ flag_list, const int* __restrict__ flag_count,
    int* __restrict__ idx_out, float* __restrict__ wgt_out) {
  int t = blockIdx.x * 64 + threadIdx.x;
  if (t >= *flag_count) return;
  int p = flag_list[t];
  int b = p >> 13, n = p & (NPT - 1);
  const float* pb = pos + (size_t)b * 3 * NPT;
  double px = (double)pb[n], py = (double)pb[NPT + n], pz = (double)pb[2 * NPT + n];
  const float* q = sposI + (size_t)b * 3 * NSMP;
  double best0 = 1e300, best1 = 1e300, best2 = 1e300;
  int i0 = 0, i1 = 0, i2 = 0;
  for (int s = 0; s < NSMP; s++) {
    double dx = px - (double)q[3 * s];
    double dy = py - (double)q[3 * s + 1];
    double dz = pz - (double)q[3 * s + 2];
    double d = dx * dx + dy * dy + dz * dz;
    if (d < best2) {
      if (d < best1) {
        best2 = best1; i2 = i1;
        if (d < best0) { best1 = best0; i1 = i0; best0 = d; i0 = s; }
        else           { best1 = d; i1 = s; }
      } else { best2 = d; i2 = s; }
    }
  }
  double w0 = 1.0 / (best0 + 1e-8);
  double w1 = 1.0 / (best1 + 1e-8);
  double w2 = 1.0 / (best2 + 1e-8);
  double inv = 1.0 / (w0 + w1 + w2);
  size_t o = (size_t)p * 3;
  idx_out[o + 0] = i0; idx_out[o + 1] = i1; idx_out[o + 2] = i2;
  wgt_out[o + 0] = (float)(w0 * inv);
  wgt_out[o + 1] = (float)(w1 * inv);
  wgt_out[o + 2] = (float)(w2 * inv);
}

// ---------------------------------------------------------------------------
// Interpolation gather: interp[p][c] = sum_k w_k * sfeatT[b, idx_k, c]
// ---------------------------------------------------------------------------
__global__ __launch_bounds__(256) void interp_kernel(
    const float* __restrict__ sfeatT,  // [B, NSMP, D2C]
    const int* __restrict__ idx,       // [BN_TOTAL,3]
    const float* __restrict__ wgt,     // [BN_TOTAL,3]
    float* __restrict__ interp) {      // [BN_TOTAL, D2C]
  int p = blockIdx.x;
  int c = threadIdx.x;
  int b = p >> 13;
  size_t o = (size_t)p * 3;
  int i0 = idx[o], i1 = idx[o + 1], i2 = idx[o + 2];
  float w0 = wgt[o], w1 = wgt[o + 1], w2 = wgt[o + 2];
  const float* base = sfeatT + (size_t)b * NSMP * D2C;
  float v = w0 * base[(size_t)i0 * D2C + c]
          + w1 * base[(size_t)i1 * D2C + c]
          + w2 * base[(size_t)i2 * D2C + c];
  interp[(size_t)p * D2C + c] = v;
}

// ---------------------------------------------------------------------------
// GEMM1: Y1[r][o] = sum_k A[r][k] * W1[o][k] + b1[o]
// A[r][k] = (k<128) ? skip[b][k][n] : interp[r][k-128]
// ---------------------------------------------------------------------------
__global__ __launch_bounds__(256) void gemm1_kernel(
    const float* __restrict__ skip,    // [B, D1C, NPT]
    const float* __restrict__ interp,  // [BN_TOTAL, D2C]
    const float* __restrict__ W1T,     // [CIN, C1]
    const float* __restrict__ bias1,   // [C1]
    float* __restrict__ Y1) {          // [BN_TOTAL, C1]
  __shared__ float As[BK][BM + 4];
  __shared__ float Bs[BK][BNT];
  int tid = threadIdx.x;
  int tx = tid & 15, ty = tid >> 4;
  int row0 = blockIdx.x * BM;
  int col0 = blockIdx.y * BNT;
  int b  = row0 >> 13;
  int n0 = row0 & (NPT - 1);

  float acc[4][4];
#pragma unroll
  for (int j = 0; j < 4; j++) {
    float bj = bias1[col0 + tx * 4 + j];
#pragma unroll
    for (int i = 0; i < 4; i++) acc[i][j] = bj;
  }

  for (int k0 = 0; k0 < CIN; k0 += BK) {
    if (k0 < D1C) {
      int m = tid & 63;
      int kk0 = tid >> 6;
#pragma unroll
      for (int u = 0; u < BK; u += 4) {
        int kk = kk0 + u;
        As[kk][m] = skip[((size_t)b * D1C + (k0 + kk)) * NPT + n0 + m];
      }
    } else {
      int m = tid >> 2;
      int q = tid & 3;
#pragma unroll
      for (int it = 0; it < 2; it++) {
        int kk = q * 4 + it * 16;
        float4 v = *(const float4*)&interp[(size_t)(row0 + m) * D2C + (k0 - D1C) + kk];
        As[kk + 0][m] = v.x; As[kk + 1][m] = v.y;
        As[kk + 2][m] = v.z; As[kk + 3][m] = v.w;
      }
    }
    {
      int j4 = tid & 15;
      int kk0 = tid >> 4;
#pragma unroll
      for (int u = 0; u < 2; u++) {
        int kk = kk0 + u * 16;
        *(float4*)&Bs[kk][j4 * 4] = *(const float4*)&W1T[(size_t)(k0 + kk) * C1 + col0 + j4 * 4];
      }
    }
    __syncthreads();
#pragma unroll
    for (int kk = 0; kk < BK; kk++) {
      float a[4], bb[4];
#pragma unroll
      for (int i = 0; i < 4; i++) a[i] = As[kk][ty * 4 + i];
#pragma unroll
      for (int j = 0; j < 4; j++) bb[j] = Bs[kk][tx * 4 + j];
#pragma unroll
      for (int i = 0; i < 4; i++)
#pragma unroll
        for (int j = 0; j < 4; j++) acc[i][j] += a[i] * bb[j];
    }
    __syncthreads();
  }
#pragma unroll
  for (int i = 0; i < 4; i++) {
    float4 o4 = make_float4(acc[i][0], acc[i][1], acc[i][2], acc[i][3]);
    *(float4*)&Y1[(size_t)(row0 + ty * 4 + i) * C1 + col0 + tx * 4] = o4;
  }
}

// ---------------------------------------------------------------------------
// GEMM2: X2 = relu(Y1*scale1+shift1);  Y2 = X2 @ W2T + b2
// ---------------------------------------------------------------------------
__global__ __launch_bounds__(256) void gemm2_kernel(
    const float* __restrict__ Y1,
    const float* __restrict__ scale1, const float* __restrict__ shift1,
    const float* __restrict__ W2T,
    const float* __restrict__ bias2,
    float* __restrict__ Y2) {
  __shared__ float As[BK][BM + 4];
  __shared__ float Bs[BK][BNT];
  int tid = threadIdx.x;
  int tx = tid & 15, ty = tid >> 4;
  int row0 = blockIdx.x * BM;
  int col0 = blockIdx.y * BNT;

  float acc[4][4];
#pragma unroll
  for (int j = 0; j < 4; j++) {
    float bj = bias2[col0 + tx * 4 + j];
#pragma unroll
    for (int i = 0; i < 4; i++) acc[i][j] = bj;
  }

  for (int k0 = 0; k0 < C1; k0 += BK) {
    int m = tid >> 2, q = tid & 3;
#pragma unroll
    for (int it = 0; it < 2; it++) {
      int kk = q * 4 + it * 16;
      int k = k0 + kk;
      float4 v  = *(const float4*)&Y1[(size_t)(row0 + m) * C1 + k];
      float4 sc = *(const float4*)&scale1[k];
      float4 sh = *(const float4*)&shift1[k];
      As[kk + 0][m] = fmaxf(fmaf(v.x, sc.x, sh.x), 0.f);
      As[kk + 1][m] = fmaxf(fmaf(v.y, sc.y, sh.y), 0.f);
      As[kk + 2][m] = fmaxf(fmaf(v.z, sc.z, sh.z), 0.f);
      As[kk + 3][m] = fmaxf(fmaf(v.w, sc.w, sh.w), 0.f);
    }
    int j4 = tid & 15, kk0 = tid >> 4;
#pragma unroll
    for (int u = 0; u < 2; u++) {
      int kk = kk0 + u * 16;
      *(float4*)&Bs[kk][j4 * 4] = *(const float4*)&W2T[(size_t)(k0 + kk) * C2 + col0 + j4 * 4];
    }
    __syncthreads();
#pragma unroll
    for (int kk = 0; kk < BK; kk++) {
      float a[4], bb[4];
#pragma unroll
      for (int i = 0; i < 4; i++) a[i] = As[kk][ty * 4 + i];
#pragma unroll
      for (int j = 0; j < 4; j++) bb[j] = Bs[kk][tx * 4 + j];
#pragma unroll
      for (int i = 0; i < 4; i++)
#pragma unroll
        for (int j = 0; j < 4; j++) acc[i][j] += a[i] * bb[j];
    }
    __syncthreads();
  }
#pragma unroll
  for (int i = 0; i < 4; i++) {
    float4 o4 = make_float4(acc[i][0], acc[i][1], acc[i][2], acc[i][3]);
    *(float4*)&Y2[(size_t)(row0 + ty * 4 + i) * C2 + col0 + tx * 4] = o4;
  }
}

// ---------------------------------------------------------------------------
__global__ void stats_kernel(const float* __restrict__ Y,
                             float* __restrict__ sum, float* __restrict__ sumsq,
                             int C, int rowsPer) {
  int c = threadIdx.x;
  size_t r0 = (size_t)blockIdx.x * rowsPer;
  float s = 0.f, s2 = 0.f;
  for (int r = 0; r < rowsPer; r++) {
    float v = Y[(r0 + r) * C + c];
    s += v;
    s2 += v * v;
  }
  atomicAdd(&sum[c], s);
  atomicAdd(&sumsq[c], s2);
}

__global__ void bn_coef_kernel(const float* __restrict__ sum, const float* __restrict__ sumsq,
                               const float* __restrict__ g, const float* __restrict__ beta,
                               float* __restrict__ scale, float* __restrict__ shift, int C) {
  int c = threadIdx.x + blockIdx.x * blockDim.x;
  if (c >= C) return;
  const float invBN = 1.0f / (float)BN_TOTAL;
  float m = sum[c] * invBN;
  float var = sumsq[c] * invBN - m * m;
  float sc = g[c] / sqrtf(var + 1e-5f);
  scale[c] = sc;
  shift[c] = beta[c] - m * sc;
}

// ---------------------------------------------------------------------------
__global__ void final_kernel(const float* __restrict__ Y2,
                             const float* __restrict__ scale, const float* __restrict__ shift,
                             float* __restrict__ out) {
  __shared__ float tile[32][33];
  int b = blockIdx.z;
  int n0 = blockIdx.x * 32;
  int c0 = blockIdx.y * 32;
  int tx = threadIdx.x, ty = threadIdx.y;
  float sc = scale[c0 + tx];
  float sh = shift[c0 + tx];
#pragma unroll
  for (int i = 0; i < 32; i += 8) {
    int n = n0 + ty + i;
    float v = Y2[((size_t)b * NPT + n) * C2 + c0 + tx];
    tile[ty + i][tx] = fmaxf(fmaf(v, sc, sh), 0.f);
  }
  __syncthreads();
#pragma unroll
  for (int i = 0; i < 32; i += 8) {
    int c = c0 + ty + i;
    out[((size_t)b * C2 + c) * NPT + n0 + tx] = tile[tx][ty + i];
  }
}

// ---------------------------------------------------------------------------
extern "C" void kernel_launch(void* const* d_in, const int* in_sizes, int n_in,
                              void* d_out, int out_size, void* d_ws, size_t ws_size,
                              hipStream_t stream) {
  (void)in_sizes; (void)n_in; (void)out_size; (void)ws_size;
  const float* pos   = (const float*)d_in[0];
  const float* spos  = (const float*)d_in[1];
  const float* skip  = (const float*)d_in[2];
  const float* sfeat = (const float*)d_in[3];
  const float* W1    = (const float*)d_in[4];
  const float* b1    = (const float*)d_in[5];
  const float* g1    = (const float*)d_in[6];
  const float* beta1 = (const float*)d_in[7];
  const float* W2    = (const float*)d_in[8];
  const float* b2    = (const float*)d_in[9];
  const float* g2    = (const float*)d_in[10];
  const float* beta2 = (const float*)d_in[11];
  float* out = (float*)d_out;

  float* ws = (float*)d_ws;
  size_t off = 0;
  float* sfeatT  = ws + off; off += (size_t)BATCH * NSMP * D2C;   // 4,194,304
  float* W1T     = ws + off; off += (size_t)CIN * C1;
  float* W2T     = ws + off; off += (size_t)C1 * C2;
  int*   knn_idx = (int*)(ws + off); off += (size_t)BN_TOTAL * 3;
  float* knn_w   = ws + off; off += (size_t)BN_TOTAL * 3;
  float* interp  = ws + off; off += (size_t)BN_TOTAL * D2C;       // 16,777,216
  float* Y1      = ws + off; off += (size_t)BN_TOTAL * C1;        // 16,777,216
  float* Y2      = interp;  // alias: interp dead after GEMM1
  float* sposI   = ws + off; off += (size_t)BATCH * NSMP * 3;     // 49,152
  int* flag_list = (int*)(ws + off); off += (size_t)BN_TOTAL;     // 65,536
  float* stats   = ws + off; off += 2048;
  float* sum1 = stats, *sumsq1 = stats + 256;
  float* sum2 = stats + 512, *sumsq2 = stats + 640;
  int*   flag_count = (int*)(stats + 768);
  float* scale1 = stats + 1024, *shift1 = stats + 1280;
  float* scale2 = stats + 1536, *shift2 = stats + 1664;

  // zero: sum1/sumsq1/sum2/sumsq2 (768 floats) + flag_count (1 int)
  hipMemsetAsync(stats, 0, 772 * sizeof(float), stream);

  dim3 tb(32, 8);
  transpose_k<<<dim3(NSMP / 32, D2C / 32, BATCH), tb, 0, stream>>>(
      sfeat, sfeatT, D2C, NSMP, (long)D2C * NSMP, (long)NSMP * D2C);
  transpose_k<<<dim3(CIN / 32, C1 / 32, 1), tb, 0, stream>>>(W1, W1T, C1, CIN, 0, 0);
  transpose_k<<<dim3(C1 / 32, C2 / 32, 1), tb, 0, stream>>>(W2, W2T, C2, C1, 0, 0);

  pack_spos<<<BATCH * NSMP / 256, 256, 0, stream>>>(spos, sposI);
  knn_kernel<<<BN_TOTAL / 64, 256, 0, stream>>>(pos, sposI, knn_idx, knn_w,
                                                flag_list, flag_count);
  knn_fallback<<<BN_TOTAL / 64, 64, 0, stream>>>(pos, sposI, flag_list, flag_count,
                                                 knn_idx, knn_w);
  interp_kernel<<<BN_TOTAL, 256, 0, stream>>>(sfeatT, knn_idx, knn_w, interp);

  gemm1_kernel<<<dim3(BN_TOTAL / BM, C1 / BNT), 256, 0, stream>>>(skip, interp, W1T, b1, Y1);
  stats_kernel<<<256, C1, 0, stream>>>(Y1, sum1, sumsq1, C1, BN_TOTAL / 256);
  bn_coef_kernel<<<1, C1, 0, stream>>>(sum1, sumsq1, g1, beta1, scale1, shift1, C1);

  gemm2_kernel<<<dim3(BN_TOTAL / BM, C2 / BNT), 256, 0, stream>>>(Y1, scale1, shift1, W2T, b2, Y2);
  stats_kernel<<<256, C2, 0, stream>>>(Y2, sum2, sumsq2, C2, BN_TOTAL / 256);
  bn_coef_kernel<<<1, C2, 0, stream>>>(sum2, sumsq2, g2, beta2, scale2, shift2, C2);

  final_kernel<<<dim3(NPT / 32, C2 / 32, BATCH), tb, 0, stream>>>(Y2, scale2, shift2, out);
}

// Round 3
// 432.003 us; speedup vs baseline: 1.6416x; 1.3789x over previous
//
#include <hip/hip_runtime.h>

// Problem constants
constexpr int BATCH = 8;
constexpr int NPT   = 8192;   // N points
constexpr int NSMP  = 2048;   // S sampled points
constexpr int D1C   = 128;    // skip feature channels
constexpr int D2C   = 256;    // sampled feature channels
constexpr int CIN   = 384;    // D1C + D2C
constexpr int C1    = 256;    // layer-1 out channels
constexpr int C2    = 128;    // layer-2 out channels
constexpr int BN_TOTAL = BATCH * NPT;  // 65536 rows

// MFMA GEMM tiling
constexpr int GM = 128, GN = 128, GK = 32;
constexpr int LDA = GK + 8;   // 40 shorts -> 80 B row stride (16B-aligned, 2-way banks only)

typedef __bf16 bf16x8 __attribute__((ext_vector_type(8)));
typedef short  s16x8  __attribute__((ext_vector_type(8)));
typedef float  f32x4  __attribute__((ext_vector_type(4)));

__device__ __forceinline__ unsigned short f2bf(float x) {
  unsigned u = __builtin_bit_cast(unsigned, x);
  u += 0x7fffu + ((u >> 16) & 1u);   // round-to-nearest-even
  return (unsigned short)(u >> 16);
}
__device__ __forceinline__ float bf2f(unsigned short h) {
  return __builtin_bit_cast(float, (unsigned)h << 16);
}

// ---------------------------------------------------------------------------
// 32x32 tiled transpose (fp32): in [rows, cols] -> out [cols, rows], batched.
// ---------------------------------------------------------------------------
__global__ void transpose_k(const float* __restrict__ in, float* __restrict__ out,
                            int rows, int cols, long inBatch, long outBatch) {
  __shared__ float tile[32][33];
  const float* inb = in + (size_t)blockIdx.z * inBatch;
  float* outb = out + (size_t)blockIdx.z * outBatch;
  int c0 = blockIdx.x * 32;
  int r0 = blockIdx.y * 32;
  int tx = threadIdx.x, ty = threadIdx.y;
#pragma unroll
  for (int i = 0; i < 32; i += 8) {
    int r = r0 + ty + i;
    tile[ty + i][tx] = inb[(size_t)r * cols + c0 + tx];
  }
  __syncthreads();
#pragma unroll
  for (int i = 0; i < 32; i += 8) {
    int c = c0 + ty + i;
    outb[(size_t)c * rows + r0 + tx] = tile[tx][ty + i];
  }
}

// ---------------------------------------------------------------------------
// skip [B, D1C, NPT] fp32 -> featB[b*NPT+n][d] bf16 (columns 0..127)
// block (32,8), grid (NPT/32, D1C/32, BATCH)
// ---------------------------------------------------------------------------
__global__ void skip_to_featB(const float* __restrict__ skip,
                              unsigned short* __restrict__ featB) {
  __shared__ float tile[32][33];
  int b = blockIdx.z;
  int n0 = blockIdx.x * 32;
  int d0 = blockIdx.y * 32;
  int tx = threadIdx.x, ty = threadIdx.y;
#pragma unroll
  for (int i = 0; i < 32; i += 8) {
    tile[ty + i][tx] = skip[((size_t)b * D1C + d0 + ty + i) * NPT + n0 + tx];
  }
  __syncthreads();
#pragma unroll
  for (int i = 0; i < 32; i += 8) {
    int n = n0 + ty + i;
    featB[((size_t)b * NPT + n) * CIN + d0 + tx] = f2bf(tile[tx][ty + i]);
  }
}

// ---------------------------------------------------------------------------
// Weight prep: W fp32 -> hi/lo bf16 pair (hi = rn(W), lo = rn(W - hi))
// ---------------------------------------------------------------------------
__global__ void wprep(const float* __restrict__ W, unsigned short* __restrict__ Wh,
                      unsigned short* __restrict__ Wl, int total) {
  int i = blockIdx.x * 256 + threadIdx.x;
  if (i >= total) return;
  float w = W[i];
  unsigned short h = f2bf(w);
  Wh[i] = h;
  Wl[i] = f2bf(w - bf2f(h));
}

// ---------------------------------------------------------------------------
// Pack spos [B,3,NSMP] -> xyz-interleaved sposI [B,NSMP,3]
// ---------------------------------------------------------------------------
__global__ void pack_spos(const float* __restrict__ spos, float* __restrict__ sposI) {
  int g = blockIdx.x * 256 + threadIdx.x;  // B*NSMP = 16384
  int b = g >> 11, s = g & (NSMP - 1);
  const float* sp = spos + (size_t)b * 3 * NSMP;
  sposI[(size_t)g * 3 + 0] = sp[s];
  sposI[(size_t)g * 3 + 1] = sp[NSMP + s];
  sposI[(size_t)g * 3 + 2] = sp[2 * NSMP + s];
}

// ---------------------------------------------------------------------------
// Branchless insert of (d,s) into sorted top-4 values / top-3 indices.
// ---------------------------------------------------------------------------
__device__ __forceinline__ void ins4(float d, int s,
                                     float& b0, float& b1, float& b2, float& b3,
                                     int& i0, int& i1, int& i2) {
  bool c0 = d < b0;
  float v1 = fmaxf(d, b0); b0 = fminf(d, b0);
  int   x1 = c0 ? i0 : s;  i0 = c0 ? s : i0;
  bool c1 = v1 < b1;
  float v2 = fmaxf(v1, b1); b1 = fminf(v1, b1);
  int   x2 = c1 ? i1 : x1; i1 = c1 ? x1 : i1;
  bool c2 = v2 < b2;
  float v3 = fmaxf(v2, b2); b2 = fminf(v2, b2);
  i2 = c2 ? x2 : i2;
  b3 = fminf(v3, b3);
}

// ---------------------------------------------------------------------------
// kNN: 4 waves x 512-sample segments, fp32 branchless top-4, LDS merge,
// fp32-noise certification -> fp64 fallback list.
// ---------------------------------------------------------------------------
constexpr int SEG = NSMP / 4;  // 512

__global__ __launch_bounds__(256) void knn_kernel(
    const float* __restrict__ pos,    // [B,3,NPT]
    const float* __restrict__ sposI,  // [B,NSMP,3] interleaved
    int* __restrict__ idx_out,        // [BN_TOTAL,3]
    float* __restrict__ wgt_out,      // [BN_TOTAL,3]
    int* __restrict__ flag_list,
    int* __restrict__ flag_count) {
  __shared__ float qs[3 * NSMP];   // 24 KB
  __shared__ float md[4][4][64];
  __shared__ int   mi[4][3][64];

  int tid = threadIdx.x;
  int wave = tid >> 6, lane = tid & 63;
  int blk = blockIdx.x;
  int b = blk >> 7;
  int n = ((blk & 127) << 6) + lane;

  const float4* src = (const float4*)(sposI + (size_t)b * 3 * NSMP);
  float4* dst = (float4*)qs;
  for (int t = tid; t < 3 * NSMP / 4; t += 256) dst[t] = src[t];
  __syncthreads();

  const float* pb = pos + (size_t)b * 3 * NPT;
  float px = pb[n], py = pb[NPT + n], pz = pb[2 * NPT + n];

  const float INF = __builtin_inff();
  float b0 = INF, b1 = INF, b2 = INF, b3 = INF;
  int i0 = 0, i1 = 0, i2 = 0;

  const float4* q4 = (const float4*)qs;
  int s0 = wave * SEG;
  for (int t = 0; t < SEG; t += 4) {
    int s = s0 + t;
    int u = 3 * (s >> 2);
    float4 qa = q4[u], qb = q4[u + 1], qc = q4[u + 2];
    {
      float dx = px - qa.x, dy = py - qa.y, dz = pz - qa.z;
      float d = fmaf(dx, dx, fmaf(dy, dy, dz * dz));
      ins4(d, s + 0, b0, b1, b2, b3, i0, i1, i2);
    }
    {
      float dx = px - qa.w, dy = py - qb.x, dz = pz - qb.y;
      float d = fmaf(dx, dx, fmaf(dy, dy, dz * dz));
      ins4(d, s + 1, b0, b1, b2, b3, i0, i1, i2);
    }
    {
      float dx = px - qb.z, dy = py - qb.w, dz = pz - qc.x;
      float d = fmaf(dx, dx, fmaf(dy, dy, dz * dz));
      ins4(d, s + 2, b0, b1, b2, b3, i0, i1, i2);
    }
    {
      float dx = px - qc.y, dy = py - qc.z, dz = pz - qc.w;
      float d = fmaf(dx, dx, fmaf(dy, dy, dz * dz));
      ins4(d, s + 3, b0, b1, b2, b3, i0, i1, i2);
    }
  }

  md[wave][0][lane] = b0; md[wave][1][lane] = b1;
  md[wave][2][lane] = b2; md[wave][3][lane] = b3;
  mi[wave][0][lane] = i0; mi[wave][1][lane] = i1; mi[wave][2][lane] = i2;
  __syncthreads();

  if (tid < 64) {
    float B0 = INF, B1 = INF, B2 = INF, B3 = INF;
    int I0 = 0, I1 = 0, I2 = 0;
#pragma unroll
    for (int w = 0; w < 4; w++) {
#pragma unroll
      for (int sl = 0; sl < 3; sl++)
        ins4(md[w][sl][tid], mi[w][sl][tid], B0, B1, B2, B3, I0, I1, I2);
      ins4(md[w][3][tid], 0x7FFFFFFF, B0, B1, B2, B3, I0, I1, I2);
    }
    int p = blk * 64 + tid;
    bool flag = (B3 - B2) < 4e-6f * (B3 + B2) + 1e-12f;
    if (flag) {
      int slot = atomicAdd(flag_count, 1);
      flag_list[slot] = p;
    }
    double w0 = 1.0 / ((double)B0 + 1e-8);
    double w1 = 1.0 / ((double)B1 + 1e-8);
    double w2 = 1.0 / ((double)B2 + 1e-8);
    double inv = 1.0 / (w0 + w1 + w2);
    size_t o = (size_t)p * 3;
    idx_out[o + 0] = I0; idx_out[o + 1] = I1; idx_out[o + 2] = I2;
    wgt_out[o + 0] = (float)(w0 * inv);
    wgt_out[o + 1] = (float)(w1 * inv);
    wgt_out[o + 2] = (float)(w2 * inv);
  }
}

// ---------------------------------------------------------------------------
// Exact fp64 fallback for flagged points.
// ---------------------------------------------------------------------------
__global__ __launch_bounds__(64) void knn_fallback(
    const float* __restrict__ pos, const float* __restrict__ sposI,
    const int* __restrict__ flag_list, const int* __restrict__ flag_count,
    int* __restrict__ idx_out, float* __restrict__ wgt_out) {
  int t = blockIdx.x * 64 + threadIdx.x;
  if (t >= *flag_count) return;
  int p = flag_list[t];
  int b = p >> 13, n = p & (NPT - 1);
  const float* pb = pos + (size_t)b * 3 * NPT;
  double px = (double)pb[n], py = (double)pb[NPT + n], pz = (double)pb[2 * NPT + n];
  const float* q = sposI + (size_t)b * 3 * NSMP;
  double best0 = 1e300, best1 = 1e300, best2 = 1e300;
  int i0 = 0, i1 = 0, i2 = 0;
  for (int s = 0; s < NSMP; s++) {
    double dx = px - (double)q[3 * s];
    double dy = py - (double)q[3 * s + 1];
    double dz = pz - (double)q[3 * s + 2];
    double d = dx * dx + dy * dy + dz * dz;
    if (d < best2) {
      if (d < best1) {
        best2 = best1; i2 = i1;
        if (d < best0) { best1 = best0; i1 = i0; best0 = d; i0 = s; }
        else           { best1 = d; i1 = s; }
      } else { best2 = d; i2 = s; }
    }
  }
  double w0 = 1.0 / (best0 + 1e-8);
  double w1 = 1.0 / (best1 + 1e-8);
  double w2 = 1.0 / (best2 + 1e-8);
  double inv = 1.0 / (w0 + w1 + w2);
  size_t o = (size_t)p * 3;
  idx_out[o + 0] = i0; idx_out[o + 1] = i1; idx_out[o + 2] = i2;
  wgt_out[o + 0] = (float)(w0 * inv);
  wgt_out[o + 1] = (float)(w1 * inv);
  wgt_out[o + 2] = (float)(w2 * inv);
}

// ---------------------------------------------------------------------------
// Interp gather -> featB columns 128..383 (bf16)
// ---------------------------------------------------------------------------
__global__ __launch_bounds__(256) void interp_kernel(
    const float* __restrict__ sfeatT,  // [B, NSMP, D2C]
    const int* __restrict__ idx,
    const float* __restrict__ wgt,
    unsigned short* __restrict__ featB) {
  int p = blockIdx.x;
  int c = threadIdx.x;
  int b = p >> 13;
  size_t o = (size_t)p * 3;
  int i0 = idx[o], i1 = idx[o + 1], i2 = idx[o + 2];
  float w0 = wgt[o], w1 = wgt[o + 1], w2 = wgt[o + 2];
  const float* base = sfeatT + (size_t)b * NSMP * D2C;
  float v = w0 * base[(size_t)i0 * D2C + c]
          + w1 * base[(size_t)i1 * D2C + c]
          + w2 * base[(size_t)i2 * D2C + c];
  featB[(size_t)p * CIN + D1C + c] = f2bf(v);
}

// ---------------------------------------------------------------------------
// GEMM1 (MFMA bf16, B hi/lo split): Y1 = featB @ W1^T + b1, bf16 out.
// Tile 128x128, BK=32, 4 waves x (4x4) 16x16x32 fragments.
// grid (BN_TOTAL/GM, C1/GN)
// ---------------------------------------------------------------------------
__global__ __launch_bounds__(256) void gemm1_mfma(
    const unsigned short* __restrict__ featB,  // [BN_TOTAL][CIN] bf16
    const unsigned short* __restrict__ W1h,    // [C1][CIN] bf16
    const unsigned short* __restrict__ W1l,
    const float* __restrict__ bias,
    unsigned short* __restrict__ Y1) {         // [BN_TOTAL][C1] bf16
  __shared__ unsigned short As[GM][LDA];
  __shared__ unsigned short Bh[GN][LDA];
  __shared__ unsigned short Bl[GN][LDA];
  int tid = threadIdx.x;
  int lane = tid & 63;
  int wave = tid >> 6;
  int wrow = (wave >> 1) * 64, wcol = (wave & 1) * 64;
  int m16 = lane & 15, quad = lane >> 4;
  int row0 = blockIdx.x * GM;
  int col0 = blockIdx.y * GN;

  f32x4 acc[4][4];
#pragma unroll
  for (int j = 0; j < 4; j++) {
    float bj = bias[col0 + wcol + j * 16 + m16];
#pragma unroll
    for (int i = 0; i < 4; i++) acc[i][j] = f32x4{bj, bj, bj, bj};
  }

  int ldr = tid >> 2;          // 0..63
  int seg = (tid & 3) * 8;     // 0,8,16,24

  for (int k0 = 0; k0 < CIN; k0 += GK) {
    *(s16x8*)&As[ldr][seg]      = *(const s16x8*)&featB[(size_t)(row0 + ldr) * CIN + k0 + seg];
    *(s16x8*)&As[ldr + 64][seg] = *(const s16x8*)&featB[(size_t)(row0 + ldr + 64) * CIN + k0 + seg];
    *(s16x8*)&Bh[ldr][seg]      = *(const s16x8*)&W1h[(size_t)(col0 + ldr) * CIN + k0 + seg];
    *(s16x8*)&Bh[ldr + 64][seg] = *(const s16x8*)&W1h[(size_t)(col0 + ldr + 64) * CIN + k0 + seg];
    *(s16x8*)&Bl[ldr][seg]      = *(const s16x8*)&W1l[(size_t)(col0 + ldr) * CIN + k0 + seg];
    *(s16x8*)&Bl[ldr + 64][seg] = *(const s16x8*)&W1l[(size_t)(col0 + ldr + 64) * CIN + k0 + seg];
    __syncthreads();

    bf16x8 a[4], bhf[4], blf[4];
#pragma unroll
    for (int i = 0; i < 4; i++)
      a[i] = __builtin_bit_cast(bf16x8, *(const s16x8*)&As[wrow + i * 16 + m16][quad * 8]);
#pragma unroll
    for (int j = 0; j < 4; j++) {
      bhf[j] = __builtin_bit_cast(bf16x8, *(const s16x8*)&Bh[wcol + j * 16 + m16][quad * 8]);
      blf[j] = __builtin_bit_cast(bf16x8, *(const s16x8*)&Bl[wcol + j * 16 + m16][quad * 8]);
    }
#pragma unroll
    for (int i = 0; i < 4; i++)
#pragma unroll
      for (int j = 0; j < 4; j++) {
        acc[i][j] = __builtin_amdgcn_mfma_f32_16x16x32_bf16(a[i], bhf[j], acc[i][j], 0, 0, 0);
        acc[i][j] = __builtin_amdgcn_mfma_f32_16x16x32_bf16(a[i], blf[j], acc[i][j], 0, 0, 0);
      }
    __syncthreads();
  }

#pragma unroll
  for (int i = 0; i < 4; i++)
#pragma unroll
    for (int j = 0; j < 4; j++) {
      int col = col0 + wcol + j * 16 + m16;
#pragma unroll
      for (int r = 0; r < 4; r++) {
        int row = row0 + wrow + i * 16 + quad * 4 + r;
        Y1[(size_t)row * C1 + col] = f2bf(acc[i][j][r]);
      }
    }
}

// ---------------------------------------------------------------------------
// GEMM2 (MFMA bf16): X2 = relu(bn1(Y1)) fused in staging; Y2 = X2 @ W2^T + b2.
// grid (BN_TOTAL/GM, 1)  (C2 == GN == 128)
// ---------------------------------------------------------------------------
__global__ __launch_bounds__(256) void gemm2_mfma(
    const unsigned short* __restrict__ Y1,   // [BN_TOTAL][C1] bf16
    const float* __restrict__ scale1, const float* __restrict__ shift1,
    const unsigned short* __restrict__ W2h,  // [C2][C1] bf16
    const unsigned short* __restrict__ W2l,
    const float* __restrict__ bias,
    unsigned short* __restrict__ Y2) {       // [BN_TOTAL][C2] bf16
  __shared__ unsigned short As[GM][LDA];
  __shared__ unsigned short Bh[GN][LDA];
  __shared__ unsigned short Bl[GN][LDA];
  __shared__ float scs[C1], shs[C1];
  int tid = threadIdx.x;
  int lane = tid & 63;
  int wave = tid >> 6;
  int wrow = (wave >> 1) * 64, wcol = (wave & 1) * 64;
  int m16 = lane & 15, quad = lane >> 4;
  int row0 = blockIdx.x * GM;

  scs[tid] = scale1[tid];
  shs[tid] = shift1[tid];

  f32x4 acc[4][4];
#pragma unroll
  for (int j = 0; j < 4; j++) {
    float bj = bias[wcol + j * 16 + m16];
#pragma unroll
    for (int i = 0; i < 4; i++) acc[i][j] = f32x4{bj, bj, bj, bj};
  }

  int ldr = tid >> 2;
  int seg = (tid & 3) * 8;
  __syncthreads();  // scs/shs visible

  for (int k0 = 0; k0 < C1; k0 += GK) {
#pragma unroll
    for (int rr = 0; rr < 2; rr++) {
      int r = ldr + rr * 64;
      s16x8 v = *(const s16x8*)&Y1[(size_t)(row0 + r) * C1 + k0 + seg];
      unsigned short ov[8];
#pragma unroll
      for (int e = 0; e < 8; e++) {
        float x = bf2f((unsigned short)v[e]);
        float y = fmaxf(fmaf(x, scs[k0 + seg + e], shs[k0 + seg + e]), 0.f);
        ov[e] = f2bf(y);
      }
      *(s16x8*)&As[r][seg] = *(const s16x8*)ov;
    }
    *(s16x8*)&Bh[ldr][seg]      = *(const s16x8*)&W2h[(size_t)ldr * C1 + k0 + seg];
    *(s16x8*)&Bh[ldr + 64][seg] = *(const s16x8*)&W2h[(size_t)(ldr + 64) * C1 + k0 + seg];
    *(s16x8*)&Bl[ldr][seg]      = *(const s16x8*)&W2l[(size_t)ldr * C1 + k0 + seg];
    *(s16x8*)&Bl[ldr + 64][seg] = *(const s16x8*)&W2l[(size_t)(ldr + 64) * C1 + k0 + seg];
    __syncthreads();

    bf16x8 a[4], bhf[4], blf[4];
#pragma unroll
    for (int i = 0; i < 4; i++)
      a[i] = __builtin_bit_cast(bf16x8, *(const s16x8*)&As[wrow + i * 16 + m16][quad * 8]);
#pragma unroll
    for (int j = 0; j < 4; j++) {
      bhf[j] = __builtin_bit_cast(bf16x8, *(const s16x8*)&Bh[wcol + j * 16 + m16][quad * 8]);
      blf[j] = __builtin_bit_cast(bf16x8, *(const s16x8*)&Bl[wcol + j * 16 + m16][quad * 8]);
    }
#pragma unroll
    for (int i = 0; i < 4; i++)
#pragma unroll
      for (int j = 0; j < 4; j++) {
        acc[i][j] = __builtin_amdgcn_mfma_f32_16x16x32_bf16(a[i], bhf[j], acc[i][j], 0, 0, 0);
        acc[i][j] = __builtin_amdgcn_mfma_f32_16x16x32_bf16(a[i], blf[j], acc[i][j], 0, 0, 0);
      }
    __syncthreads();
  }

#pragma unroll
  for (int i = 0; i < 4; i++)
#pragma unroll
    for (int j = 0; j < 4; j++) {
      int col = wcol + j * 16 + m16;
#pragma unroll
      for (int r = 0; r < 4; r++) {
        int row = row0 + wrow + i * 16 + quad * 4 + r;
        Y2[(size_t)row * C2 + col] = f2bf(acc[i][j][r]);
      }
    }
}

// ---------------------------------------------------------------------------
// Per-channel sum / sumsq over rows (bf16 input). block = C threads.
// ---------------------------------------------------------------------------
__global__ void stats_bf16(const unsigned short* __restrict__ Y,
                           float* __restrict__ sum, float* __restrict__ sumsq,
                           int C, int rowsPer) {
  int c = threadIdx.x;
  size_t r0 = (size_t)blockIdx.x * rowsPer;
  float s = 0.f, s2 = 0.f;
  for (int r = 0; r < rowsPer; r++) {
    float v = bf2f(Y[(r0 + r) * C + c]);
    s += v;
    s2 += v * v;
  }
  atomicAdd(&sum[c], s);
  atomicAdd(&sumsq[c], s2);
}

__global__ void bn_coef_kernel(const float* __restrict__ sum, const float* __restrict__ sumsq,
                               const float* __restrict__ g, const float* __restrict__ beta,
                               float* __restrict__ scale, float* __restrict__ shift, int C) {
  int c = threadIdx.x + blockIdx.x * blockDim.x;
  if (c >= C) return;
  const float invBN = 1.0f / (float)BN_TOTAL;
  float m = sum[c] * invBN;
  float var = sumsq[c] * invBN - m * m;
  float sc = g[c] / sqrtf(var + 1e-5f);
  scale[c] = sc;
  shift[c] = beta[c] - m * sc;
}

// ---------------------------------------------------------------------------
// Final: out[b][c][n] = relu(bn2(Y2)) transposed, fp32 out. Y2 is bf16.
// ---------------------------------------------------------------------------
__global__ void final_kernel(const unsigned short* __restrict__ Y2,
                             const float* __restrict__ scale, const float* __restrict__ shift,
                             float* __restrict__ out) {
  __shared__ float tile[32][33];
  int b = blockIdx.z;
  int n0 = blockIdx.x * 32;
  int c0 = blockIdx.y * 32;
  int tx = threadIdx.x, ty = threadIdx.y;
  float sc = scale[c0 + tx];
  float sh = shift[c0 + tx];
#pragma unroll
  for (int i = 0; i < 32; i += 8) {
    int n = n0 + ty + i;
    float v = bf2f(Y2[((size_t)b * NPT + n) * C2 + c0 + tx]);
    tile[ty + i][tx] = fmaxf(fmaf(v, sc, sh), 0.f);
  }
  __syncthreads();
#pragma unroll
  for (int i = 0; i < 32; i += 8) {
    int c = c0 + ty + i;
    out[((size_t)b * C2 + c) * NPT + n0 + tx] = tile[tx][ty + i];
  }
}

// ---------------------------------------------------------------------------
extern "C" void kernel_launch(void* const* d_in, const int* in_sizes, int n_in,
                              void* d_out, int out_size, void* d_ws, size_t ws_size,
                              hipStream_t stream) {
  (void)in_sizes; (void)n_in; (void)out_size; (void)ws_size;
  const float* pos   = (const float*)d_in[0];
  const float* spos  = (const float*)d_in[1];
  const float* skip  = (const float*)d_in[2];
  const float* sfeat = (const float*)d_in[3];
  const float* W1    = (const float*)d_in[4];
  const float* b1    = (const float*)d_in[5];
  const float* g1    = (const float*)d_in[6];
  const float* beta1 = (const float*)d_in[7];
  const float* W2    = (const float*)d_in[8];
  const float* b2    = (const float*)d_in[9];
  const float* g2    = (const float*)d_in[10];
  const float* beta2 = (const float*)d_in[11];
  float* out = (float*)d_out;

  // Workspace layout (float units; all chunks 16B-aligned). ~30M floats.
  float* ws = (float*)d_ws;
  size_t off = 0;
  float* sfeatT  = ws + off; off += (size_t)BATCH * NSMP * D2C;        // 4,194,304
  unsigned short* featB = (unsigned short*)(ws + off); off += (size_t)BN_TOTAL * CIN / 2;  // 12,582,912
  unsigned short* Y1    = (unsigned short*)(ws + off); off += (size_t)BN_TOTAL * C1 / 2;   //  8,388,608
  unsigned short* Y2    = (unsigned short*)(ws + off); off += (size_t)BN_TOTAL * C2 / 2;   //  4,194,304
  unsigned short* W1h   = (unsigned short*)(ws + off); off += (size_t)C1 * CIN / 2;
  unsigned short* W1l   = (unsigned short*)(ws + off); off += (size_t)C1 * CIN / 2;
  unsigned short* W2h   = (unsigned short*)(ws + off); off += (size_t)C2 * C1 / 2;
  unsigned short* W2l   = (unsigned short*)(ws + off); off += (size_t)C2 * C1 / 2;
  int*   knn_idx = (int*)(ws + off); off += (size_t)BN_TOTAL * 3;
  float* knn_w   = ws + off; off += (size_t)BN_TOTAL * 3;
  float* sposI   = ws + off; off += (size_t)BATCH * NSMP * 3;
  int* flag_list = (int*)(ws + off); off += (size_t)BN_TOTAL;
  float* stats   = ws + off; off += 2048;
  float* sum1 = stats, *sumsq1 = stats + 256;
  float* sum2 = stats + 512, *sumsq2 = stats + 640;
  int*   flag_count = (int*)(stats + 768);
  float* scale1 = stats + 1024, *shift1 = stats + 1280;
  float* scale2 = stats + 1536, *shift2 = stats + 1664;

  hipMemsetAsync(stats, 0, 772 * sizeof(float), stream);

  dim3 tb(32, 8);
  // sfeat [B, D2C, NSMP] -> sfeatT [B, NSMP, D2C] (fp32, for gather)
  transpose_k<<<dim3(NSMP / 32, D2C / 32, BATCH), tb, 0, stream>>>(
      sfeat, sfeatT, D2C, NSMP, (long)D2C * NSMP, (long)NSMP * D2C);
  // weights -> bf16 hi/lo (native [out][in] layout == MFMA B layout, no transpose)
  wprep<<<(C1 * CIN + 255) / 256, 256, 0, stream>>>(W1, W1h, W1l, C1 * CIN);
  wprep<<<(C2 * C1 + 255) / 256, 256, 0, stream>>>(W2, W2h, W2l, C2 * C1);
  // skip -> featB[:, 0:128] bf16
  skip_to_featB<<<dim3(NPT / 32, D1C / 32, BATCH), tb, 0, stream>>>(skip, featB);

  pack_spos<<<BATCH * NSMP / 256, 256, 0, stream>>>(spos, sposI);
  knn_kernel<<<BN_TOTAL / 64, 256, 0, stream>>>(pos, sposI, knn_idx, knn_w,
                                                flag_list, flag_count);
  knn_fallback<<<BN_TOTAL / 64, 64, 0, stream>>>(pos, sposI, flag_list, flag_count,
                                                 knn_idx, knn_w);
  // interp -> featB[:, 128:384] bf16
  interp_kernel<<<BN_TOTAL, 256, 0, stream>>>(sfeatT, knn_idx, knn_w, featB);

  gemm1_mfma<<<dim3(BN_TOTAL / GM, C1 / GN), 256, 0, stream>>>(featB, W1h, W1l, b1, Y1);
  stats_bf16<<<256, C1, 0, stream>>>(Y1, sum1, sumsq1, C1, BN_TOTAL / 256);
  bn_coef_kernel<<<1, C1, 0, stream>>>(sum1, sumsq1, g1, beta1, scale1, shift1, C1);

  gemm2_mfma<<<dim3(BN_TOTAL / GM, 1), 256, 0, stream>>>(Y1, scale1, shift1, W2h, W2l, b2, Y2);
  stats_bf16<<<256, C2, 0, stream>>>(Y2, sum2, sumsq2, C2, BN_TOTAL / 256);
  bn_coef_kernel<<<1, C2, 0, stream>>>(sum2, sumsq2, g2, beta2, scale2, shift2, C2);

  final_kernel<<<dim3(NPT / 32, C2 / 32, BATCH), tb, 0, stream>>>(Y2, scale2, shift2, out);
}

// Round 4
// 428.820 us; speedup vs baseline: 1.6538x; 1.0074x over previous
//
#include <hip/hip_runtime.h>

// Problem constants
constexpr int BATCH = 8;
constexpr int NPT   = 8192;   // N points
constexpr int NSMP  = 2048;   // S sampled points
constexpr int D1C   = 128;    // skip feature channels
constexpr int D2C   = 256;    // sampled feature channels
constexpr int CIN   = 384;    // D1C + D2C
constexpr int C1    = 256;    // layer-1 out channels
constexpr int C2    = 128;    // layer-2 out channels
constexpr int BN_TOTAL = BATCH * NPT;  // 65536 rows

// MFMA GEMM tiling
constexpr int GM = 128, GN = 128, GK = 32;
constexpr int LDA = GK + 8;   // 40 shorts -> 80 B row stride

typedef __bf16 bf16x8 __attribute__((ext_vector_type(8)));
typedef short  s16x8  __attribute__((ext_vector_type(8)));
typedef float  f32x4  __attribute__((ext_vector_type(4)));

__device__ __forceinline__ unsigned short f2bf(float x) {
  unsigned u = __builtin_bit_cast(unsigned, x);
  u += 0x7fffu + ((u >> 16) & 1u);   // round-to-nearest-even
  return (unsigned short)(u >> 16);
}
__device__ __forceinline__ float bf2f(unsigned short h) {
  return __builtin_bit_cast(float, (unsigned)h << 16);
}

// ---------------------------------------------------------------------------
// 32x32 tiled transpose (fp32)
// ---------------------------------------------------------------------------
__global__ void transpose_k(const float* __restrict__ in, float* __restrict__ out,
                            int rows, int cols, long inBatch, long outBatch) {
  __shared__ float tile[32][33];
  const float* inb = in + (size_t)blockIdx.z * inBatch;
  float* outb = out + (size_t)blockIdx.z * outBatch;
  int c0 = blockIdx.x * 32;
  int r0 = blockIdx.y * 32;
  int tx = threadIdx.x, ty = threadIdx.y;
#pragma unroll
  for (int i = 0; i < 32; i += 8) {
    int r = r0 + ty + i;
    tile[ty + i][tx] = inb[(size_t)r * cols + c0 + tx];
  }
  __syncthreads();
#pragma unroll
  for (int i = 0; i < 32; i += 8) {
    int c = c0 + ty + i;
    outb[(size_t)c * rows + r0 + tx] = tile[tx][ty + i];
  }
}

// ---------------------------------------------------------------------------
// skip [B, D1C, NPT] fp32 -> featB[b*NPT+n][d] bf16 (columns 0..127)
// ---------------------------------------------------------------------------
__global__ void skip_to_featB(const float* __restrict__ skip,
                              unsigned short* __restrict__ featB) {
  __shared__ float tile[32][33];
  int b = blockIdx.z;
  int n0 = blockIdx.x * 32;
  int d0 = blockIdx.y * 32;
  int tx = threadIdx.x, ty = threadIdx.y;
#pragma unroll
  for (int i = 0; i < 32; i += 8) {
    tile[ty + i][tx] = skip[((size_t)b * D1C + d0 + ty + i) * NPT + n0 + tx];
  }
  __syncthreads();
#pragma unroll
  for (int i = 0; i < 32; i += 8) {
    int n = n0 + ty + i;
    featB[((size_t)b * NPT + n) * CIN + d0 + tx] = f2bf(tile[tx][ty + i]);
  }
}

// ---------------------------------------------------------------------------
// Weight prep: W fp32 -> hi/lo bf16 pair
// ---------------------------------------------------------------------------
__global__ void wprep(const float* __restrict__ W, unsigned short* __restrict__ Wh,
                      unsigned short* __restrict__ Wl, int total) {
  int i = blockIdx.x * 256 + threadIdx.x;
  if (i >= total) return;
  float w = W[i];
  unsigned short h = f2bf(w);
  Wh[i] = h;
  Wl[i] = f2bf(w - bf2f(h));
}

// ---------------------------------------------------------------------------
// Pack spos [B,3,NSMP] -> xyz-interleaved sposI [B,NSMP,3]
// ---------------------------------------------------------------------------
__global__ void pack_spos(const float* __restrict__ spos, float* __restrict__ sposI) {
  int g = blockIdx.x * 256 + threadIdx.x;  // B*NSMP = 16384
  int b = g >> 11, s = g & (NSMP - 1);
  const float* sp = spos + (size_t)b * 3 * NSMP;
  sposI[(size_t)g * 3 + 0] = sp[s];
  sposI[(size_t)g * 3 + 1] = sp[NSMP + s];
  sposI[(size_t)g * 3 + 2] = sp[2 * NSMP + s];
}

// ---------------------------------------------------------------------------
// kNN with packed keys: key = (bits(d) & ~0x7FF) | sample_idx (11 bits).
// Positive-float ordering == int ordering, so a 7-op fmin/fmax sort-4 chain
// tracks indices for free with lexicographic (d, idx) tie-breaking (matches
// jax.lax.top_k). 4 waves x 512-sample segments; LDS key merge; certification
// on the masked 3rd/4th gap -> wave-parallel fp64 fallback for the rare flags.
// Weights recomputed in exact fp64 from chosen indices.
// ---------------------------------------------------------------------------
constexpr int SEG = NSMP / 4;  // 512

__global__ __launch_bounds__(256) void knn_kernel(
    const float* __restrict__ pos,    // [B,3,NPT]
    const float* __restrict__ sposI,  // [B,NSMP,3] interleaved
    int* __restrict__ idx_out,        // [BN_TOTAL,3]
    float* __restrict__ wgt_out,      // [BN_TOTAL,3]
    int* __restrict__ flag_list,
    int* __restrict__ flag_count) {
  __shared__ float qs[3 * NSMP];   // 24 KB
  __shared__ float mk[4][4][64];   // per-wave sorted top-4 keys (4 KB)

  int tid = threadIdx.x;
  int wave = tid >> 6, lane = tid & 63;
  int blk = blockIdx.x;
  int b = blk >> 7;
  int n = ((blk & 127) << 6) + lane;

  const float4* src = (const float4*)(sposI + (size_t)b * 3 * NSMP);
  float4* dst = (float4*)qs;
  for (int t = tid; t < 3 * NSMP / 4; t += 256) dst[t] = src[t];
  __syncthreads();

  const float* pb = pos + (size_t)b * 3 * NPT;
  float px = pb[n], py = pb[NPT + n], pz = pb[2 * NPT + n];

  const float INF = __builtin_inff();
  float k0 = INF, k1 = INF, k2 = INF, k3 = INF;

  const float4* q4 = (const float4*)qs;
  int s0 = wave * SEG;

#define KNN_STEP(QX, QY, QZ, SS)                                          \
  {                                                                       \
    float dx = px - (QX), dy = py - (QY), dz = pz - (QZ);                 \
    float d = fmaf(dx, dx, fmaf(dy, dy, dz * dz));                        \
    unsigned ki = (__builtin_bit_cast(unsigned, d) & 0xFFFFF800u) |       \
                  (unsigned)(SS);                                         \
    float kf = __builtin_bit_cast(float, ki);                             \
    float v1 = fmaxf(kf, k0); k0 = fminf(kf, k0);                         \
    float v2 = fmaxf(v1, k1); k1 = fminf(v1, k1);                         \
    float v3 = fmaxf(v2, k2); k2 = fminf(v2, k2);                         \
    k3 = fminf(v3, k3);                                                   \
  }

  for (int t = 0; t < SEG; t += 4) {
    int s = s0 + t;
    int u = 3 * (s >> 2);
    float4 qa = q4[u], qb = q4[u + 1], qc = q4[u + 2];
    KNN_STEP(qa.x, qa.y, qa.z, s + 0)
    KNN_STEP(qa.w, qb.x, qb.y, s + 1)
    KNN_STEP(qb.z, qb.w, qc.x, s + 2)
    KNN_STEP(qc.y, qc.z, qc.w, s + 3)
  }
#undef KNN_STEP

  mk[wave][0][lane] = k0; mk[wave][1][lane] = k1;
  mk[wave][2][lane] = k2; mk[wave][3][lane] = k3;
  __syncthreads();

  if (tid < 64) {
    float K0 = INF, K1 = INF, K2 = INF, K3 = INF;
#pragma unroll
    for (int w = 0; w < 4; w++) {
#pragma unroll
      for (int sl = 0; sl < 4; sl++) {
        float kf = mk[w][sl][tid];
        float v1 = fmaxf(kf, K0); K0 = fminf(kf, K0);
        float v2 = fmaxf(v1, K1); K1 = fminf(v1, K1);
        float v3 = fmaxf(v2, K2); K2 = fminf(v2, K2);
        K3 = fminf(v3, K3);
      }
    }
    int p = blk * 64 + tid;
    int I0 = (int)(__builtin_bit_cast(unsigned, K0) & 0x7FFu);
    int I1 = (int)(__builtin_bit_cast(unsigned, K1) & 0x7FFu);
    int I2 = (int)(__builtin_bit_cast(unsigned, K2) & 0x7FFu);
    float d2m = __builtin_bit_cast(float, __builtin_bit_cast(unsigned, K2) & 0xFFFFF800u);
    float d3m = __builtin_bit_cast(float, __builtin_bit_cast(unsigned, K3) & 0xFFFFF800u);
    // packing perturbs d by <=2^-12 rel; flag gaps within 4x margin of that
    bool flag = (d3m - d2m) < 2e-3f * d3m + 1e-7f;
    if (flag) {
      int slot = atomicAdd(flag_count, 1);
      flag_list[slot] = p;
    }
    // exact fp64 weights from chosen indices
    const float* q = sposI + (size_t)b * 3 * NSMP;
    double pxd = (double)px, pyd = (double)py, pzd = (double)pz;
    double dd[3]; int II[3] = {I0, I1, I2};
#pragma unroll
    for (int k = 0; k < 3; k++) {
      double dx = pxd - (double)q[3 * II[k]];
      double dy = pyd - (double)q[3 * II[k] + 1];
      double dz = pzd - (double)q[3 * II[k] + 2];
      dd[k] = dx * dx + dy * dy + dz * dz;
    }
    double w0 = 1.0 / (dd[0] + 1e-8);
    double w1 = 1.0 / (dd[1] + 1e-8);
    double w2 = 1.0 / (dd[2] + 1e-8);
    double inv = 1.0 / (w0 + w1 + w2);
    size_t o = (size_t)p * 3;
    idx_out[o + 0] = I0; idx_out[o + 1] = I1; idx_out[o + 2] = I2;
    wgt_out[o + 0] = (float)(w0 * inv);
    wgt_out[o + 1] = (float)(w1 * inv);
    wgt_out[o + 2] = (float)(w2 * inv);
  }
}

// ---------------------------------------------------------------------------
// Exact fp64 fallback, wave-parallel: one wave per flagged point; 64 lanes
// scan 32 samples each, then butterfly shuffle-merge of sorted top-3 with
// lexicographic (d, idx) compare. No block barriers (divergent trip counts).
// ---------------------------------------------------------------------------
__device__ __forceinline__ bool dless(double d, int i, double D, int I) {
  return d < D || (d == D && i < I);
}
__device__ __forceinline__ void dins3(double d, int i,
                                      double& b0, double& b1, double& b2,
                                      int& i0, int& i1, int& i2) {
  if (dless(d, i, b2, i2)) {
    if (dless(d, i, b1, i1)) {
      b2 = b1; i2 = i1;
      if (dless(d, i, b0, i0)) { b1 = b0; i1 = i0; b0 = d; i0 = i; }
      else                     { b1 = d; i1 = i; }
    } else { b2 = d; i2 = i; }
  }
}

__global__ __launch_bounds__(256) void knn_fallback(
    const float* __restrict__ pos, const float* __restrict__ sposI,
    const int* __restrict__ flag_list, const int* __restrict__ flag_count,
    int* __restrict__ idx_out, float* __restrict__ wgt_out) {
  int wave = threadIdx.x >> 6, lane = threadIdx.x & 63;
  int gw = blockIdx.x * 4 + wave;           // global wave id, 0..1023
  int cnt = *flag_count;
  for (int t = gw; t < cnt; t += 1024) {
    int p = flag_list[t];
    int b = p >> 13, n = p & (NPT - 1);
    const float* pb = pos + (size_t)b * 3 * NPT;
    double px = (double)pb[n], py = (double)pb[NPT + n], pz = (double)pb[2 * NPT + n];
    const float* q = sposI + (size_t)b * 3 * NSMP;
    double b0 = 1e300, b1 = 1e300, b2 = 1e300;
    int i0 = 0x7FFFFFFF, i1 = 0x7FFFFFFF, i2 = 0x7FFFFFFF;
    for (int s = lane; s < NSMP; s += 64) {
      double dx = px - (double)q[3 * s];
      double dy = py - (double)q[3 * s + 1];
      double dz = pz - (double)q[3 * s + 2];
      double d = dx * dx + dy * dy + dz * dz;
      dins3(d, s, b0, b1, b2, i0, i1, i2);
    }
    // butterfly merge across the wave
#pragma unroll
    for (int m = 1; m < 64; m <<= 1) {
      double o0 = __shfl_xor(b0, m, 64), o1 = __shfl_xor(b1, m, 64), o2 = __shfl_xor(b2, m, 64);
      int    j0 = __shfl_xor(i0, m, 64), j1 = __shfl_xor(i1, m, 64), j2 = __shfl_xor(i2, m, 64);
      dins3(o0, j0, b0, b1, b2, i0, i1, i2);
      dins3(o1, j1, b0, b1, b2, i0, i1, i2);
      dins3(o2, j2, b0, b1, b2, i0, i1, i2);
    }
    if (lane == 0) {
      double w0 = 1.0 / (b0 + 1e-8);
      double w1 = 1.0 / (b1 + 1e-8);
      double w2 = 1.0 / (b2 + 1e-8);
      double inv = 1.0 / (w0 + w1 + w2);
      size_t o = (size_t)p * 3;
      idx_out[o + 0] = i0; idx_out[o + 1] = i1; idx_out[o + 2] = i2;
      wgt_out[o + 0] = (float)(w0 * inv);
      wgt_out[o + 1] = (float)(w1 * inv);
      wgt_out[o + 2] = (float)(w2 * inv);
    }
  }
}

// ---------------------------------------------------------------------------
// Interp gather -> featB columns 128..383 (bf16)
// ---------------------------------------------------------------------------
__global__ __launch_bounds__(256) void interp_kernel(
    const float* __restrict__ sfeatT,  // [B, NSMP, D2C]
    const int* __restrict__ idx,
    const float* __restrict__ wgt,
    unsigned short* __restrict__ featB) {
  int p = blockIdx.x;
  int c = threadIdx.x;
  int b = p >> 13;
  size_t o = (size_t)p * 3;
  int i0 = idx[o], i1 = idx[o + 1], i2 = idx[o + 2];
  float w0 = wgt[o], w1 = wgt[o + 1], w2 = wgt[o + 2];
  const float* base = sfeatT + (size_t)b * NSMP * D2C;
  float v = w0 * base[(size_t)i0 * D2C + c]
          + w1 * base[(size_t)i1 * D2C + c]
          + w2 * base[(size_t)i2 * D2C + c];
  featB[(size_t)p * CIN + D1C + c] = f2bf(v);
}

// ---------------------------------------------------------------------------
// GEMM1 (MFMA bf16, B hi/lo split): Y1 = featB @ W1^T + b1, bf16 out.
// ---------------------------------------------------------------------------
__global__ __launch_bounds__(256) void gemm1_mfma(
    const unsigned short* __restrict__ featB,  // [BN_TOTAL][CIN] bf16
    const unsigned short* __restrict__ W1h,    // [C1][CIN] bf16
    const unsigned short* __restrict__ W1l,
    const float* __restrict__ bias,
    unsigned short* __restrict__ Y1) {         // [BN_TOTAL][C1] bf16
  __shared__ unsigned short As[GM][LDA];
  __shared__ unsigned short Bh[GN][LDA];
  __shared__ unsigned short Bl[GN][LDA];
  int tid = threadIdx.x;
  int lane = tid & 63;
  int wave = tid >> 6;
  int wrow = (wave >> 1) * 64, wcol = (wave & 1) * 64;
  int m16 = lane & 15, quad = lane >> 4;
  int row0 = blockIdx.x * GM;
  int col0 = blockIdx.y * GN;

  f32x4 acc[4][4];
#pragma unroll
  for (int j = 0; j < 4; j++) {
    float bj = bias[col0 + wcol + j * 16 + m16];
#pragma unroll
    for (int i = 0; i < 4; i++) acc[i][j] = f32x4{bj, bj, bj, bj};
  }

  int ldr = tid >> 2;          // 0..63
  int seg = (tid & 3) * 8;     // 0,8,16,24

  for (int k0 = 0; k0 < CIN; k0 += GK) {
    *(s16x8*)&As[ldr][seg]      = *(const s16x8*)&featB[(size_t)(row0 + ldr) * CIN + k0 + seg];
    *(s16x8*)&As[ldr + 64][seg] = *(const s16x8*)&featB[(size_t)(row0 + ldr + 64) * CIN + k0 + seg];
    *(s16x8*)&Bh[ldr][seg]      = *(const s16x8*)&W1h[(size_t)(col0 + ldr) * CIN + k0 + seg];
    *(s16x8*)&Bh[ldr + 64][seg] = *(const s16x8*)&W1h[(size_t)(col0 + ldr + 64) * CIN + k0 + seg];
    *(s16x8*)&Bl[ldr][seg]      = *(const s16x8*)&W1l[(size_t)(col0 + ldr) * CIN + k0 + seg];
    *(s16x8*)&Bl[ldr + 64][seg] = *(const s16x8*)&W1l[(size_t)(col0 + ldr + 64) * CIN + k0 + seg];
    __syncthreads();

    bf16x8 a[4], bhf[4], blf[4];
#pragma unroll
    for (int i = 0; i < 4; i++)
      a[i] = __builtin_bit_cast(bf16x8, *(const s16x8*)&As[wrow + i * 16 + m16][quad * 8]);
#pragma unroll
    for (int j = 0; j < 4; j++) {
      bhf[j] = __builtin_bit_cast(bf16x8, *(const s16x8*)&Bh[wcol + j * 16 + m16][quad * 8]);
      blf[j] = __builtin_bit_cast(bf16x8, *(const s16x8*)&Bl[wcol + j * 16 + m16][quad * 8]);
    }
#pragma unroll
    for (int i = 0; i < 4; i++)
#pragma unroll
      for (int j = 0; j < 4; j++) {
        acc[i][j] = __builtin_amdgcn_mfma_f32_16x16x32_bf16(a[i], bhf[j], acc[i][j], 0, 0, 0);
        acc[i][j] = __builtin_amdgcn_mfma_f32_16x16x32_bf16(a[i], blf[j], acc[i][j], 0, 0, 0);
      }
    __syncthreads();
  }

#pragma unroll
  for (int i = 0; i < 4; i++)
#pragma unroll
    for (int j = 0; j < 4; j++) {
      int col = col0 + wcol + j * 16 + m16;
#pragma unroll
      for (int r = 0; r < 4; r++) {
        int row = row0 + wrow + i * 16 + quad * 4 + r;
        Y1[(size_t)row * C1 + col] = f2bf(acc[i][j][r]);
      }
    }
}

// ---------------------------------------------------------------------------
// GEMM2 (MFMA bf16): X2 = relu(bn1(Y1)) fused in staging; Y2 = X2 @ W2^T + b2.
// ---------------------------------------------------------------------------
__global__ __launch_bounds__(256) void gemm2_mfma(
    const unsigned short* __restrict__ Y1,   // [BN_TOTAL][C1] bf16
    const float* __restrict__ scale1, const float* __restrict__ shift1,
    const unsigned short* __restrict__ W2h,  // [C2][C1] bf16
    const unsigned short* __restrict__ W2l,
    const float* __restrict__ bias,
    unsigned short* __restrict__ Y2) {       // [BN_TOTAL][C2] bf16
  __shared__ unsigned short As[GM][LDA];
  __shared__ unsigned short Bh[GN][LDA];
  __shared__ unsigned short Bl[GN][LDA];
  __shared__ float scs[C1], shs[C1];
  int tid = threadIdx.x;
  int lane = tid & 63;
  int wave = tid >> 6;
  int wrow = (wave >> 1) * 64, wcol = (wave & 1) * 64;
  int m16 = lane & 15, quad = lane >> 4;
  int row0 = blockIdx.x * GM;

  scs[tid] = scale1[tid];
  shs[tid] = shift1[tid];

  f32x4 acc[4][4];
#pragma unroll
  for (int j = 0; j < 4; j++) {
    float bj = bias[wcol + j * 16 + m16];
#pragma unroll
    for (int i = 0; i < 4; i++) acc[i][j] = f32x4{bj, bj, bj, bj};
  }

  int ldr = tid >> 2;
  int seg = (tid & 3) * 8;
  __syncthreads();  // scs/shs visible

  for (int k0 = 0; k0 < C1; k0 += GK) {
#pragma unroll
    for (int rr = 0; rr < 2; rr++) {
      int r = ldr + rr * 64;
      s16x8 v = *(const s16x8*)&Y1[(size_t)(row0 + r) * C1 + k0 + seg];
      unsigned short ov[8];
#pragma unroll
      for (int e = 0; e < 8; e++) {
        float x = bf2f((unsigned short)v[e]);
        float y = fmaxf(fmaf(x, scs[k0 + seg + e], shs[k0 + seg + e]), 0.f);
        ov[e] = f2bf(y);
      }
      *(s16x8*)&As[r][seg] = *(const s16x8*)ov;
    }
    *(s16x8*)&Bh[ldr][seg]      = *(const s16x8*)&W2h[(size_t)ldr * C1 + k0 + seg];
    *(s16x8*)&Bh[ldr + 64][seg] = *(const s16x8*)&W2h[(size_t)(ldr + 64) * C1 + k0 + seg];
    *(s16x8*)&Bl[ldr][seg]      = *(const s16x8*)&W2l[(size_t)ldr * C1 + k0 + seg];
    *(s16x8*)&Bl[ldr + 64][seg] = *(const s16x8*)&W2l[(size_t)(ldr + 64) * C1 + k0 + seg];
    __syncthreads();

    bf16x8 a[4], bhf[4], blf[4];
#pragma unroll
    for (int i = 0; i < 4; i++)
      a[i] = __builtin_bit_cast(bf16x8, *(const s16x8*)&As[wrow + i * 16 + m16][quad * 8]);
#pragma unroll
    for (int j = 0; j < 4; j++) {
      bhf[j] = __builtin_bit_cast(bf16x8, *(const s16x8*)&Bh[wcol + j * 16 + m16][quad * 8]);
      blf[j] = __builtin_bit_cast(bf16x8, *(const s16x8*)&Bl[wcol + j * 16 + m16][quad * 8]);
    }
#pragma unroll
    for (int i = 0; i < 4; i++)
#pragma unroll
      for (int j = 0; j < 4; j++) {
        acc[i][j] = __builtin_amdgcn_mfma_f32_16x16x32_bf16(a[i], bhf[j], acc[i][j], 0, 0, 0);
        acc[i][j] = __builtin_amdgcn_mfma_f32_16x16x32_bf16(a[i], blf[j], acc[i][j], 0, 0, 0);
      }
    __syncthreads();
  }

#pragma unroll
  for (int i = 0; i < 4; i++)
#pragma unroll
    for (int j = 0; j < 4; j++) {
      int col = wcol + j * 16 + m16;
#pragma unroll
      for (int r = 0; r < 4; r++) {
        int row = row0 + wrow + i * 16 + quad * 4 + r;
        Y2[(size_t)row * C2 + col] = f2bf(acc[i][j][r]);
      }
    }
}

// ---------------------------------------------------------------------------
// Per-channel sum / sumsq over rows (bf16 input).
// ---------------------------------------------------------------------------
__global__ void stats_bf16(const unsigned short* __restrict__ Y,
                           float* __restrict__ sum, float* __restrict__ sumsq,
                           int C, int rowsPer) {
  int c = threadIdx.x;
  size_t r0 = (size_t)blockIdx.x * rowsPer;
  float s = 0.f, s2 = 0.f;
  for (int r = 0; r < rowsPer; r++) {
    float v = bf2f(Y[(r0 + r) * C + c]);
    s += v;
    s2 += v * v;
  }
  atomicAdd(&sum[c], s);
  atomicAdd(&sumsq[c], s2);
}

__global__ void bn_coef_kernel(const float* __restrict__ sum, const float* __restrict__ sumsq,
                               const float* __restrict__ g, const float* __restrict__ beta,
                               float* __restrict__ scale, float* __restrict__ shift, int C) {
  int c = threadIdx.x + blockIdx.x * blockDim.x;
  if (c >= C) return;
  const float invBN = 1.0f / (float)BN_TOTAL;
  float m = sum[c] * invBN;
  float var = sumsq[c] * invBN - m * m;
  float sc = g[c] / sqrtf(var + 1e-5f);
  scale[c] = sc;
  shift[c] = beta[c] - m * sc;
}

// ---------------------------------------------------------------------------
// Final: out[b][c][n] = relu(bn2(Y2)) transposed, fp32 out.
// ---------------------------------------------------------------------------
__global__ void final_kernel(const unsigned short* __restrict__ Y2,
                             const float* __restrict__ scale, const float* __restrict__ shift,
                             float* __restrict__ out) {
  __shared__ float tile[32][33];
  int b = blockIdx.z;
  int n0 = blockIdx.x * 32;
  int c0 = blockIdx.y * 32;
  int tx = threadIdx.x, ty = threadIdx.y;
  float sc = scale[c0 + tx];
  float sh = shift[c0 + tx];
#pragma unroll
  for (int i = 0; i < 32; i += 8) {
    int n = n0 + ty + i;
    float v = bf2f(Y2[((size_t)b * NPT + n) * C2 + c0 + tx]);
    tile[ty + i][tx] = fmaxf(fmaf(v, sc, sh), 0.f);
  }
  __syncthreads();
#pragma unroll
  for (int i = 0; i < 32; i += 8) {
    int c = c0 + ty + i;
    out[((size_t)b * C2 + c) * NPT + n0 + tx] = tile[tx][ty + i];
  }
}

// ---------------------------------------------------------------------------
extern "C" void kernel_launch(void* const* d_in, const int* in_sizes, int n_in,
                              void* d_out, int out_size, void* d_ws, size_t ws_size,
                              hipStream_t stream) {
  (void)in_sizes; (void)n_in; (void)out_size; (void)ws_size;
  const float* pos   = (const float*)d_in[0];
  const float* spos  = (const float*)d_in[1];
  const float* skip  = (const float*)d_in[2];
  const float* sfeat = (const float*)d_in[3];
  const float* W1    = (const float*)d_in[4];
  const float* b1    = (const float*)d_in[5];
  const float* g1    = (const float*)d_in[6];
  const float* beta1 = (const float*)d_in[7];
  const float* W2    = (const float*)d_in[8];
  const float* b2    = (const float*)d_in[9];
  const float* g2    = (const float*)d_in[10];
  const float* beta2 = (const float*)d_in[11];
  float* out = (float*)d_out;

  float* ws = (float*)d_ws;
  size_t off = 0;
  float* sfeatT  = ws + off; off += (size_t)BATCH * NSMP * D2C;        // 4,194,304
  unsigned short* featB = (unsigned short*)(ws + off); off += (size_t)BN_TOTAL * CIN / 2;
  unsigned short* Y1    = (unsigned short*)(ws + off); off += (size_t)BN_TOTAL * C1 / 2;
  unsigned short* Y2    = (unsigned short*)(ws + off); off += (size_t)BN_TOTAL * C2 / 2;
  unsigned short* W1h   = (unsigned short*)(ws + off); off += (size_t)C1 * CIN / 2;
  unsigned short* W1l   = (unsigned short*)(ws + off); off += (size_t)C1 * CIN / 2;
  unsigned short* W2h   = (unsigned short*)(ws + off); off += (size_t)C2 * C1 / 2;
  unsigned short* W2l   = (unsigned short*)(ws + off); off += (size_t)C2 * C1 / 2;
  int*   knn_idx = (int*)(ws + off); off += (size_t)BN_TOTAL * 3;
  float* knn_w   = ws + off; off += (size_t)BN_TOTAL * 3;
  float* sposI   = ws + off; off += (size_t)BATCH * NSMP * 3;
  int* flag_list = (int*)(ws + off); off += (size_t)BN_TOTAL;
  float* stats   = ws + off; off += 2048;
  float* sum1 = stats, *sumsq1 = stats + 256;
  float* sum2 = stats + 512, *sumsq2 = stats + 640;
  int*   flag_count = (int*)(stats + 768);
  float* scale1 = stats + 1024, *shift1 = stats + 1280;
  float* scale2 = stats + 1536, *shift2 = stats + 1664;

  hipMemsetAsync(stats, 0, 772 * sizeof(float), stream);

  dim3 tb(32, 8);
  transpose_k<<<dim3(NSMP / 32, D2C / 32, BATCH), tb, 0, stream>>>(
      sfeat, sfeatT, D2C, NSMP, (long)D2C * NSMP, (long)NSMP * D2C);
  wprep<<<(C1 * CIN + 255) / 256, 256, 0, stream>>>(W1, W1h, W1l, C1 * CIN);
  wprep<<<(C2 * C1 + 255) / 256, 256, 0, stream>>>(W2, W2h, W2l, C2 * C1);
  skip_to_featB<<<dim3(NPT / 32, D1C / 32, BATCH), tb, 0, stream>>>(skip, featB);

  pack_spos<<<BATCH * NSMP / 256, 256, 0, stream>>>(spos, sposI);
  knn_kernel<<<BN_TOTAL / 64, 256, 0, stream>>>(pos, sposI, knn_idx, knn_w,
                                                flag_list, flag_count);
  knn_fallback<<<256, 256, 0, stream>>>(pos, sposI, flag_list, flag_count,
                                        knn_idx, knn_w);
  interp_kernel<<<BN_TOTAL, 256, 0, stream>>>(sfeatT, knn_idx, knn_w, featB);

  gemm1_mfma<<<dim3(BN_TOTAL / GM, C1 / GN), 256, 0, stream>>>(featB, W1h, W1l, b1, Y1);
  stats_bf16<<<256, C1, 0, stream>>>(Y1, sum1, sumsq1, C1, BN_TOTAL / 256);
  bn_coef_kernel<<<1, C1, 0, stream>>>(sum1, sumsq1, g1, beta1, scale1, shift1, C1);

  gemm2_mfma<<<dim3(BN_TOTAL / GM, 1), 256, 0, stream>>>(Y1, scale1, shift1, W2h, W2l, b2, Y2);
  stats_bf16<<<256, C2, 0, stream>>>(Y2, sum2, sumsq2, C2, BN_TOTAL / 256);
  bn_coef_kernel<<<1, C2, 0, stream>>>(sum2, sumsq2, g2, beta2, scale2, shift2, C2);

  final_kernel<<<dim3(NPT / 32, C2 / 32, BATCH), tb, 0, stream>>>(Y2, scale2, shift2, out);
}

// Round 5
// 355.146 us; speedup vs baseline: 1.9968x; 1.2074x over previous
//
#include <hip/hip_runtime.h>

// Problem constants
constexpr int BATCH = 8;
constexpr int NPT   = 8192;   // N points
constexpr int NSMP  = 2048;   // S sampled points
constexpr int D1C   = 128;    // skip feature channels
constexpr int D2C   = 256;    // sampled feature channels
constexpr int CIN   = 384;    // D1C + D2C
constexpr int C1    = 256;    // layer-1 out channels
constexpr int C2    = 128;    // layer-2 out channels
constexpr int BN_TOTAL = BATCH * NPT;  // 65536 rows

// MFMA GEMM tiling
constexpr int GM = 128, GN = 128, GK = 32;
constexpr int LDA = GK + 8;   // 40 shorts -> 80 B row stride

typedef __bf16 bf16x8 __attribute__((ext_vector_type(8)));
typedef short  s16x8  __attribute__((ext_vector_type(8)));
typedef float  f32x4  __attribute__((ext_vector_type(4)));

__device__ __forceinline__ unsigned short f2bf(float x) {
  unsigned u = __builtin_bit_cast(unsigned, x);
  u += 0x7fffu + ((u >> 16) & 1u);   // round-to-nearest-even
  return (unsigned short)(u >> 16);
}
__device__ __forceinline__ float bf2f(unsigned short h) {
  return __builtin_bit_cast(float, (unsigned)h << 16);
}

// ---------------------------------------------------------------------------
// 32x32 tiled transpose (fp32)
// ---------------------------------------------------------------------------
__global__ void transpose_k(const float* __restrict__ in, float* __restrict__ out,
                            int rows, int cols, long inBatch, long outBatch) {
  __shared__ float tile[32][33];
  const float* inb = in + (size_t)blockIdx.z * inBatch;
  float* outb = out + (size_t)blockIdx.z * outBatch;
  int c0 = blockIdx.x * 32;
  int r0 = blockIdx.y * 32;
  int tx = threadIdx.x, ty = threadIdx.y;
#pragma unroll
  for (int i = 0; i < 32; i += 8) {
    int r = r0 + ty + i;
    tile[ty + i][tx] = inb[(size_t)r * cols + c0 + tx];
  }
  __syncthreads();
#pragma unroll
  for (int i = 0; i < 32; i += 8) {
    int c = c0 + ty + i;
    outb[(size_t)c * rows + r0 + tx] = tile[tx][ty + i];
  }
}

// ---------------------------------------------------------------------------
// skip [B, D1C, NPT] fp32 -> featB[b*NPT+n][d] bf16 (columns 0..127)
// ---------------------------------------------------------------------------
__global__ void skip_to_featB(const float* __restrict__ skip,
                              unsigned short* __restrict__ featB) {
  __shared__ float tile[32][33];
  int b = blockIdx.z;
  int n0 = blockIdx.x * 32;
  int d0 = blockIdx.y * 32;
  int tx = threadIdx.x, ty = threadIdx.y;
#pragma unroll
  for (int i = 0; i < 32; i += 8) {
    tile[ty + i][tx] = skip[((size_t)b * D1C + d0 + ty + i) * NPT + n0 + tx];
  }
  __syncthreads();
#pragma unroll
  for (int i = 0; i < 32; i += 8) {
    int n = n0 + ty + i;
    featB[((size_t)b * NPT + n) * CIN + d0 + tx] = f2bf(tile[tx][ty + i]);
  }
}

// ---------------------------------------------------------------------------
// Weight prep: W fp32 -> hi/lo bf16 pair
// ---------------------------------------------------------------------------
__global__ void wprep(const float* __restrict__ W, unsigned short* __restrict__ Wh,
                      unsigned short* __restrict__ Wl, int total) {
  int i = blockIdx.x * 256 + threadIdx.x;
  if (i >= total) return;
  float w = W[i];
  unsigned short h = f2bf(w);
  Wh[i] = h;
  Wl[i] = f2bf(w - bf2f(h));
}

// ---------------------------------------------------------------------------
// Pack spos [B,3,NSMP] -> xyz-interleaved sposI [B,NSMP,3]
// ---------------------------------------------------------------------------
__global__ void pack_spos(const float* __restrict__ spos, float* __restrict__ sposI) {
  int g = blockIdx.x * 256 + threadIdx.x;  // B*NSMP = 16384
  int b = g >> 11, s = g & (NSMP - 1);
  const float* sp = spos + (size_t)b * 3 * NSMP;
  sposI[(size_t)g * 3 + 0] = sp[s];
  sposI[(size_t)g * 3 + 1] = sp[NSMP + s];
  sposI[(size_t)g * 3 + 2] = sp[2 * NSMP + s];
}

// ---------------------------------------------------------------------------
// kNN with packed keys (idx in low 11 bits of fp32 distance); 7-op sort-4.
// ---------------------------------------------------------------------------
constexpr int SEG = NSMP / 4;  // 512

__global__ __launch_bounds__(256) void knn_kernel(
    const float* __restrict__ pos,    // [B,3,NPT]
    const float* __restrict__ sposI,  // [B,NSMP,3] interleaved
    int* __restrict__ idx_out,        // [BN_TOTAL,3]
    float* __restrict__ wgt_out,      // [BN_TOTAL,3]
    int* __restrict__ flag_list,
    int* __restrict__ flag_count) {
  __shared__ float qs[3 * NSMP];   // 24 KB
  __shared__ float mk[4][4][64];   // per-wave sorted top-4 keys

  int tid = threadIdx.x;
  int wave = tid >> 6, lane = tid & 63;
  int blk = blockIdx.x;
  int b = blk >> 7;
  int n = ((blk & 127) << 6) + lane;

  const float4* src = (const float4*)(sposI + (size_t)b * 3 * NSMP);
  float4* dst = (float4*)qs;
  for (int t = tid; t < 3 * NSMP / 4; t += 256) dst[t] = src[t];
  __syncthreads();

  const float* pb = pos + (size_t)b * 3 * NPT;
  float px = pb[n], py = pb[NPT + n], pz = pb[2 * NPT + n];

  const float INF = __builtin_inff();
  float k0 = INF, k1 = INF, k2 = INF, k3 = INF;

  const float4* q4 = (const float4*)qs;
  int s0 = wave * SEG;

#define KNN_STEP(QX, QY, QZ, SS)                                          \
  {                                                                       \
    float dx = px - (QX), dy = py - (QY), dz = pz - (QZ);                 \
    float d = fmaf(dx, dx, fmaf(dy, dy, dz * dz));                        \
    unsigned ki = (__builtin_bit_cast(unsigned, d) & 0xFFFFF800u) |       \
                  (unsigned)(SS);                                         \
    float kf = __builtin_bit_cast(float, ki);                             \
    float v1 = fmaxf(kf, k0); k0 = fminf(kf, k0);                         \
    float v2 = fmaxf(v1, k1); k1 = fminf(v1, k1);                         \
    float v3 = fmaxf(v2, k2); k2 = fminf(v2, k2);                         \
    k3 = fminf(v3, k3);                                                   \
  }

  for (int t = 0; t < SEG; t += 4) {
    int s = s0 + t;
    int u = 3 * (s >> 2);
    float4 qa = q4[u], qb = q4[u + 1], qc = q4[u + 2];
    KNN_STEP(qa.x, qa.y, qa.z, s + 0)
    KNN_STEP(qa.w, qb.x, qb.y, s + 1)
    KNN_STEP(qb.z, qb.w, qc.x, s + 2)
    KNN_STEP(qc.y, qc.z, qc.w, s + 3)
  }
#undef KNN_STEP

  mk[wave][0][lane] = k0; mk[wave][1][lane] = k1;
  mk[wave][2][lane] = k2; mk[wave][3][lane] = k3;
  __syncthreads();

  if (tid < 64) {
    float K0 = INF, K1 = INF, K2 = INF, K3 = INF;
#pragma unroll
    for (int w = 0; w < 4; w++) {
#pragma unroll
      for (int sl = 0; sl < 4; sl++) {
        float kf = mk[w][sl][tid];
        float v1 = fmaxf(kf, K0); K0 = fminf(kf, K0);
        float v2 = fmaxf(v1, K1); K1 = fminf(v1, K1);
        float v3 = fmaxf(v2, K2); K2 = fminf(v2, K2);
        K3 = fminf(v3, K3);
      }
    }
    int p = blk * 64 + tid;
    int I0 = (int)(__builtin_bit_cast(unsigned, K0) & 0x7FFu);
    int I1 = (int)(__builtin_bit_cast(unsigned, K1) & 0x7FFu);
    int I2 = (int)(__builtin_bit_cast(unsigned, K2) & 0x7FFu);
    float d2m = __builtin_bit_cast(float, __builtin_bit_cast(unsigned, K2) & 0xFFFFF800u);
    float d3m = __builtin_bit_cast(float, __builtin_bit_cast(unsigned, K3) & 0xFFFFF800u);
    bool flag = (d3m - d2m) < 2e-3f * d3m + 1e-7f;
    if (flag) {
      int slot = atomicAdd(flag_count, 1);
      flag_list[slot] = p;
    }
    const float* q = sposI + (size_t)b * 3 * NSMP;
    double pxd = (double)px, pyd = (double)py, pzd = (double)pz;
    double dd[3]; int II[3] = {I0, I1, I2};
#pragma unroll
    for (int k = 0; k < 3; k++) {
      double dx = pxd - (double)q[3 * II[k]];
      double dy = pyd - (double)q[3 * II[k] + 1];
      double dz = pzd - (double)q[3 * II[k] + 2];
      dd[k] = dx * dx + dy * dy + dz * dz;
    }
    double w0 = 1.0 / (dd[0] + 1e-8);
    double w1 = 1.0 / (dd[1] + 1e-8);
    double w2 = 1.0 / (dd[2] + 1e-8);
    double inv = 1.0 / (w0 + w1 + w2);
    size_t o = (size_t)p * 3;
    idx_out[o + 0] = I0; idx_out[o + 1] = I1; idx_out[o + 2] = I2;
    wgt_out[o + 0] = (float)(w0 * inv);
    wgt_out[o + 1] = (float)(w1 * inv);
    wgt_out[o + 2] = (float)(w2 * inv);
  }
}

// ---------------------------------------------------------------------------
// Exact fp64 fallback, wave-parallel.
// ---------------------------------------------------------------------------
__device__ __forceinline__ bool dless(double d, int i, double D, int I) {
  return d < D || (d == D && i < I);
}
__device__ __forceinline__ void dins3(double d, int i,
                                      double& b0, double& b1, double& b2,
                                      int& i0, int& i1, int& i2) {
  if (dless(d, i, b2, i2)) {
    if (dless(d, i, b1, i1)) {
      b2 = b1; i2 = i1;
      if (dless(d, i, b0, i0)) { b1 = b0; i1 = i0; b0 = d; i0 = i; }
      else                     { b1 = d; i1 = i; }
    } else { b2 = d; i2 = i; }
  }
}

__global__ __launch_bounds__(256) void knn_fallback(
    const float* __restrict__ pos, const float* __restrict__ sposI,
    const int* __restrict__ flag_list, const int* __restrict__ flag_count,
    int* __restrict__ idx_out, float* __restrict__ wgt_out) {
  int wave = threadIdx.x >> 6, lane = threadIdx.x & 63;
  int gw = blockIdx.x * 4 + wave;
  int cnt = *flag_count;
  for (int t = gw; t < cnt; t += 1024) {
    int p = flag_list[t];
    int b = p >> 13, n = p & (NPT - 1);
    const float* pb = pos + (size_t)b * 3 * NPT;
    double px = (double)pb[n], py = (double)pb[NPT + n], pz = (double)pb[2 * NPT + n];
    const float* q = sposI + (size_t)b * 3 * NSMP;
    double b0 = 1e300, b1 = 1e300, b2 = 1e300;
    int i0 = 0x7FFFFFFF, i1 = 0x7FFFFFFF, i2 = 0x7FFFFFFF;
    for (int s = lane; s < NSMP; s += 64) {
      double dx = px - (double)q[3 * s];
      double dy = py - (double)q[3 * s + 1];
      double dz = pz - (double)q[3 * s + 2];
      double d = dx * dx + dy * dy + dz * dz;
      dins3(d, s, b0, b1, b2, i0, i1, i2);
    }
#pragma unroll
    for (int m = 1; m < 64; m <<= 1) {
      double o0 = __shfl_xor(b0, m, 64), o1 = __shfl_xor(b1, m, 64), o2 = __shfl_xor(b2, m, 64);
      int    j0 = __shfl_xor(i0, m, 64), j1 = __shfl_xor(i1, m, 64), j2 = __shfl_xor(i2, m, 64);
      dins3(o0, j0, b0, b1, b2, i0, i1, i2);
      dins3(o1, j1, b0, b1, b2, i0, i1, i2);
      dins3(o2, j2, b0, b1, b2, i0, i1, i2);
    }
    if (lane == 0) {
      double w0 = 1.0 / (b0 + 1e-8);
      double w1 = 1.0 / (b1 + 1e-8);
      double w2 = 1.0 / (b2 + 1e-8);
      double inv = 1.0 / (w0 + w1 + w2);
      size_t o = (size_t)p * 3;
      idx_out[o + 0] = i0; idx_out[o + 1] = i1; idx_out[o + 2] = i2;
      wgt_out[o + 0] = (float)(w0 * inv);
      wgt_out[o + 1] = (float)(w1 * inv);
      wgt_out[o + 2] = (float)(w2 * inv);
    }
  }
}

// ---------------------------------------------------------------------------
// Interp gather -> featB columns 128..383 (bf16)
// ---------------------------------------------------------------------------
__global__ __launch_bounds__(256) void interp_kernel(
    const float* __restrict__ sfeatT,  // [B, NSMP, D2C]
    const int* __restrict__ idx,
    const float* __restrict__ wgt,
    unsigned short* __restrict__ featB) {
  int p = blockIdx.x;
  int c = threadIdx.x;
  int b = p >> 13;
  size_t o = (size_t)p * 3;
  int i0 = idx[o], i1 = idx[o + 1], i2 = idx[o + 2];
  float w0 = wgt[o], w1 = wgt[o + 1], w2 = wgt[o + 2];
  const float* base = sfeatT + (size_t)b * NSMP * D2C;
  float v = w0 * base[(size_t)i0 * D2C + c]
          + w1 * base[(size_t)i1 * D2C + c]
          + w2 * base[(size_t)i2 * D2C + c];
  featB[(size_t)p * CIN + D1C + c] = f2bf(v);
}

// ---------------------------------------------------------------------------
// GEMM1 (MFMA bf16, B hi/lo split) with fused per-channel stats:
// Y1 = featB @ W1^T + b1 (bf16 out); sum/sumsq accumulated from fp32 acc.
// ---------------------------------------------------------------------------
__global__ __launch_bounds__(256) void gemm1_mfma(
    const unsigned short* __restrict__ featB,  // [BN_TOTAL][CIN] bf16
    const unsigned short* __restrict__ W1h,    // [C1][CIN] bf16
    const unsigned short* __restrict__ W1l,
    const float* __restrict__ bias,
    unsigned short* __restrict__ Y1,           // [BN_TOTAL][C1] bf16
    float* __restrict__ sum, float* __restrict__ sumsq) {
  __shared__ unsigned short As[GM][LDA];
  __shared__ unsigned short Bh[GN][LDA];
  __shared__ unsigned short Bl[GN][LDA];
  int tid = threadIdx.x;
  int lane = tid & 63;
  int wave = tid >> 6;
  int wrow = (wave >> 1) * 64, wcol = (wave & 1) * 64;
  int m16 = lane & 15, quad = lane >> 4;
  int row0 = blockIdx.x * GM;
  int col0 = blockIdx.y * GN;

  f32x4 acc[4][4];
#pragma unroll
  for (int j = 0; j < 4; j++) {
    float bj = bias[col0 + wcol + j * 16 + m16];
#pragma unroll
    for (int i = 0; i < 4; i++) acc[i][j] = f32x4{bj, bj, bj, bj};
  }

  int ldr = tid >> 2;          // 0..63
  int seg = (tid & 3) * 8;     // 0,8,16,24

  for (int k0 = 0; k0 < CIN; k0 += GK) {
    *(s16x8*)&As[ldr][seg]      = *(const s16x8*)&featB[(size_t)(row0 + ldr) * CIN + k0 + seg];
    *(s16x8*)&As[ldr + 64][seg] = *(const s16x8*)&featB[(size_t)(row0 + ldr + 64) * CIN + k0 + seg];
    *(s16x8*)&Bh[ldr][seg]      = *(const s16x8*)&W1h[(size_t)(col0 + ldr) * CIN + k0 + seg];
    *(s16x8*)&Bh[ldr + 64][seg] = *(const s16x8*)&W1h[(size_t)(col0 + ldr + 64) * CIN + k0 + seg];
    *(s16x8*)&Bl[ldr][seg]      = *(const s16x8*)&W1l[(size_t)(col0 + ldr) * CIN + k0 + seg];
    *(s16x8*)&Bl[ldr + 64][seg] = *(const s16x8*)&W1l[(size_t)(col0 + ldr + 64) * CIN + k0 + seg];
    __syncthreads();

    bf16x8 a[4], bhf[4], blf[4];
#pragma unroll
    for (int i = 0; i < 4; i++)
      a[i] = __builtin_bit_cast(bf16x8, *(const s16x8*)&As[wrow + i * 16 + m16][quad * 8]);
#pragma unroll
    for (int j = 0; j < 4; j++) {
      bhf[j] = __builtin_bit_cast(bf16x8, *(const s16x8*)&Bh[wcol + j * 16 + m16][quad * 8]);
      blf[j] = __builtin_bit_cast(bf16x8, *(const s16x8*)&Bl[wcol + j * 16 + m16][quad * 8]);
    }
#pragma unroll
    for (int i = 0; i < 4; i++)
#pragma unroll
      for (int j = 0; j < 4; j++) {
        acc[i][j] = __builtin_amdgcn_mfma_f32_16x16x32_bf16(a[i], bhf[j], acc[i][j], 0, 0, 0);
        acc[i][j] = __builtin_amdgcn_mfma_f32_16x16x32_bf16(a[i], blf[j], acc[i][j], 0, 0, 0);
      }
    __syncthreads();
  }

#pragma unroll
  for (int i = 0; i < 4; i++)
#pragma unroll
    for (int j = 0; j < 4; j++) {
      int col = col0 + wcol + j * 16 + m16;
#pragma unroll
      for (int r = 0; r < 4; r++) {
        int row = row0 + wrow + i * 16 + quad * 4 + r;
        Y1[(size_t)row * C1 + col] = f2bf(acc[i][j][r]);
      }
    }

  // fused per-channel stats: column sums of this 128-row tile
#pragma unroll
  for (int j = 0; j < 4; j++) {
    float s = 0.f, q = 0.f;
#pragma unroll
    for (int i = 0; i < 4; i++)
#pragma unroll
      for (int r = 0; r < 4; r++) {
        float v = acc[i][j][r];
        s += v; q = fmaf(v, v, q);
      }
    s += __shfl_xor(s, 16, 64); s += __shfl_xor(s, 32, 64);
    q += __shfl_xor(q, 16, 64); q += __shfl_xor(q, 32, 64);
    if (quad == 0) {
      int col = col0 + wcol + j * 16 + m16;
      atomicAdd(&sum[col], s);
      atomicAdd(&sumsq[col], q);
    }
  }
}

// ---------------------------------------------------------------------------
// GEMM2 (MFMA bf16) with fused BN1+ReLU staging and fused layer-2 stats.
// ---------------------------------------------------------------------------
__global__ __launch_bounds__(256) void gemm2_mfma(
    const unsigned short* __restrict__ Y1,   // [BN_TOTAL][C1] bf16
    const float* __restrict__ scale1, const float* __restrict__ shift1,
    const unsigned short* __restrict__ W2h,  // [C2][C1] bf16
    const unsigned short* __restrict__ W2l,
    const float* __restrict__ bias,
    unsigned short* __restrict__ Y2,         // [BN_TOTAL][C2] bf16
    float* __restrict__ sum, float* __restrict__ sumsq) {
  __shared__ unsigned short As[GM][LDA];
  __shared__ unsigned short Bh[GN][LDA];
  __shared__ unsigned short Bl[GN][LDA];
  __shared__ float scs[C1], shs[C1];
  int tid = threadIdx.x;
  int lane = tid & 63;
  int wave = tid >> 6;
  int wrow = (wave >> 1) * 64, wcol = (wave & 1) * 64;
  int m16 = lane & 15, quad = lane >> 4;
  int row0 = blockIdx.x * GM;

  scs[tid] = scale1[tid];
  shs[tid] = shift1[tid];

  f32x4 acc[4][4];
#pragma unroll
  for (int j = 0; j < 4; j++) {
    float bj = bias[wcol + j * 16 + m16];
#pragma unroll
    for (int i = 0; i < 4; i++) acc[i][j] = f32x4{bj, bj, bj, bj};
  }

  int ldr = tid >> 2;
  int seg = (tid & 3) * 8;
  __syncthreads();  // scs/shs visible

  for (int k0 = 0; k0 < C1; k0 += GK) {
#pragma unroll
    for (int rr = 0; rr < 2; rr++) {
      int r = ldr + rr * 64;
      s16x8 v = *(const s16x8*)&Y1[(size_t)(row0 + r) * C1 + k0 + seg];
      unsigned short ov[8];
#pragma unroll
      for (int e = 0; e < 8; e++) {
        float x = bf2f((unsigned short)v[e]);
        float y = fmaxf(fmaf(x, scs[k0 + seg + e], shs[k0 + seg + e]), 0.f);
        ov[e] = f2bf(y);
      }
      *(s16x8*)&As[r][seg] = *(const s16x8*)ov;
    }
    *(s16x8*)&Bh[ldr][seg]      = *(const s16x8*)&W2h[(size_t)ldr * C1 + k0 + seg];
    *(s16x8*)&Bh[ldr + 64][seg] = *(const s16x8*)&W2h[(size_t)(ldr + 64) * C1 + k0 + seg];
    *(s16x8*)&Bl[ldr][seg]      = *(const s16x8*)&W2l[(size_t)ldr * C1 + k0 + seg];
    *(s16x8*)&Bl[ldr + 64][seg] = *(const s16x8*)&W2l[(size_t)(ldr + 64) * C1 + k0 + seg];
    __syncthreads();

    bf16x8 a[4], bhf[4], blf[4];
#pragma unroll
    for (int i = 0; i < 4; i++)
      a[i] = __builtin_bit_cast(bf16x8, *(const s16x8*)&As[wrow + i * 16 + m16][quad * 8]);
#pragma unroll
    for (int j = 0; j < 4; j++) {
      bhf[j] = __builtin_bit_cast(bf16x8, *(const s16x8*)&Bh[wcol + j * 16 + m16][quad * 8]);
      blf[j] = __builtin_bit_cast(bf16x8, *(const s16x8*)&Bl[wcol + j * 16 + m16][quad * 8]);
    }
#pragma unroll
    for (int i = 0; i < 4; i++)
#pragma unroll
      for (int j = 0; j < 4; j++) {
        acc[i][j] = __builtin_amdgcn_mfma_f32_16x16x32_bf16(a[i], bhf[j], acc[i][j], 0, 0, 0);
        acc[i][j] = __builtin_amdgcn_mfma_f32_16x16x32_bf16(a[i], blf[j], acc[i][j], 0, 0, 0);
      }
    __syncthreads();
  }

#pragma unroll
  for (int i = 0; i < 4; i++)
#pragma unroll
    for (int j = 0; j < 4; j++) {
      int col = wcol + j * 16 + m16;
#pragma unroll
      for (int r = 0; r < 4; r++) {
        int row = row0 + wrow + i * 16 + quad * 4 + r;
        Y2[(size_t)row * C2 + col] = f2bf(acc[i][j][r]);
      }
    }

  // fused per-channel stats
#pragma unroll
  for (int j = 0; j < 4; j++) {
    float s = 0.f, q = 0.f;
#pragma unroll
    for (int i = 0; i < 4; i++)
#pragma unroll
      for (int r = 0; r < 4; r++) {
        float v = acc[i][j][r];
        s += v; q = fmaf(v, v, q);
      }
    s += __shfl_xor(s, 16, 64); s += __shfl_xor(s, 32, 64);
    q += __shfl_xor(q, 16, 64); q += __shfl_xor(q, 32, 64);
    if (quad == 0) {
      int col = wcol + j * 16 + m16;
      atomicAdd(&sum[col], s);
      atomicAdd(&sumsq[col], q);
    }
  }
}

// ---------------------------------------------------------------------------
__global__ void bn_coef_kernel(const float* __restrict__ sum, const float* __restrict__ sumsq,
                               const float* __restrict__ g, const float* __restrict__ beta,
                               float* __restrict__ scale, float* __restrict__ shift, int C) {
  int c = threadIdx.x + blockIdx.x * blockDim.x;
  if (c >= C) return;
  const float invBN = 1.0f / (float)BN_TOTAL;
  float m = sum[c] * invBN;
  float var = sumsq[c] * invBN - m * m;
  float sc = g[c] / sqrtf(var + 1e-5f);
  scale[c] = sc;
  shift[c] = beta[c] - m * sc;
}

// ---------------------------------------------------------------------------
// Final: out[b][c][n] = relu(bn2(Y2)) transposed, fp32 out.
// ---------------------------------------------------------------------------
__global__ void final_kernel(const unsigned short* __restrict__ Y2,
                             const float* __restrict__ scale, const float* __restrict__ shift,
                             float* __restrict__ out) {
  __shared__ float tile[32][33];
  int b = blockIdx.z;
  int n0 = blockIdx.x * 32;
  int c0 = blockIdx.y * 32;
  int tx = threadIdx.x, ty = threadIdx.y;
  float sc = scale[c0 + tx];
  float sh = shift[c0 + tx];
#pragma unroll
  for (int i = 0; i < 32; i += 8) {
    int n = n0 + ty + i;
    float v = bf2f(Y2[((size_t)b * NPT + n) * C2 + c0 + tx]);
    tile[ty + i][tx] = fmaxf(fmaf(v, sc, sh), 0.f);
  }
  __syncthreads();
#pragma unroll
  for (int i = 0; i < 32; i += 8) {
    int c = c0 + ty + i;
    out[((size_t)b * C2 + c) * NPT + n0 + tx] = tile[tx][ty + i];
  }
}

// ---------------------------------------------------------------------------
extern "C" void kernel_launch(void* const* d_in, const int* in_sizes, int n_in,
                              void* d_out, int out_size, void* d_ws, size_t ws_size,
                              hipStream_t stream) {
  (void)in_sizes; (void)n_in; (void)out_size; (void)ws_size;
  const float* pos   = (const float*)d_in[0];
  const float* spos  = (const float*)d_in[1];
  const float* skip  = (const float*)d_in[2];
  const float* sfeat = (const float*)d_in[3];
  const float* W1    = (const float*)d_in[4];
  const float* b1    = (const float*)d_in[5];
  const float* g1    = (const float*)d_in[6];
  const float* beta1 = (const float*)d_in[7];
  const float* W2    = (const float*)d_in[8];
  const float* b2    = (const float*)d_in[9];
  const float* g2    = (const float*)d_in[10];
  const float* beta2 = (const float*)d_in[11];
  float* out = (float*)d_out;

  float* ws = (float*)d_ws;
  size_t off = 0;
  float* sfeatT  = ws + off; off += (size_t)BATCH * NSMP * D2C;
  unsigned short* featB = (unsigned short*)(ws + off); off += (size_t)BN_TOTAL * CIN / 2;
  unsigned short* Y1    = (unsigned short*)(ws + off); off += (size_t)BN_TOTAL * C1 / 2;
  unsigned short* Y2    = (unsigned short*)(ws + off); off += (size_t)BN_TOTAL * C2 / 2;
  unsigned short* W1h   = (unsigned short*)(ws + off); off += (size_t)C1 * CIN / 2;
  unsigned short* W1l   = (unsigned short*)(ws + off); off += (size_t)C1 * CIN / 2;
  unsigned short* W2h   = (unsigned short*)(ws + off); off += (size_t)C2 * C1 / 2;
  unsigned short* W2l   = (unsigned short*)(ws + off); off += (size_t)C2 * C1 / 2;
  int*   knn_idx = (int*)(ws + off); off += (size_t)BN_TOTAL * 3;
  float* knn_w   = ws + off; off += (size_t)BN_TOTAL * 3;
  float* sposI   = ws + off; off += (size_t)BATCH * NSMP * 3;
  int* flag_list = (int*)(ws + off); off += (size_t)BN_TOTAL;
  float* stats   = ws + off; off += 2048;
  float* sum1 = stats, *sumsq1 = stats + 256;
  float* sum2 = stats + 512, *sumsq2 = stats + 640;
  int*   flag_count = (int*)(stats + 768);
  float* scale1 = stats + 1024, *shift1 = stats + 1280;
  float* scale2 = stats + 1536, *shift2 = stats + 1664;

  hipMemsetAsync(stats, 0, 772 * sizeof(float), stream);

  dim3 tb(32, 8);
  transpose_k<<<dim3(NSMP / 32, D2C / 32, BATCH), tb, 0, stream>>>(
      sfeat, sfeatT, D2C, NSMP, (long)D2C * NSMP, (long)NSMP * D2C);
  wprep<<<(C1 * CIN + 255) / 256, 256, 0, stream>>>(W1, W1h, W1l, C1 * CIN);
  wprep<<<(C2 * C1 + 255) / 256, 256, 0, stream>>>(W2, W2h, W2l, C2 * C1);
  skip_to_featB<<<dim3(NPT / 32, D1C / 32, BATCH), tb, 0, stream>>>(skip, featB);

  pack_spos<<<BATCH * NSMP / 256, 256, 0, stream>>>(spos, sposI);
  knn_kernel<<<BN_TOTAL / 64, 256, 0, stream>>>(pos, sposI, knn_idx, knn_w,
                                                flag_list, flag_count);
  knn_fallback<<<256, 256, 0, stream>>>(pos, sposI, flag_list, flag_count,
                                        knn_idx, knn_w);
  interp_kernel<<<BN_TOTAL, 256, 0, stream>>>(sfeatT, knn_idx, knn_w, featB);

  gemm1_mfma<<<dim3(BN_TOTAL / GM, C1 / GN), 256, 0, stream>>>(
      featB, W1h, W1l, b1, Y1, sum1, sumsq1);
  bn_coef_kernel<<<1, C1, 0, stream>>>(sum1, sumsq1, g1, beta1, scale1, shift1, C1);

  gemm2_mfma<<<dim3(BN_TOTAL / GM, 1), 256, 0, stream>>>(
      Y1, scale1, shift1, W2h, W2l, b2, Y2, sum2, sumsq2);
  bn_coef_kernel<<<1, C2, 0, stream>>>(sum2, sumsq2, g2, beta2, scale2, shift2, C2);

  final_kernel<<<dim3(NPT / 32, C2 / 32, BATCH), tb, 0, stream>>>(Y2, scale2, shift2, out);
}

// Round 6
// 345.400 us; speedup vs baseline: 2.0532x; 1.0282x over previous
//
#include <hip/hip_runtime.h>

// Problem constants
constexpr int BATCH = 8;
constexpr int NPT   = 8192;   // N points
constexpr int NSMP  = 2048;   // S sampled points
constexpr int D1C   = 128;    // skip feature channels
constexpr int D2C   = 256;    // sampled feature channels
constexpr int CIN   = 384;    // D1C + D2C
constexpr int C1    = 256;    // layer-1 out channels
constexpr int C2    = 128;    // layer-2 out channels
constexpr int BN_TOTAL = BATCH * NPT;  // 65536 rows

// MFMA GEMM tiling (m97-style: unpadded [row][GK] bf16 tiles, 64 B rows)
constexpr int GM = 128, GN = 128, GK = 32;

typedef __bf16 bf16x8 __attribute__((ext_vector_type(8)));
typedef short  s16x8  __attribute__((ext_vector_type(8)));
typedef float  f32x4  __attribute__((ext_vector_type(4)));

__device__ __forceinline__ unsigned short f2bf(float x) {
  unsigned u = __builtin_bit_cast(unsigned, x);
  u += 0x7fffu + ((u >> 16) & 1u);   // round-to-nearest-even
  return (unsigned short)(u >> 16);
}
__device__ __forceinline__ float bf2f(unsigned short h) {
  return __builtin_bit_cast(float, (unsigned)h << 16);
}

// async global -> LDS, 16 B per lane; lds dest must be wave-uniform base
__device__ __forceinline__ void gld_lds16(const void* g, void* l) {
  __builtin_amdgcn_global_load_lds(
      (const __attribute__((address_space(1))) void*)g,
      (__attribute__((address_space(3))) void*)l, 16, 0, 0);
}

// ---------------------------------------------------------------------------
// 32x32 tiled transpose (fp32)
// ---------------------------------------------------------------------------
__global__ void transpose_k(const float* __restrict__ in, float* __restrict__ out,
                            int rows, int cols, long inBatch, long outBatch) {
  __shared__ float tile[32][33];
  const float* inb = in + (size_t)blockIdx.z * inBatch;
  float* outb = out + (size_t)blockIdx.z * outBatch;
  int c0 = blockIdx.x * 32;
  int r0 = blockIdx.y * 32;
  int tx = threadIdx.x, ty = threadIdx.y;
#pragma unroll
  for (int i = 0; i < 32; i += 8) {
    int r = r0 + ty + i;
    tile[ty + i][tx] = inb[(size_t)r * cols + c0 + tx];
  }
  __syncthreads();
#pragma unroll
  for (int i = 0; i < 32; i += 8) {
    int c = c0 + ty + i;
    outb[(size_t)c * rows + r0 + tx] = tile[tx][ty + i];
  }
}

// ---------------------------------------------------------------------------
// skip [B, D1C, NPT] fp32 -> featB[b*NPT+n][d] bf16 (columns 0..127)
// ---------------------------------------------------------------------------
__global__ void skip_to_featB(const float* __restrict__ skip,
                              unsigned short* __restrict__ featB) {
  __shared__ float tile[32][33];
  int b = blockIdx.z;
  int n0 = blockIdx.x * 32;
  int d0 = blockIdx.y * 32;
  int tx = threadIdx.x, ty = threadIdx.y;
#pragma unroll
  for (int i = 0; i < 32; i += 8) {
    tile[ty + i][tx] = skip[((size_t)b * D1C + d0 + ty + i) * NPT + n0 + tx];
  }
  __syncthreads();
#pragma unroll
  for (int i = 0; i < 32; i += 8) {
    int n = n0 + ty + i;
    featB[((size_t)b * NPT + n) * CIN + d0 + tx] = f2bf(tile[tx][ty + i]);
  }
}

// ---------------------------------------------------------------------------
// Weight prep: W fp32 -> bf16 (single pass; A-rounding dominates error)
// ---------------------------------------------------------------------------
__global__ void wprep(const float* __restrict__ W, unsigned short* __restrict__ Wh,
                      int total) {
  int i = blockIdx.x * 256 + threadIdx.x;
  if (i >= total) return;
  Wh[i] = f2bf(W[i]);
}

// ---------------------------------------------------------------------------
// Pack spos [B,3,NSMP] -> xyz-interleaved sposI [B,NSMP,3]
// ---------------------------------------------------------------------------
__global__ void pack_spos(const float* __restrict__ spos, float* __restrict__ sposI) {
  int g = blockIdx.x * 256 + threadIdx.x;  // B*NSMP = 16384
  int b = g >> 11, s = g & (NSMP - 1);
  const float* sp = spos + (size_t)b * 3 * NSMP;
  sposI[(size_t)g * 3 + 0] = sp[s];
  sposI[(size_t)g * 3 + 1] = sp[NSMP + s];
  sposI[(size_t)g * 3 + 2] = sp[2 * NSMP + s];
}

// ---------------------------------------------------------------------------
// kNN with packed keys (idx in low 11 bits of fp32 distance); 7-op sort-4.
// ---------------------------------------------------------------------------
constexpr int SEG = NSMP / 4;  // 512

__global__ __launch_bounds__(256) void knn_kernel(
    const float* __restrict__ pos,    // [B,3,NPT]
    const float* __restrict__ sposI,  // [B,NSMP,3] interleaved
    int* __restrict__ idx_out,        // [BN_TOTAL,3]
    float* __restrict__ wgt_out,      // [BN_TOTAL,3]
    int* __restrict__ flag_list,
    int* __restrict__ flag_count) {
  __shared__ float qs[3 * NSMP];   // 24 KB
  __shared__ float mk[4][4][64];   // per-wave sorted top-4 keys

  int tid = threadIdx.x;
  int wave = tid >> 6, lane = tid & 63;
  int blk = blockIdx.x;
  int b = blk >> 7;
  int n = ((blk & 127) << 6) + lane;

  const float4* src = (const float4*)(sposI + (size_t)b * 3 * NSMP);
  float4* dst = (float4*)qs;
  for (int t = tid; t < 3 * NSMP / 4; t += 256) dst[t] = src[t];
  __syncthreads();

  const float* pb = pos + (size_t)b * 3 * NPT;
  float px = pb[n], py = pb[NPT + n], pz = pb[2 * NPT + n];

  const float INF = __builtin_inff();
  float k0 = INF, k1 = INF, k2 = INF, k3 = INF;

  const float4* q4 = (const float4*)qs;
  int s0 = wave * SEG;

#define KNN_STEP(QX, QY, QZ, SS)                                          \
  {                                                                       \
    float dx = px - (QX), dy = py - (QY), dz = pz - (QZ);                 \
    float d = fmaf(dx, dx, fmaf(dy, dy, dz * dz));                        \
    unsigned ki = (__builtin_bit_cast(unsigned, d) & 0xFFFFF800u) |       \
                  (unsigned)(SS);                                         \
    float kf = __builtin_bit_cast(float, ki);                             \
    float v1 = fmaxf(kf, k0); k0 = fminf(kf, k0);                         \
    float v2 = fmaxf(v1, k1); k1 = fminf(v1, k1);                         \
    float v3 = fmaxf(v2, k2); k2 = fminf(v2, k2);                         \
    k3 = fminf(v3, k3);                                                   \
  }

  for (int t = 0; t < SEG; t += 4) {
    int s = s0 + t;
    int u = 3 * (s >> 2);
    float4 qa = q4[u], qb = q4[u + 1], qc = q4[u + 2];
    KNN_STEP(qa.x, qa.y, qa.z, s + 0)
    KNN_STEP(qa.w, qb.x, qb.y, s + 1)
    KNN_STEP(qb.z, qb.w, qc.x, s + 2)
    KNN_STEP(qc.y, qc.z, qc.w, s + 3)
  }
#undef KNN_STEP

  mk[wave][0][lane] = k0; mk[wave][1][lane] = k1;
  mk[wave][2][lane] = k2; mk[wave][3][lane] = k3;
  __syncthreads();

  if (tid < 64) {
    float K0 = INF, K1 = INF, K2 = INF, K3 = INF;
#pragma unroll
    for (int w = 0; w < 4; w++) {
#pragma unroll
      for (int sl = 0; sl < 4; sl++) {
        float kf = mk[w][sl][tid];
        float v1 = fmaxf(kf, K0); K0 = fminf(kf, K0);
        float v2 = fmaxf(v1, K1); K1 = fminf(v1, K1);
        float v3 = fmaxf(v2, K2); K2 = fminf(v2, K2);
        K3 = fminf(v3, K3);
      }
    }
    int p = blk * 64 + tid;
    int I0 = (int)(__builtin_bit_cast(unsigned, K0) & 0x7FFu);
    int I1 = (int)(__builtin_bit_cast(unsigned, K1) & 0x7FFu);
    int I2 = (int)(__builtin_bit_cast(unsigned, K2) & 0x7FFu);
    float d2m = __builtin_bit_cast(float, __builtin_bit_cast(unsigned, K2) & 0xFFFFF800u);
    float d3m = __builtin_bit_cast(float, __builtin_bit_cast(unsigned, K3) & 0xFFFFF800u);
    bool flag = (d3m - d2m) < 2e-3f * d3m + 1e-7f;
    if (flag) {
      int slot = atomicAdd(flag_count, 1);
      flag_list[slot] = p;
    }
    const float* q = sposI + (size_t)b * 3 * NSMP;
    double pxd = (double)px, pyd = (double)py, pzd = (double)pz;
    double dd[3]; int II[3] = {I0, I1, I2};
#pragma unroll
    for (int k = 0; k < 3; k++) {
      double dx = pxd - (double)q[3 * II[k]];
      double dy = pyd - (double)q[3 * II[k] + 1];
      double dz = pzd - (double)q[3 * II[k] + 2];
      dd[k] = dx * dx + dy * dy + dz * dz;
    }
    double w0 = 1.0 / (dd[0] + 1e-8);
    double w1 = 1.0 / (dd[1] + 1e-8);
    double w2 = 1.0 / (dd[2] + 1e-8);
    double inv = 1.0 / (w0 + w1 + w2);
    size_t o = (size_t)p * 3;
    idx_out[o + 0] = I0; idx_out[o + 1] = I1; idx_out[o + 2] = I2;
    wgt_out[o + 0] = (float)(w0 * inv);
    wgt_out[o + 1] = (float)(w1 * inv);
    wgt_out[o + 2] = (float)(w2 * inv);
  }
}

// ---------------------------------------------------------------------------
// Exact fp64 fallback, wave-parallel.
// ---------------------------------------------------------------------------
__device__ __forceinline__ bool dless(double d, int i, double D, int I) {
  return d < D || (d == D && i < I);
}
__device__ __forceinline__ void dins3(double d, int i,
                                      double& b0, double& b1, double& b2,
                                      int& i0, int& i1, int& i2) {
  if (dless(d, i, b2, i2)) {
    if (dless(d, i, b1, i1)) {
      b2 = b1; i2 = i1;
      if (dless(d, i, b0, i0)) { b1 = b0; i1 = i0; b0 = d; i0 = i; }
      else                     { b1 = d; i1 = i; }
    } else { b2 = d; i2 = i; }
  }
}

__global__ __launch_bounds__(256) void knn_fallback(
    const float* __restrict__ pos, const float* __restrict__ sposI,
    const int* __restrict__ flag_list, const int* __restrict__ flag_count,
    int* __restrict__ idx_out, float* __restrict__ wgt_out) {
  int wave = threadIdx.x >> 6, lane = threadIdx.x & 63;
  int gw = blockIdx.x * 4 + wave;
  int cnt = *flag_count;
  for (int t = gw; t < cnt; t += 1024) {
    int p = flag_list[t];
    int b = p >> 13, n = p & (NPT - 1);
    const float* pb = pos + (size_t)b * 3 * NPT;
    double px = (double)pb[n], py = (double)pb[NPT + n], pz = (double)pb[2 * NPT + n];
    const float* q = sposI + (size_t)b * 3 * NSMP;
    double b0 = 1e300, b1 = 1e300, b2 = 1e300;
    int i0 = 0x7FFFFFFF, i1 = 0x7FFFFFFF, i2 = 0x7FFFFFFF;
    for (int s = lane; s < NSMP; s += 64) {
      double dx = px - (double)q[3 * s];
      double dy = py - (double)q[3 * s + 1];
      double dz = pz - (double)q[3 * s + 2];
      double d = dx * dx + dy * dy + dz * dz;
      dins3(d, s, b0, b1, b2, i0, i1, i2);
    }
#pragma unroll
    for (int m = 1; m < 64; m <<= 1) {
      double o0 = __shfl_xor(b0, m, 64), o1 = __shfl_xor(b1, m, 64), o2 = __shfl_xor(b2, m, 64);
      int    j0 = __shfl_xor(i0, m, 64), j1 = __shfl_xor(i1, m, 64), j2 = __shfl_xor(i2, m, 64);
      dins3(o0, j0, b0, b1, b2, i0, i1, i2);
      dins3(o1, j1, b0, b1, b2, i0, i1, i2);
      dins3(o2, j2, b0, b1, b2, i0, i1, i2);
    }
    if (lane == 0) {
      double w0 = 1.0 / (b0 + 1e-8);
      double w1 = 1.0 / (b1 + 1e-8);
      double w2 = 1.0 / (b2 + 1e-8);
      double inv = 1.0 / (w0 + w1 + w2);
      size_t o = (size_t)p * 3;
      idx_out[o + 0] = i0; idx_out[o + 1] = i1; idx_out[o + 2] = i2;
      wgt_out[o + 0] = (float)(w0 * inv);
      wgt_out[o + 1] = (float)(w1 * inv);
      wgt_out[o + 2] = (float)(w2 * inv);
    }
  }
}

// ---------------------------------------------------------------------------
// Interp gather -> featB columns 128..383 (bf16)
// ---------------------------------------------------------------------------
__global__ __launch_bounds__(256) void interp_kernel(
    const float* __restrict__ sfeatT,  // [B, NSMP, D2C]
    const int* __restrict__ idx,
    const float* __restrict__ wgt,
    unsigned short* __restrict__ featB) {
  int p = blockIdx.x;
  int c = threadIdx.x;
  int b = p >> 13;
  size_t o = (size_t)p * 3;
  int i0 = idx[o], i1 = idx[o + 1], i2 = idx[o + 2];
  float w0 = wgt[o], w1 = wgt[o + 1], w2 = wgt[o + 2];
  const float* base = sfeatT + (size_t)b * NSMP * D2C;
  float v = w0 * base[(size_t)i0 * D2C + c]
          + w1 * base[(size_t)i1 * D2C + c]
          + w2 * base[(size_t)i2 * D2C + c];
  featB[(size_t)p * CIN + D1C + c] = f2bf(v);
}

// ---------------------------------------------------------------------------
// GEMM1 (MFMA bf16, single weight pass, global_load_lds staging, fused stats)
// Y1 = featB @ W1^T + b1 (bf16 out). Unpadded [128][32] LDS tiles (m97 layout).
// grid (BN_TOTAL/GM, C1/GN)
// ---------------------------------------------------------------------------
__global__ __launch_bounds__(256) void gemm1_mfma(
    const unsigned short* __restrict__ featB,  // [BN_TOTAL][CIN] bf16
    const unsigned short* __restrict__ W1h,    // [C1][CIN] bf16
    const float* __restrict__ bias,
    unsigned short* __restrict__ Y1,           // [BN_TOTAL][C1] bf16
    float* __restrict__ sum, float* __restrict__ sumsq) {
  __shared__ __align__(16) unsigned short As[GM * GK];  // 8 KB
  __shared__ __align__(16) unsigned short Bs[GN * GK];  // 8 KB
  int tid = threadIdx.x;
  int lane = tid & 63;
  int wave = tid >> 6;
  int wrow = (wave >> 1) * 64, wcol = (wave & 1) * 64;
  int m16 = lane & 15, quad = lane >> 4;
  int row0 = blockIdx.x * GM;
  int col0 = blockIdx.y * GN;

  f32x4 acc[4][4];
#pragma unroll
  for (int j = 0; j < 4; j++) {
    float bj = bias[col0 + wcol + j * 16 + m16];
#pragma unroll
    for (int i = 0; i < 4; i++) acc[i][j] = f32x4{bj, bj, bj, bj};
  }

  int rIn  = lane >> 2;        // 0..15 row within 16-row chunk
  int col8 = (lane & 3) * 8;   // k-element offset

  for (int k0 = 0; k0 < CIN; k0 += GK) {
    // stage A and B tiles: 8 chunks of 16 rows each; wave w -> chunks 2w,2w+1
#pragma unroll
    for (int u = 0; u < 2; u++) {
      int c = wave * 2 + u;
      int row = c * 16 + rIn;
      gld_lds16(&featB[(size_t)(row0 + row) * CIN + k0 + col8], &As[c * 16 * GK]);
      gld_lds16(&W1h [(size_t)(col0 + row) * CIN + k0 + col8], &Bs[c * 16 * GK]);
    }
    __syncthreads();

    bf16x8 a[4], bf[4];
#pragma unroll
    for (int i = 0; i < 4; i++)
      a[i] = __builtin_bit_cast(bf16x8, *(const s16x8*)&As[(wrow + i * 16 + m16) * GK + quad * 8]);
#pragma unroll
    for (int j = 0; j < 4; j++)
      bf[j] = __builtin_bit_cast(bf16x8, *(const s16x8*)&Bs[(wcol + j * 16 + m16) * GK + quad * 8]);
#pragma unroll
    for (int i = 0; i < 4; i++)
#pragma unroll
      for (int j = 0; j < 4; j++)
        acc[i][j] = __builtin_amdgcn_mfma_f32_16x16x32_bf16(a[i], bf[j], acc[i][j], 0, 0, 0);
    __syncthreads();
  }

#pragma unroll
  for (int i = 0; i < 4; i++)
#pragma unroll
    for (int j = 0; j < 4; j++) {
      int col = col0 + wcol + j * 16 + m16;
#pragma unroll
      for (int r = 0; r < 4; r++) {
        int row = row0 + wrow + i * 16 + quad * 4 + r;
        Y1[(size_t)row * C1 + col] = f2bf(acc[i][j][r]);
      }
    }

  // fused per-channel stats: column sums of this 128-row tile
#pragma unroll
  for (int j = 0; j < 4; j++) {
    float s = 0.f, q = 0.f;
#pragma unroll
    for (int i = 0; i < 4; i++)
#pragma unroll
      for (int r = 0; r < 4; r++) {
        float v = acc[i][j][r];
        s += v; q = fmaf(v, v, q);
      }
    s += __shfl_xor(s, 16, 64); s += __shfl_xor(s, 32, 64);
    q += __shfl_xor(q, 16, 64); q += __shfl_xor(q, 32, 64);
    if (quad == 0) {
      int col = col0 + wcol + j * 16 + m16;
      atomicAdd(&sum[col], s);
      atomicAdd(&sumsq[col], q);
    }
  }
}

// ---------------------------------------------------------------------------
// GEMM2: X2 = relu(bn1(Y1)) fused in VALU A-staging; B via global_load_lds.
// Fused layer-2 stats. grid (BN_TOTAL/GM, 1)  (C2 == GN == 128)
// ---------------------------------------------------------------------------
__global__ __launch_bounds__(256) void gemm2_mfma(
    const unsigned short* __restrict__ Y1,   // [BN_TOTAL][C1] bf16
    const float* __restrict__ scale1, const float* __restrict__ shift1,
    const unsigned short* __restrict__ W2h,  // [C2][C1] bf16
    const float* __restrict__ bias,
    unsigned short* __restrict__ Y2,         // [BN_TOTAL][C2] bf16
    float* __restrict__ sum, float* __restrict__ sumsq) {
  __shared__ __align__(16) unsigned short As[GM * GK];
  __shared__ __align__(16) unsigned short Bs[GN * GK];
  __shared__ float scs[C1], shs[C1];
  int tid = threadIdx.x;
  int lane = tid & 63;
  int wave = tid >> 6;
  int wrow = (wave >> 1) * 64, wcol = (wave & 1) * 64;
  int m16 = lane & 15, quad = lane >> 4;
  int row0 = blockIdx.x * GM;

  scs[tid] = scale1[tid];
  shs[tid] = shift1[tid];

  f32x4 acc[4][4];
#pragma unroll
  for (int j = 0; j < 4; j++) {
    float bj = bias[wcol + j * 16 + m16];
#pragma unroll
    for (int i = 0; i < 4; i++) acc[i][j] = f32x4{bj, bj, bj, bj};
  }

  int ldr  = tid >> 2;         // 0..63
  int seg  = (tid & 3) * 8;
  int rIn  = lane >> 2;
  int col8 = (lane & 3) * 8;
  __syncthreads();  // scs/shs visible

  for (int k0 = 0; k0 < C1; k0 += GK) {
    // B tile via async direct-to-LDS
#pragma unroll
    for (int u = 0; u < 2; u++) {
      int c = wave * 2 + u;
      int row = c * 16 + rIn;
      gld_lds16(&W2h[(size_t)row * C1 + k0 + col8], &Bs[c * 16 * GK]);
    }
    // A tile: load Y1, apply BN1+ReLU, write LDS
#pragma unroll
    for (int rr = 0; rr < 2; rr++) {
      int r = ldr + rr * 64;
      s16x8 v = *(const s16x8*)&Y1[(size_t)(row0 + r) * C1 + k0 + seg];
      unsigned short ov[8];
#pragma unroll
      for (int e = 0; e < 8; e++) {
        float x = bf2f((unsigned short)v[e]);
        float y = fmaxf(fmaf(x, scs[k0 + seg + e], shs[k0 + seg + e]), 0.f);
        ov[e] = f2bf(y);
      }
      *(s16x8*)&As[r * GK + seg] = *(const s16x8*)ov;
    }
    __syncthreads();

    bf16x8 a[4], bf[4];
#pragma unroll
    for (int i = 0; i < 4; i++)
      a[i] = __builtin_bit_cast(bf16x8, *(const s16x8*)&As[(wrow + i * 16 + m16) * GK + quad * 8]);
#pragma unroll
    for (int j = 0; j < 4; j++)
      bf[j] = __builtin_bit_cast(bf16x8, *(const s16x8*)&Bs[(wcol + j * 16 + m16) * GK + quad * 8]);
#pragma unroll
    for (int i = 0; i < 4; i++)
#pragma unroll
      for (int j = 0; j < 4; j++)
        acc[i][j] = __builtin_amdgcn_mfma_f32_16x16x32_bf16(a[i], bf[j], acc[i][j], 0, 0, 0);
    __syncthreads();
  }

#pragma unroll
  for (int i = 0; i < 4; i++)
#pragma unroll
    for (int j = 0; j < 4; j++) {
      int col = wcol + j * 16 + m16;
#pragma unroll
      for (int r = 0; r < 4; r++) {
        int row = row0 + wrow + i * 16 + quad * 4 + r;
        Y2[(size_t)row * C2 + col] = f2bf(acc[i][j][r]);
      }
    }

  // fused per-channel stats
#pragma unroll
  for (int j = 0; j < 4; j++) {
    float s = 0.f, q = 0.f;
#pragma unroll
    for (int i = 0; i < 4; i++)
#pragma unroll
      for (int r = 0; r < 4; r++) {
        float v = acc[i][j][r];
        s += v; q = fmaf(v, v, q);
      }
    s += __shfl_xor(s, 16, 64); s += __shfl_xor(s, 32, 64);
    q += __shfl_xor(q, 16, 64); q += __shfl_xor(q, 32, 64);
    if (quad == 0) {
      int col = wcol + j * 16 + m16;
      atomicAdd(&sum[col], s);
      atomicAdd(&sumsq[col], q);
    }
  }
}

// ---------------------------------------------------------------------------
__global__ void bn_coef_kernel(const float* __restrict__ sum, const float* __restrict__ sumsq,
                               const float* __restrict__ g, const float* __restrict__ beta,
                               float* __restrict__ scale, float* __restrict__ shift, int C) {
  int c = threadIdx.x + blockIdx.x * blockDim.x;
  if (c >= C) return;
  const float invBN = 1.0f / (float)BN_TOTAL;
  float m = sum[c] * invBN;
  float var = sumsq[c] * invBN - m * m;
  float sc = g[c] / sqrtf(var + 1e-5f);
  scale[c] = sc;
  shift[c] = beta[c] - m * sc;
}

// ---------------------------------------------------------------------------
// Final: out[b][c][n] = relu(bn2(Y2)) transposed, fp32 out.
// ---------------------------------------------------------------------------
__global__ void final_kernel(const unsigned short* __restrict__ Y2,
                             const float* __restrict__ scale, const float* __restrict__ shift,
                             float* __restrict__ out) {
  __shared__ float tile[32][33];
  int b = blockIdx.z;
  int n0 = blockIdx.x * 32;
  int c0 = blockIdx.y * 32;
  int tx = threadIdx.x, ty = threadIdx.y;
  float sc = scale[c0 + tx];
  float sh = shift[c0 + tx];
#pragma unroll
  for (int i = 0; i < 32; i += 8) {
    int n = n0 + ty + i;
    float v = bf2f(Y2[((size_t)b * NPT + n) * C2 + c0 + tx]);
    tile[ty + i][tx] = fmaxf(fmaf(v, sc, sh), 0.f);
  }
  __syncthreads();
#pragma unroll
  for (int i = 0; i < 32; i += 8) {
    int c = c0 + ty + i;
    out[((size_t)b * C2 + c) * NPT + n0 + tx] = tile[tx][ty + i];
  }
}

// ---------------------------------------------------------------------------
extern "C" void kernel_launch(void* const* d_in, const int* in_sizes, int n_in,
                              void* d_out, int out_size, void* d_ws, size_t ws_size,
                              hipStream_t stream) {
  (void)in_sizes; (void)n_in; (void)out_size; (void)ws_size;
  const float* pos   = (const float*)d_in[0];
  const float* spos  = (const float*)d_in[1];
  const float* skip  = (const float*)d_in[2];
  const float* sfeat = (const float*)d_in[3];
  const float* W1    = (const float*)d_in[4];
  const float* b1    = (const float*)d_in[5];
  const float* g1    = (const float*)d_in[6];
  const float* beta1 = (const float*)d_in[7];
  const float* W2    = (const float*)d_in[8];
  const float* b2    = (const float*)d_in[9];
  const float* g2    = (const float*)d_in[10];
  const float* beta2 = (const float*)d_in[11];
  float* out = (float*)d_out;

  float* ws = (float*)d_ws;
  size_t off = 0;
  float* sfeatT  = ws + off; off += (size_t)BATCH * NSMP * D2C;
  unsigned short* featB = (unsigned short*)(ws + off); off += (size_t)BN_TOTAL * CIN / 2;
  unsigned short* Y1    = (unsigned short*)(ws + off); off += (size_t)BN_TOTAL * C1 / 2;
  unsigned short* Y2    = (unsigned short*)(ws + off); off += (size_t)BN_TOTAL * C2 / 2;
  unsigned short* W1h   = (unsigned short*)(ws + off); off += (size_t)C1 * CIN / 2;
  unsigned short* W2h   = (unsigned short*)(ws + off); off += (size_t)C2 * C1 / 2;
  int*   knn_idx = (int*)(ws + off); off += (size_t)BN_TOTAL * 3;
  float* knn_w   = ws + off; off += (size_t)BN_TOTAL * 3;
  float* sposI   = ws + off; off += (size_t)BATCH * NSMP * 3;
  int* flag_list = (int*)(ws + off); off += (size_t)BN_TOTAL;
  float* stats   = ws + off; off += 2048;
  float* sum1 = stats, *sumsq1 = stats + 256;
  float* sum2 = stats + 512, *sumsq2 = stats + 640;
  int*   flag_count = (int*)(stats + 768);
  float* scale1 = stats + 1024, *shift1 = stats + 1280;
  float* scale2 = stats + 1536, *shift2 = stats + 1664;

  hipMemsetAsync(stats, 0, 772 * sizeof(float), stream);

  dim3 tb(32, 8);
  transpose_k<<<dim3(NSMP / 32, D2C / 32, BATCH), tb, 0, stream>>>(
      sfeat, sfeatT, D2C, NSMP, (long)D2C * NSMP, (long)NSMP * D2C);
  wprep<<<(C1 * CIN + 255) / 256, 256, 0, stream>>>(W1, W1h, C1 * CIN);
  wprep<<<(C2 * C1 + 255) / 256, 256, 0, stream>>>(W2, W2h, C2 * C1);
  skip_to_featB<<<dim3(NPT / 32, D1C / 32, BATCH), tb, 0, stream>>>(skip, featB);

  pack_spos<<<BATCH * NSMP / 256, 256, 0, stream>>>(spos, sposI);
  knn_kernel<<<BN_TOTAL / 64, 256, 0, stream>>>(pos, sposI, knn_idx, knn_w,
                                                flag_list, flag_count);
  knn_fallback<<<256, 256, 0, stream>>>(pos, sposI, flag_list, flag_count,
                                        knn_idx, knn_w);
  interp_kernel<<<BN_TOTAL, 256, 0, stream>>>(sfeatT, knn_idx, knn_w, featB);

  gemm1_mfma<<<dim3(BN_TOTAL / GM, C1 / GN), 256, 0, stream>>>(
      featB, W1h, b1, Y1, sum1, sumsq1);
  bn_coef_kernel<<<1, C1, 0, stream>>>(sum1, sumsq1, g1, beta1, scale1, shift1, C1);

  gemm2_mfma<<<dim3(BN_TOTAL / GM, 1), 256, 0, stream>>>(
      Y1, scale1, shift1, W2h, b2, Y2, sum2, sumsq2);
  bn_coef_kernel<<<1, C2, 0, stream>>>(sum2, sumsq2, g2, beta2, scale2, shift2, C2);

  final_kernel<<<dim3(NPT / 32, C2 / 32, BATCH), tb, 0, stream>>>(Y2, scale2, shift2, out);
}

// Round 7
// 315.566 us; speedup vs baseline: 2.2473x; 1.0945x over previous
//
#include <hip/hip_runtime.h>

// Problem constants
constexpr int BATCH = 8;
constexpr int NPT   = 8192;   // N points
constexpr int NSMP  = 2048;   // S sampled points
constexpr int D1C   = 128;    // skip feature channels
constexpr int D2C   = 256;    // sampled feature channels
constexpr int CIN   = 384;    // D1C + D2C
constexpr int C1    = 256;    // layer-1 out channels
constexpr int C2    = 128;    // layer-2 out channels
constexpr int BN_TOTAL = BATCH * NPT;  // 65536 rows

// Wave-GEMM tiling: one 64-lane wave per block, 128x64 tile, K-chunk 32.
// No cross-wave barrier -> no vmcnt(0)+s_barrier drain; latency hidden by
// ~8 independent resident waves/CU.
constexpr int WM = 128, WN = 64, WK = 32;
constexpr int NRB = BN_TOTAL / WM;  // 512 row-blocks

typedef __bf16 bf16x8 __attribute__((ext_vector_type(8)));
typedef short  s16x8  __attribute__((ext_vector_type(8)));
typedef float  f32x4  __attribute__((ext_vector_type(4)));

__device__ __forceinline__ unsigned short f2bf(float x) {
  unsigned u = __builtin_bit_cast(unsigned, x);
  u += 0x7fffu + ((u >> 16) & 1u);   // round-to-nearest-even
  return (unsigned short)(u >> 16);
}
__device__ __forceinline__ float bf2f(unsigned short h) {
  return __builtin_bit_cast(float, (unsigned)h << 16);
}

// async global -> LDS, 16 B per lane; lds dest wave-uniform base + lane*16
__device__ __forceinline__ void gld_lds16(const void* g, void* l) {
  __builtin_amdgcn_global_load_lds(
      (const __attribute__((address_space(1))) void*)g,
      (__attribute__((address_space(3))) void*)l, 16, 0, 0);
}

// ---------------------------------------------------------------------------
// 32x32 tiled transpose (fp32)
// ---------------------------------------------------------------------------
__global__ void transpose_k(const float* __restrict__ in, float* __restrict__ out,
                            int rows, int cols, long inBatch, long outBatch) {
  __shared__ float tile[32][33];
  const float* inb = in + (size_t)blockIdx.z * inBatch;
  float* outb = out + (size_t)blockIdx.z * outBatch;
  int c0 = blockIdx.x * 32;
  int r0 = blockIdx.y * 32;
  int tx = threadIdx.x, ty = threadIdx.y;
#pragma unroll
  for (int i = 0; i < 32; i += 8) {
    int r = r0 + ty + i;
    tile[ty + i][tx] = inb[(size_t)r * cols + c0 + tx];
  }
  __syncthreads();
#pragma unroll
  for (int i = 0; i < 32; i += 8) {
    int c = c0 + ty + i;
    outb[(size_t)c * rows + r0 + tx] = tile[tx][ty + i];
  }
}

// ---------------------------------------------------------------------------
// skip [B, D1C, NPT] fp32 -> featB[b*NPT+n][d] bf16 (columns 0..127)
// ---------------------------------------------------------------------------
__global__ void skip_to_featB(const float* __restrict__ skip,
                              unsigned short* __restrict__ featB) {
  __shared__ float tile[32][33];
  int b = blockIdx.z;
  int n0 = blockIdx.x * 32;
  int d0 = blockIdx.y * 32;
  int tx = threadIdx.x, ty = threadIdx.y;
#pragma unroll
  for (int i = 0; i < 32; i += 8) {
    tile[ty + i][tx] = skip[((size_t)b * D1C + d0 + ty + i) * NPT + n0 + tx];
  }
  __syncthreads();
#pragma unroll
  for (int i = 0; i < 32; i += 8) {
    int n = n0 + ty + i;
    featB[((size_t)b * NPT + n) * CIN + d0 + tx] = f2bf(tile[tx][ty + i]);
  }
}

// ---------------------------------------------------------------------------
// Weight prep: W fp32 -> bf16
// ---------------------------------------------------------------------------
__global__ void wprep(const float* __restrict__ W, unsigned short* __restrict__ Wh,
                      int total) {
  int i = blockIdx.x * 256 + threadIdx.x;
  if (i >= total) return;
  Wh[i] = f2bf(W[i]);
}

// ---------------------------------------------------------------------------
// Pack spos [B,3,NSMP] -> xyz-interleaved sposI [B,NSMP,3]
// ---------------------------------------------------------------------------
__global__ void pack_spos(const float* __restrict__ spos, float* __restrict__ sposI) {
  int g = blockIdx.x * 256 + threadIdx.x;  // B*NSMP = 16384
  int b = g >> 11, s = g & (NSMP - 1);
  const float* sp = spos + (size_t)b * 3 * NSMP;
  sposI[(size_t)g * 3 + 0] = sp[s];
  sposI[(size_t)g * 3 + 1] = sp[NSMP + s];
  sposI[(size_t)g * 3 + 2] = sp[2 * NSMP + s];
}

// ---------------------------------------------------------------------------
// kNN with packed keys (idx in low 11 bits of fp32 distance); 7-op sort-4.
// ---------------------------------------------------------------------------
constexpr int SEG = NSMP / 4;  // 512

__global__ __launch_bounds__(256) void knn_kernel(
    const float* __restrict__ pos,    // [B,3,NPT]
    const float* __restrict__ sposI,  // [B,NSMP,3] interleaved
    int* __restrict__ idx_out,        // [BN_TOTAL,3]
    float* __restrict__ wgt_out,      // [BN_TOTAL,3]
    int* __restrict__ flag_list,
    int* __restrict__ flag_count) {
  __shared__ float qs[3 * NSMP];   // 24 KB
  __shared__ float mk[4][4][64];   // per-wave sorted top-4 keys

  int tid = threadIdx.x;
  int wave = tid >> 6, lane = tid & 63;
  int blk = blockIdx.x;
  int b = blk >> 7;
  int n = ((blk & 127) << 6) + lane;

  const float4* src = (const float4*)(sposI + (size_t)b * 3 * NSMP);
  float4* dst = (float4*)qs;
  for (int t = tid; t < 3 * NSMP / 4; t += 256) dst[t] = src[t];
  __syncthreads();

  const float* pb = pos + (size_t)b * 3 * NPT;
  float px = pb[n], py = pb[NPT + n], pz = pb[2 * NPT + n];

  const float INF = __builtin_inff();
  float k0 = INF, k1 = INF, k2 = INF, k3 = INF;

  const float4* q4 = (const float4*)qs;
  int s0 = wave * SEG;

#define KNN_STEP(QX, QY, QZ, SS)                                          \
  {                                                                       \
    float dx = px - (QX), dy = py - (QY), dz = pz - (QZ);                 \
    float d = fmaf(dx, dx, fmaf(dy, dy, dz * dz));                        \
    unsigned ki = (__builtin_bit_cast(unsigned, d) & 0xFFFFF800u) |       \
                  (unsigned)(SS);                                         \
    float kf = __builtin_bit_cast(float, ki);                             \
    float v1 = fmaxf(kf, k0); k0 = fminf(kf, k0);                         \
    float v2 = fmaxf(v1, k1); k1 = fminf(v1, k1);                         \
    float v3 = fmaxf(v2, k2); k2 = fminf(v2, k2);                         \
    k3 = fminf(v3, k3);                                                   \
  }

  for (int t = 0; t < SEG; t += 4) {
    int s = s0 + t;
    int u = 3 * (s >> 2);
    float4 qa = q4[u], qb = q4[u + 1], qc = q4[u + 2];
    KNN_STEP(qa.x, qa.y, qa.z, s + 0)
    KNN_STEP(qa.w, qb.x, qb.y, s + 1)
    KNN_STEP(qb.z, qb.w, qc.x, s + 2)
    KNN_STEP(qc.y, qc.z, qc.w, s + 3)
  }
#undef KNN_STEP

  mk[wave][0][lane] = k0; mk[wave][1][lane] = k1;
  mk[wave][2][lane] = k2; mk[wave][3][lane] = k3;
  __syncthreads();

  if (tid < 64) {
    float K0 = INF, K1 = INF, K2 = INF, K3 = INF;
#pragma unroll
    for (int w = 0; w < 4; w++) {
#pragma unroll
      for (int sl = 0; sl < 4; sl++) {
        float kf = mk[w][sl][tid];
        float v1 = fmaxf(kf, K0); K0 = fminf(kf, K0);
        float v2 = fmaxf(v1, K1); K1 = fminf(v1, K1);
        float v3 = fmaxf(v2, K2); K2 = fminf(v2, K2);
        K3 = fminf(v3, K3);
      }
    }
    int p = blk * 64 + tid;
    int I0 = (int)(__builtin_bit_cast(unsigned, K0) & 0x7FFu);
    int I1 = (int)(__builtin_bit_cast(unsigned, K1) & 0x7FFu);
    int I2 = (int)(__builtin_bit_cast(unsigned, K2) & 0x7FFu);
    float d2m = __builtin_bit_cast(float, __builtin_bit_cast(unsigned, K2) & 0xFFFFF800u);
    float d3m = __builtin_bit_cast(float, __builtin_bit_cast(unsigned, K3) & 0xFFFFF800u);
    bool flag = (d3m - d2m) < 2e-3f * d3m + 1e-7f;
    if (flag) {
      int slot = atomicAdd(flag_count, 1);
      flag_list[slot] = p;
    }
    const float* q = sposI + (size_t)b * 3 * NSMP;
    double pxd = (double)px, pyd = (double)py, pzd = (double)pz;
    double dd[3]; int II[3] = {I0, I1, I2};
#pragma unroll
    for (int k = 0; k < 3; k++) {
      double dx = pxd - (double)q[3 * II[k]];
      double dy = pyd - (double)q[3 * II[k] + 1];
      double dz = pzd - (double)q[3 * II[k] + 2];
      dd[k] = dx * dx + dy * dy + dz * dz;
    }
    double w0 = 1.0 / (dd[0] + 1e-8);
    double w1 = 1.0 / (dd[1] + 1e-8);
    double w2 = 1.0 / (dd[2] + 1e-8);
    double inv = 1.0 / (w0 + w1 + w2);
    size_t o = (size_t)p * 3;
    idx_out[o + 0] = I0; idx_out[o + 1] = I1; idx_out[o + 2] = I2;
    wgt_out[o + 0] = (float)(w0 * inv);
    wgt_out[o + 1] = (float)(w1 * inv);
    wgt_out[o + 2] = (float)(w2 * inv);
  }
}

// ---------------------------------------------------------------------------
// Exact fp64 fallback, wave-parallel.
// ---------------------------------------------------------------------------
__device__ __forceinline__ bool dless(double d, int i, double D, int I) {
  return d < D || (d == D && i < I);
}
__device__ __forceinline__ void dins3(double d, int i,
                                      double& b0, double& b1, double& b2,
                                      int& i0, int& i1, int& i2) {
  if (dless(d, i, b2, i2)) {
    if (dless(d, i, b1, i1)) {
      b2 = b1; i2 = i1;
      if (dless(d, i, b0, i0)) { b1 = b0; i1 = i0; b0 = d; i0 = i; }
      else                     { b1 = d; i1 = i; }
    } else { b2 = d; i2 = i; }
  }
}

__global__ __launch_bounds__(256) void knn_fallback(
    const float* __restrict__ pos, const float* __restrict__ sposI,
    const int* __restrict__ flag_list, const int* __restrict__ flag_count,
    int* __restrict__ idx_out, float* __restrict__ wgt_out) {
  int wave = threadIdx.x >> 6, lane = threadIdx.x & 63;
  int gw = blockIdx.x * 4 + wave;
  int cnt = *flag_count;
  for (int t = gw; t < cnt; t += 1024) {
    int p = flag_list[t];
    int b = p >> 13, n = p & (NPT - 1);
    const float* pb = pos + (size_t)b * 3 * NPT;
    double px = (double)pb[n], py = (double)pb[NPT + n], pz = (double)pb[2 * NPT + n];
    const float* q = sposI + (size_t)b * 3 * NSMP;
    double b0 = 1e300, b1 = 1e300, b2 = 1e300;
    int i0 = 0x7FFFFFFF, i1 = 0x7FFFFFFF, i2 = 0x7FFFFFFF;
    for (int s = lane; s < NSMP; s += 64) {
      double dx = px - (double)q[3 * s];
      double dy = py - (double)q[3 * s + 1];
      double dz = pz - (double)q[3 * s + 2];
      double d = dx * dx + dy * dy + dz * dz;
      dins3(d, s, b0, b1, b2, i0, i1, i2);
    }
#pragma unroll
    for (int m = 1; m < 64; m <<= 1) {
      double o0 = __shfl_xor(b0, m, 64), o1 = __shfl_xor(b1, m, 64), o2 = __shfl_xor(b2, m, 64);
      int    j0 = __shfl_xor(i0, m, 64), j1 = __shfl_xor(i1, m, 64), j2 = __shfl_xor(i2, m, 64);
      dins3(o0, j0, b0, b1, b2, i0, i1, i2);
      dins3(o1, j1, b0, b1, b2, i0, i1, i2);
      dins3(o2, j2, b0, b1, b2, i0, i1, i2);
    }
    if (lane == 0) {
      double w0 = 1.0 / (b0 + 1e-8);
      double w1 = 1.0 / (b1 + 1e-8);
      double w2 = 1.0 / (b2 + 1e-8);
      double inv = 1.0 / (w0 + w1 + w2);
      size_t o = (size_t)p * 3;
      idx_out[o + 0] = i0; idx_out[o + 1] = i1; idx_out[o + 2] = i2;
      wgt_out[o + 0] = (float)(w0 * inv);
      wgt_out[o + 1] = (float)(w1 * inv);
      wgt_out[o + 2] = (float)(w2 * inv);
    }
  }
}

// ---------------------------------------------------------------------------
// Interp gather -> featB columns 128..383 (bf16)
// ---------------------------------------------------------------------------
__global__ __launch_bounds__(256) void interp_kernel(
    const float* __restrict__ sfeatT,  // [B, NSMP, D2C]
    const int* __restrict__ idx,
    const float* __restrict__ wgt,
    unsigned short* __restrict__ featB) {
  int p = blockIdx.x;
  int c = threadIdx.x;
  int b = p >> 13;
  size_t o = (size_t)p * 3;
  int i0 = idx[o], i1 = idx[o + 1], i2 = idx[o + 2];
  float w0 = wgt[o], w1 = wgt[o + 1], w2 = wgt[o + 2];
  const float* base = sfeatT + (size_t)b * NSMP * D2C;
  float v = w0 * base[(size_t)i0 * D2C + c]
          + w1 * base[(size_t)i1 * D2C + c]
          + w2 * base[(size_t)i2 * D2C + c];
  featB[(size_t)p * CIN + D1C + c] = f2bf(v);
}

// ---------------------------------------------------------------------------
// GEMM1, single-wave blocks: Y1 = featB @ W1^T + b1, 128x64 tile/wave.
// No cross-wave barriers. Partial (sum, sumsq) per [col][rowblock] written
// to global for a separate tiny reduce (no atomics).
// grid (NRB, C1/WN) = (512, 4), block 64.
// ---------------------------------------------------------------------------
__global__ __launch_bounds__(64) void gemm1_wave(
    const unsigned short* __restrict__ featB,  // [BN_TOTAL][CIN] bf16
    const unsigned short* __restrict__ W1h,    // [C1][CIN] bf16
    const float* __restrict__ bias,
    unsigned short* __restrict__ Y1,           // [BN_TOTAL][C1] bf16
    float* __restrict__ part_s,                // [C1][NRB]
    float* __restrict__ part_q) {
  __shared__ __align__(16) unsigned short As[WM * WK];  // 8 KB
  __shared__ __align__(16) unsigned short Bs[WN * WK];  // 4 KB
  int lane = threadIdx.x;
  int m16 = lane & 15, quad = lane >> 4;
  int rb = blockIdx.x, cb = blockIdx.y;
  int row0 = rb * WM, col0 = cb * WN;
  int row16 = lane >> 2, col8 = (lane & 3) * 8;

  f32x4 acc[8][4];
#pragma unroll
  for (int j = 0; j < 4; j++) {
    float bj = bias[col0 + j * 16 + m16];
#pragma unroll
    for (int i = 0; i < 8; i++) acc[i][j] = f32x4{bj, bj, bj, bj};
  }

  for (int k0 = 0; k0 < CIN; k0 += WK) {
#pragma unroll
    for (int c = 0; c < 8; c++)
      gld_lds16(&featB[(size_t)(row0 + c * 16 + row16) * CIN + k0 + col8],
                &As[c * 16 * WK]);
#pragma unroll
    for (int c = 0; c < 4; c++)
      gld_lds16(&W1h[(size_t)(col0 + c * 16 + row16) * CIN + k0 + col8],
                &Bs[c * 16 * WK]);
    __syncthreads();  // 1-wave block: local waitcnt, no cross-wave drain

    bf16x8 a[8], bf[4];
#pragma unroll
    for (int i = 0; i < 8; i++)
      a[i] = __builtin_bit_cast(bf16x8, *(const s16x8*)&As[(i * 16 + m16) * WK + quad * 8]);
#pragma unroll
    for (int j = 0; j < 4; j++)
      bf[j] = __builtin_bit_cast(bf16x8, *(const s16x8*)&Bs[(j * 16 + m16) * WK + quad * 8]);
#pragma unroll
    for (int i = 0; i < 8; i++)
#pragma unroll
      for (int j = 0; j < 4; j++)
        acc[i][j] = __builtin_amdgcn_mfma_f32_16x16x32_bf16(a[i], bf[j], acc[i][j], 0, 0, 0);
    __syncthreads();
  }

#pragma unroll
  for (int j = 0; j < 4; j++) {
    int col = col0 + j * 16 + m16;
    float s = 0.f, q = 0.f;
#pragma unroll
    for (int i = 0; i < 8; i++)
#pragma unroll
      for (int r = 0; r < 4; r++) {
        float v = acc[i][j][r];
        Y1[(size_t)(row0 + i * 16 + quad * 4 + r) * C1 + col] = f2bf(v);
        s += v; q = fmaf(v, v, q);
      }
    s += __shfl_xor(s, 16, 64); s += __shfl_xor(s, 32, 64);
    q += __shfl_xor(q, 16, 64); q += __shfl_xor(q, 32, 64);
    if (quad == 0) {
      part_s[(size_t)col * NRB + rb] = s;
      part_q[(size_t)col * NRB + rb] = q;
    }
  }
}

// ---------------------------------------------------------------------------
// GEMM2, single-wave blocks: X2 = relu(bn1(Y1)) fused in A staging (VALU),
// B via global_load_lds. 128x64 tile/wave. grid (NRB, C2/WN) = (512, 2).
// ---------------------------------------------------------------------------
__global__ __launch_bounds__(64) void gemm2_wave(
    const unsigned short* __restrict__ Y1,   // [BN_TOTAL][C1] bf16
    const float* __restrict__ scale1, const float* __restrict__ shift1,
    const unsigned short* __restrict__ W2h,  // [C2][C1] bf16
    const float* __restrict__ bias,
    unsigned short* __restrict__ Y2,         // [BN_TOTAL][C2] bf16
    float* __restrict__ part_s,              // [C2][NRB]
    float* __restrict__ part_q) {
  __shared__ __align__(16) unsigned short As[WM * WK];
  __shared__ __align__(16) unsigned short Bs[WN * WK];
  __shared__ float scs[C1], shs[C1];
  int lane = threadIdx.x;
  int m16 = lane & 15, quad = lane >> 4;
  int rb = blockIdx.x, cb = blockIdx.y;
  int row0 = rb * WM, col0 = cb * WN;
  int row16 = lane >> 2, col8 = (lane & 3) * 8;

  for (int t = lane; t < C1; t += 64) { scs[t] = scale1[t]; shs[t] = shift1[t]; }

  f32x4 acc[8][4];
#pragma unroll
  for (int j = 0; j < 4; j++) {
    float bj = bias[col0 + j * 16 + m16];
#pragma unroll
    for (int i = 0; i < 8; i++) acc[i][j] = f32x4{bj, bj, bj, bj};
  }
  __syncthreads();  // scs/shs visible (single wave: cheap)

  for (int k0 = 0; k0 < C1; k0 += WK) {
#pragma unroll
    for (int c = 0; c < 4; c++)
      gld_lds16(&W2h[(size_t)(col0 + c * 16 + row16) * C1 + k0 + col8],
                &Bs[c * 16 * WK]);
    // A tile: load Y1, apply BN1+ReLU, write LDS
#pragma unroll
    for (int c = 0; c < 8; c++) {
      int row = c * 16 + row16;
      s16x8 v = *(const s16x8*)&Y1[(size_t)(row0 + row) * C1 + k0 + col8];
      unsigned short ov[8];
#pragma unroll
      for (int e = 0; e < 8; e++) {
        float x = bf2f((unsigned short)v[e]);
        float y = fmaxf(fmaf(x, scs[k0 + col8 + e], shs[k0 + col8 + e]), 0.f);
        ov[e] = f2bf(y);
      }
      *(s16x8*)&As[row * WK + col8] = *(const s16x8*)ov;
    }
    __syncthreads();

    bf16x8 a[8], bf[4];
#pragma unroll
    for (int i = 0; i < 8; i++)
      a[i] = __builtin_bit_cast(bf16x8, *(const s16x8*)&As[(i * 16 + m16) * WK + quad * 8]);
#pragma unroll
    for (int j = 0; j < 4; j++)
      bf[j] = __builtin_bit_cast(bf16x8, *(const s16x8*)&Bs[(j * 16 + m16) * WK + quad * 8]);
#pragma unroll
    for (int i = 0; i < 8; i++)
#pragma unroll
      for (int j = 0; j < 4; j++)
        acc[i][j] = __builtin_amdgcn_mfma_f32_16x16x32_bf16(a[i], bf[j], acc[i][j], 0, 0, 0);
    __syncthreads();
  }

#pragma unroll
  for (int j = 0; j < 4; j++) {
    int col = col0 + j * 16 + m16;
    float s = 0.f, q = 0.f;
#pragma unroll
    for (int i = 0; i < 8; i++)
#pragma unroll
      for (int r = 0; r < 4; r++) {
        float v = acc[i][j][r];
        Y2[(size_t)(row0 + i * 16 + quad * 4 + r) * C2 + col] = f2bf(v);
        s += v; q = fmaf(v, v, q);
      }
    s += __shfl_xor(s, 16, 64); s += __shfl_xor(s, 32, 64);
    q += __shfl_xor(q, 16, 64); q += __shfl_xor(q, 32, 64);
    if (quad == 0) {
      part_s[(size_t)col * NRB + rb] = s;
      part_q[(size_t)col * NRB + rb] = q;
    }
  }
}

// ---------------------------------------------------------------------------
// Reduce partials [C][NRB] + compute BN scale/shift. grid = C, block = 256.
// ---------------------------------------------------------------------------
__global__ __launch_bounds__(256) void bn_reduce_coef(
    const float* __restrict__ part_s, const float* __restrict__ part_q, int nrb,
    const float* __restrict__ g, const float* __restrict__ beta,
    float* __restrict__ scale, float* __restrict__ shift) {
  int ch = blockIdx.x;
  int tid = threadIdx.x;
  float s = 0.f, q = 0.f;
  for (int t = tid; t < nrb; t += 256) {
    s += part_s[(size_t)ch * nrb + t];
    q += part_q[(size_t)ch * nrb + t];
  }
#pragma unroll
  for (int m = 1; m < 64; m <<= 1) {
    s += __shfl_xor(s, m, 64);
    q += __shfl_xor(q, m, 64);
  }
  __shared__ float ls[4], lq[4];
  int wave = tid >> 6;
  if ((tid & 63) == 0) { ls[wave] = s; lq[wave] = q; }
  __syncthreads();
  if (tid == 0) {
    s = ls[0] + ls[1] + ls[2] + ls[3];
    q = lq[0] + lq[1] + lq[2] + lq[3];
    const float invBN = 1.0f / (float)BN_TOTAL;
    float mean = s * invBN;
    float var = q * invBN - mean * mean;
    float sc = g[ch] / sqrtf(var + 1e-5f);
    scale[ch] = sc;
    shift[ch] = beta[ch] - mean * sc;
  }
}

// ---------------------------------------------------------------------------
// Final: out[b][c][n] = relu(bn2(Y2)) transposed, fp32 out.
// ---------------------------------------------------------------------------
__global__ void final_kernel(const unsigned short* __restrict__ Y2,
                             const float* __restrict__ scale, const float* __restrict__ shift,
                             float* __restrict__ out) {
  __shared__ float tile[32][33];
  int b = blockIdx.z;
  int n0 = blockIdx.x * 32;
  int c0 = blockIdx.y * 32;
  int tx = threadIdx.x, ty = threadIdx.y;
  float sc = scale[c0 + tx];
  float sh = shift[c0 + tx];
#pragma unroll
  for (int i = 0; i < 32; i += 8) {
    int n = n0 + ty + i;
    float v = bf2f(Y2[((size_t)b * NPT + n) * C2 + c0 + tx]);
    tile[ty + i][tx] = fmaxf(fmaf(v, sc, sh), 0.f);
  }
  __syncthreads();
#pragma unroll
  for (int i = 0; i < 32; i += 8) {
    int c = c0 + ty + i;
    out[((size_t)b * C2 + c) * NPT + n0 + tx] = tile[tx][ty + i];
  }
}

// ---------------------------------------------------------------------------
extern "C" void kernel_launch(void* const* d_in, const int* in_sizes, int n_in,
                              void* d_out, int out_size, void* d_ws, size_t ws_size,
                              hipStream_t stream) {
  (void)in_sizes; (void)n_in; (void)out_size; (void)ws_size;
  const float* pos   = (const float*)d_in[0];
  const float* spos  = (const float*)d_in[1];
  const float* skip  = (const float*)d_in[2];
  const float* sfeat = (const float*)d_in[3];
  const float* W1    = (const float*)d_in[4];
  const float* b1    = (const float*)d_in[5];
  const float* g1    = (const float*)d_in[6];
  const float* beta1 = (const float*)d_in[7];
  const float* W2    = (const float*)d_in[8];
  const float* b2    = (const float*)d_in[9];
  const float* g2    = (const float*)d_in[10];
  const float* beta2 = (const float*)d_in[11];
  float* out = (float*)d_out;

  float* ws = (float*)d_ws;
  size_t off = 0;
  float* sfeatT  = ws + off; off += (size_t)BATCH * NSMP * D2C;
  unsigned short* featB = (unsigned short*)(ws + off); off += (size_t)BN_TOTAL * CIN / 2;
  unsigned short* Y1    = (unsigned short*)(ws + off); off += (size_t)BN_TOTAL * C1 / 2;
  unsigned short* Y2    = (unsigned short*)(ws + off); off += (size_t)BN_TOTAL * C2 / 2;
  unsigned short* W1h   = (unsigned short*)(ws + off); off += (size_t)C1 * CIN / 2;
  unsigned short* W2h   = (unsigned short*)(ws + off); off += (size_t)C2 * C1 / 2;
  int*   knn_idx = (int*)(ws + off); off += (size_t)BN_TOTAL * 3;
  float* knn_w   = ws + off; off += (size_t)BN_TOTAL * 3;
  float* sposI   = ws + off; off += (size_t)BATCH * NSMP * 3;
  int* flag_list = (int*)(ws + off); off += (size_t)BN_TOTAL;
  float* part1_s = ws + off; off += (size_t)C1 * NRB;   // 131072
  float* part1_q = ws + off; off += (size_t)C1 * NRB;
  float* part2_s = ws + off; off += (size_t)C2 * NRB;   // 65536
  float* part2_q = ws + off; off += (size_t)C2 * NRB;
  float* stats   = ws + off; off += 2048;
  int*   flag_count = (int*)stats;
  float* scale1 = stats + 256, *shift1 = stats + 512;
  float* scale2 = stats + 768, *shift2 = stats + 1024;

  hipMemsetAsync(flag_count, 0, sizeof(int), stream);

  dim3 tb(32, 8);
  transpose_k<<<dim3(NSMP / 32, D2C / 32, BATCH), tb, 0, stream>>>(
      sfeat, sfeatT, D2C, NSMP, (long)D2C * NSMP, (long)NSMP * D2C);
  wprep<<<(C1 * CIN + 255) / 256, 256, 0, stream>>>(W1, W1h, C1 * CIN);
  wprep<<<(C2 * C1 + 255) / 256, 256, 0, stream>>>(W2, W2h, C2 * C1);
  skip_to_featB<<<dim3(NPT / 32, D1C / 32, BATCH), tb, 0, stream>>>(skip, featB);

  pack_spos<<<BATCH * NSMP / 256, 256, 0, stream>>>(spos, sposI);
  knn_kernel<<<BN_TOTAL / 64, 256, 0, stream>>>(pos, sposI, knn_idx, knn_w,
                                                flag_list, flag_count);
  knn_fallback<<<256, 256, 0, stream>>>(pos, sposI, flag_list, flag_count,
                                        knn_idx, knn_w);
  interp_kernel<<<BN_TOTAL, 256, 0, stream>>>(sfeatT, knn_idx, knn_w, featB);

  gemm1_wave<<<dim3(NRB, C1 / WN), 64, 0, stream>>>(
      featB, W1h, b1, Y1, part1_s, part1_q);
  bn_reduce_coef<<<C1, 256, 0, stream>>>(part1_s, part1_q, NRB, g1, beta1, scale1, shift1);

  gemm2_wave<<<dim3(NRB, C2 / WN), 64, 0, stream>>>(
      Y1, scale1, shift1, W2h, b2, Y2, part2_s, part2_q);
  bn_reduce_coef<<<C2, 256, 0, stream>>>(part2_s, part2_q, NRB, g2, beta2, scale2, shift2);

  final_kernel<<<dim3(NPT / 32, C2 / 32, BATCH), tb, 0, stream>>>(Y2, scale2, shift2, out);
}

// Round 8
// 301.706 us; speedup vs baseline: 2.3505x; 1.0459x over previous
//
#include <hip/hip_runtime.h>

// Problem constants
constexpr int BATCH = 8;
constexpr int NPT   = 8192;   // N points
constexpr int NSMP  = 2048;   // S sampled points
constexpr int D1C   = 128;    // skip feature channels
constexpr int D2C   = 256;    // sampled feature channels
constexpr int CIN   = 384;    // D1C + D2C
constexpr int C1    = 256;    // layer-1 out channels
constexpr int C2    = 128;    // layer-2 out channels
constexpr int BN_TOTAL = BATCH * NPT;  // 65536 rows

// Wave-GEMM tiling: one 64-lane wave per block, 128x64 tile, K-chunk 32.
constexpr int WM = 128, WN = 64, WK = 32;
constexpr int NRB = BN_TOTAL / WM;  // 512 row-blocks

typedef __bf16 bf16x8 __attribute__((ext_vector_type(8)));
typedef short  s16x8  __attribute__((ext_vector_type(8)));
typedef float  f32x4  __attribute__((ext_vector_type(4)));

__device__ __forceinline__ unsigned short f2bf(float x) {
  unsigned u = __builtin_bit_cast(unsigned, x);
  u += 0x7fffu + ((u >> 16) & 1u);   // round-to-nearest-even
  return (unsigned short)(u >> 16);
}
__device__ __forceinline__ float bf2f(unsigned short h) {
  return __builtin_bit_cast(float, (unsigned)h << 16);
}

// async global -> LDS, 16 B per lane; lds dest wave-uniform base + lane*16
__device__ __forceinline__ void gld_lds16(const void* g, void* l) {
  __builtin_amdgcn_global_load_lds(
      (const __attribute__((address_space(1))) void*)g,
      (__attribute__((address_space(3))) void*)l, 16, 0, 0);
}

// ---------------------------------------------------------------------------
// 32x32 tiled transpose (fp32)
// ---------------------------------------------------------------------------
__global__ void transpose_k(const float* __restrict__ in, float* __restrict__ out,
                            int rows, int cols, long inBatch, long outBatch) {
  __shared__ float tile[32][33];
  const float* inb = in + (size_t)blockIdx.z * inBatch;
  float* outb = out + (size_t)blockIdx.z * outBatch;
  int c0 = blockIdx.x * 32;
  int r0 = blockIdx.y * 32;
  int tx = threadIdx.x, ty = threadIdx.y;
#pragma unroll
  for (int i = 0; i < 32; i += 8) {
    int r = r0 + ty + i;
    tile[ty + i][tx] = inb[(size_t)r * cols + c0 + tx];
  }
  __syncthreads();
#pragma unroll
  for (int i = 0; i < 32; i += 8) {
    int c = c0 + ty + i;
    outb[(size_t)c * rows + r0 + tx] = tile[tx][ty + i];
  }
}

// ---------------------------------------------------------------------------
// skip [B, D1C, NPT] fp32 -> featB[b*NPT+n][d] bf16 (columns 0..127)
// ---------------------------------------------------------------------------
__global__ void skip_to_featB(const float* __restrict__ skip,
                              unsigned short* __restrict__ featB) {
  __shared__ float tile[32][33];
  int b = blockIdx.z;
  int n0 = blockIdx.x * 32;
  int d0 = blockIdx.y * 32;
  int tx = threadIdx.x, ty = threadIdx.y;
#pragma unroll
  for (int i = 0; i < 32; i += 8) {
    tile[ty + i][tx] = skip[((size_t)b * D1C + d0 + ty + i) * NPT + n0 + tx];
  }
  __syncthreads();
#pragma unroll
  for (int i = 0; i < 32; i += 8) {
    int n = n0 + ty + i;
    featB[((size_t)b * NPT + n) * CIN + d0 + tx] = f2bf(tile[tx][ty + i]);
  }
}

// ---------------------------------------------------------------------------
// Weight prep: W fp32 -> bf16
// ---------------------------------------------------------------------------
__global__ void wprep(const float* __restrict__ W, unsigned short* __restrict__ Wh,
                      int total) {
  int i = blockIdx.x * 256 + threadIdx.x;
  if (i >= total) return;
  Wh[i] = f2bf(W[i]);
}

// ---------------------------------------------------------------------------
// Pack spos: original interleaved sposI [B,NSMP,3] (for exact fp64 paths)
// and transformed qs4 [B,NSMP,4] = (-2x, -2y, -2z, |q|^2) for the scan.
// ---------------------------------------------------------------------------
__global__ void pack_spos(const float* __restrict__ spos, float* __restrict__ sposI,
                          float4* __restrict__ qs4) {
  int g = blockIdx.x * 256 + threadIdx.x;  // B*NSMP = 16384
  int b = g >> 11, s = g & (NSMP - 1);
  const float* sp = spos + (size_t)b * 3 * NSMP;
  float x = sp[s], y = sp[NSMP + s], z = sp[2 * NSMP + s];
  sposI[(size_t)g * 3 + 0] = x;
  sposI[(size_t)g * 3 + 1] = y;
  sposI[(size_t)g * 3 + 2] = z;
  qs4[g] = make_float4(-2.f * x, -2.f * y, -2.f * z,
                       fmaf(x, x, fmaf(y, y, z * z)));
}

// ---------------------------------------------------------------------------
// kNN scan, 10 VALU ops/pair:
//   d  = fma(px,-2qx, fma(py,-2qy, fma(pz,-2qz, |q|^2+|p|^2)))   (4 ops)
//   ki = (bits(d) & ~0x7FF) | s                                   (2 ops)
//   sorted top-4 insert via min + 3x v_med3_f32                   (4 ops)
// Packed keys carry indices for free with lexicographic tie-break.
// Certification: expansion-form abs noise ~7e-7 + packing 2^-12 rel ->
// flag if (d3m-d2m) < 2e-3*d3m + 1e-5 (>=8x margin) -> exact fp64 fallback.
// ---------------------------------------------------------------------------
constexpr int SEG = NSMP / 4;  // 512

__device__ __forceinline__ void ins_med3(float kf, float& k0, float& k1,
                                         float& k2, float& k3) {
  float o0 = k0, o1 = k1, o2 = k2;
  k0 = fminf(kf, o0);
  k1 = __builtin_amdgcn_fmed3f(kf, o0, o1);
  k2 = __builtin_amdgcn_fmed3f(kf, o1, o2);
  k3 = __builtin_amdgcn_fmed3f(kf, o2, k3);
}

__global__ __launch_bounds__(256) void knn_kernel(
    const float* __restrict__ pos,    // [B,3,NPT]
    const float4* __restrict__ qs4g,  // [B,NSMP] transformed
    const float* __restrict__ sposI,  // [B,NSMP,3] original (fp64 weights)
    int* __restrict__ idx_out,        // [BN_TOTAL,3]
    float* __restrict__ wgt_out,      // [BN_TOTAL,3]
    int* __restrict__ flag_list,
    int* __restrict__ flag_count) {
  __shared__ float4 qs[NSMP];      // 32 KB
  __shared__ float mk[4][4][64];   // per-wave sorted top-4 keys (4 KB)

  int tid = threadIdx.x;
  int wave = tid >> 6, lane = tid & 63;
  int blk = blockIdx.x;
  int b = blk >> 7;
  int n = ((blk & 127) << 6) + lane;

  const float4* src = qs4g + (size_t)b * NSMP;
  for (int t = tid; t < NSMP; t += 256) qs[t] = src[t];
  __syncthreads();

  const float* pb = pos + (size_t)b * 3 * NPT;
  float px = pb[n], py = pb[NPT + n], pz = pb[2 * NPT + n];
  float pp = fmaf(px, px, fmaf(py, py, pz * pz));

  const float INF = __builtin_inff();
  float k0 = INF, k1 = INF, k2 = INF, k3 = INF;

  int s0 = wave * SEG;

#define KNN_STEP(Q, SS)                                                   \
  {                                                                       \
    float d = fmaf(px, (Q).x, fmaf(py, (Q).y, fmaf(pz, (Q).z, (Q).w + pp))); \
    unsigned ki = (__builtin_bit_cast(unsigned, d) & 0xFFFFF800u) |       \
                  (unsigned)(SS);                                         \
    ins_med3(__builtin_bit_cast(float, ki), k0, k1, k2, k3);              \
  }

  for (int t = 0; t < SEG; t += 4) {
    int s = s0 + t;
    float4 qa = qs[s], qb = qs[s + 1], qc = qs[s + 2], qd = qs[s + 3];
    KNN_STEP(qa, s + 0)
    KNN_STEP(qb, s + 1)
    KNN_STEP(qc, s + 2)
    KNN_STEP(qd, s + 3)
  }
#undef KNN_STEP

  mk[wave][0][lane] = k0; mk[wave][1][lane] = k1;
  mk[wave][2][lane] = k2; mk[wave][3][lane] = k3;
  __syncthreads();

  if (tid < 64) {
    float K0 = INF, K1 = INF, K2 = INF, K3 = INF;
#pragma unroll
    for (int w = 0; w < 4; w++)
#pragma unroll
      for (int sl = 0; sl < 4; sl++)
        ins_med3(mk[w][sl][tid], K0, K1, K2, K3);

    int p = blk * 64 + tid;
    int I0 = (int)(__builtin_bit_cast(unsigned, K0) & 0x7FFu);
    int I1 = (int)(__builtin_bit_cast(unsigned, K1) & 0x7FFu);
    int I2 = (int)(__builtin_bit_cast(unsigned, K2) & 0x7FFu);
    float d2m = __builtin_bit_cast(float, __builtin_bit_cast(unsigned, K2) & 0xFFFFF800u);
    float d3m = __builtin_bit_cast(float, __builtin_bit_cast(unsigned, K3) & 0xFFFFF800u);
    bool flag = (d3m - d2m) < 2e-3f * fmaxf(d3m, 0.f) + 1e-5f;
    if (flag) {
      int slot = atomicAdd(flag_count, 1);
      flag_list[slot] = p;
    }
    // exact fp64 weights from chosen indices (original coords, diff form)
    const float* q = sposI + (size_t)b * 3 * NSMP;
    double pxd = (double)px, pyd = (double)py, pzd = (double)pz;
    double dd[3]; int II[3] = {I0, I1, I2};
#pragma unroll
    for (int k = 0; k < 3; k++) {
      double dx = pxd - (double)q[3 * II[k]];
      double dy = pyd - (double)q[3 * II[k] + 1];
      double dz = pzd - (double)q[3 * II[k] + 2];
      dd[k] = dx * dx + dy * dy + dz * dz;
    }
    double w0 = 1.0 / (dd[0] + 1e-8);
    double w1 = 1.0 / (dd[1] + 1e-8);
    double w2 = 1.0 / (dd[2] + 1e-8);
    double inv = 1.0 / (w0 + w1 + w2);
    size_t o = (size_t)p * 3;
    idx_out[o + 0] = I0; idx_out[o + 1] = I1; idx_out[o + 2] = I2;
    wgt_out[o + 0] = (float)(w0 * inv);
    wgt_out[o + 1] = (float)(w1 * inv);
    wgt_out[o + 2] = (float)(w2 * inv);
  }
}

// ---------------------------------------------------------------------------
// Exact fp64 fallback, wave-parallel (original coords, difference form).
// ---------------------------------------------------------------------------
__device__ __forceinline__ bool dless(double d, int i, double D, int I) {
  return d < D || (d == D && i < I);
}
__device__ __forceinline__ void dins3(double d, int i,
                                      double& b0, double& b1, double& b2,
                                      int& i0, int& i1, int& i2) {
  if (dless(d, i, b2, i2)) {
    if (dless(d, i, b1, i1)) {
      b2 = b1; i2 = i1;
      if (dless(d, i, b0, i0)) { b1 = b0; i1 = i0; b0 = d; i0 = i; }
      else                     { b1 = d; i1 = i; }
    } else { b2 = d; i2 = i; }
  }
}

__global__ __launch_bounds__(256) void knn_fallback(
    const float* __restrict__ pos, const float* __restrict__ sposI,
    const int* __restrict__ flag_list, const int* __restrict__ flag_count,
    int* __restrict__ idx_out, float* __restrict__ wgt_out) {
  int wave = threadIdx.x >> 6, lane = threadIdx.x & 63;
  int gw = blockIdx.x * 4 + wave;
  int cnt = *flag_count;
  for (int t = gw; t < cnt; t += 1024) {
    int p = flag_list[t];
    int b = p >> 13, n = p & (NPT - 1);
    const float* pb = pos + (size_t)b * 3 * NPT;
    double px = (double)pb[n], py = (double)pb[NPT + n], pz = (double)pb[2 * NPT + n];
    const float* q = sposI + (size_t)b * 3 * NSMP;
    double b0 = 1e300, b1 = 1e300, b2 = 1e300;
    int i0 = 0x7FFFFFFF, i1 = 0x7FFFFFFF, i2 = 0x7FFFFFFF;
    for (int s = lane; s < NSMP; s += 64) {
      double dx = px - (double)q[3 * s];
      double dy = py - (double)q[3 * s + 1];
      double dz = pz - (double)q[3 * s + 2];
      double d = dx * dx + dy * dy + dz * dz;
      dins3(d, s, b0, b1, b2, i0, i1, i2);
    }
#pragma unroll
    for (int m = 1; m < 64; m <<= 1) {
      double o0 = __shfl_xor(b0, m, 64), o1 = __shfl_xor(b1, m, 64), o2 = __shfl_xor(b2, m, 64);
      int    j0 = __shfl_xor(i0, m, 64), j1 = __shfl_xor(i1, m, 64), j2 = __shfl_xor(i2, m, 64);
      dins3(o0, j0, b0, b1, b2, i0, i1, i2);
      dins3(o1, j1, b0, b1, b2, i0, i1, i2);
      dins3(o2, j2, b0, b1, b2, i0, i1, i2);
    }
    if (lane == 0) {
      double w0 = 1.0 / (b0 + 1e-8);
      double w1 = 1.0 / (b1 + 1e-8);
      double w2 = 1.0 / (b2 + 1e-8);
      double inv = 1.0 / (w0 + w1 + w2);
      size_t o = (size_t)p * 3;
      idx_out[o + 0] = i0; idx_out[o + 1] = i1; idx_out[o + 2] = i2;
      wgt_out[o + 0] = (float)(w0 * inv);
      wgt_out[o + 1] = (float)(w1 * inv);
      wgt_out[o + 2] = (float)(w2 * inv);
    }
  }
}

// ---------------------------------------------------------------------------
// Interp gather -> featB columns 128..383 (bf16)
// ---------------------------------------------------------------------------
__global__ __launch_bounds__(256) void interp_kernel(
    const float* __restrict__ sfeatT,  // [B, NSMP, D2C]
    const int* __restrict__ idx,
    const float* __restrict__ wgt,
    unsigned short* __restrict__ featB) {
  int p = blockIdx.x;
  int c = threadIdx.x;
  int b = p >> 13;
  size_t o = (size_t)p * 3;
  int i0 = idx[o], i1 = idx[o + 1], i2 = idx[o + 2];
  float w0 = wgt[o], w1 = wgt[o + 1], w2 = wgt[o + 2];
  const float* base = sfeatT + (size_t)b * NSMP * D2C;
  float v = w0 * base[(size_t)i0 * D2C + c]
          + w1 * base[(size_t)i1 * D2C + c]
          + w2 * base[(size_t)i2 * D2C + c];
  featB[(size_t)p * CIN + D1C + c] = f2bf(v);
}

// ---------------------------------------------------------------------------
// GEMM1, single-wave blocks: Y1 = featB @ W1^T + b1, 128x64 tile/wave.
// Partial (sum,sumsq) per [col][rowblock]; no atomics.
// grid (NRB, C1/WN) = (512, 4), block 64.
// ---------------------------------------------------------------------------
__global__ __launch_bounds__(64) void gemm1_wave(
    const unsigned short* __restrict__ featB,  // [BN_TOTAL][CIN] bf16
    const unsigned short* __restrict__ W1h,    // [C1][CIN] bf16
    const float* __restrict__ bias,
    unsigned short* __restrict__ Y1,           // [BN_TOTAL][C1] bf16
    float* __restrict__ part_s,                // [C1][NRB]
    float* __restrict__ part_q) {
  __shared__ __align__(16) unsigned short As[WM * WK];  // 8 KB
  __shared__ __align__(16) unsigned short Bs[WN * WK];  // 4 KB
  int lane = threadIdx.x;
  int m16 = lane & 15, quad = lane >> 4;
  int rb = blockIdx.x, cb = blockIdx.y;
  int row0 = rb * WM, col0 = cb * WN;
  int row16 = lane >> 2, col8 = (lane & 3) * 8;

  f32x4 acc[8][4];
#pragma unroll
  for (int j = 0; j < 4; j++) {
    float bj = bias[col0 + j * 16 + m16];
#pragma unroll
    for (int i = 0; i < 8; i++) acc[i][j] = f32x4{bj, bj, bj, bj};
  }

  for (int k0 = 0; k0 < CIN; k0 += WK) {
#pragma unroll
    for (int c = 0; c < 8; c++)
      gld_lds16(&featB[(size_t)(row0 + c * 16 + row16) * CIN + k0 + col8],
                &As[c * 16 * WK]);
#pragma unroll
    for (int c = 0; c < 4; c++)
      gld_lds16(&W1h[(size_t)(col0 + c * 16 + row16) * CIN + k0 + col8],
                &Bs[c * 16 * WK]);
    __syncthreads();  // 1-wave block: local waitcnt, no cross-wave drain

    bf16x8 a[8], bf[4];
#pragma unroll
    for (int i = 0; i < 8; i++)
      a[i] = __builtin_bit_cast(bf16x8, *(const s16x8*)&As[(i * 16 + m16) * WK + quad * 8]);
#pragma unroll
    for (int j = 0; j < 4; j++)
      bf[j] = __builtin_bit_cast(bf16x8, *(const s16x8*)&Bs[(j * 16 + m16) * WK + quad * 8]);
#pragma unroll
    for (int i = 0; i < 8; i++)
#pragma unroll
      for (int j = 0; j < 4; j++)
        acc[i][j] = __builtin_amdgcn_mfma_f32_16x16x32_bf16(a[i], bf[j], acc[i][j], 0, 0, 0);
    __syncthreads();
  }

#pragma unroll
  for (int j = 0; j < 4; j++) {
    int col = col0 + j * 16 + m16;
    float s = 0.f, q = 0.f;
#pragma unroll
    for (int i = 0; i < 8; i++)
#pragma unroll
      for (int r = 0; r < 4; r++) {
        float v = acc[i][j][r];
        Y1[(size_t)(row0 + i * 16 + quad * 4 + r) * C1 + col] = f2bf(v);
        s += v; q = fmaf(v, v, q);
      }
    s += __shfl_xor(s, 16, 64); s += __shfl_xor(s, 32, 64);
    q += __shfl_xor(q, 16, 64); q += __shfl_xor(q, 32, 64);
    if (quad == 0) {
      part_s[(size_t)col * NRB + rb] = s;
      part_q[(size_t)col * NRB + rb] = q;
    }
  }
}

// ---------------------------------------------------------------------------
// GEMM2, single-wave blocks: X2 = relu(bn1(Y1)) fused in A staging (VALU),
// B via global_load_lds. 128x64 tile/wave. grid (NRB, C2/WN) = (512, 2).
// ---------------------------------------------------------------------------
__global__ __launch_bounds__(64) void gemm2_wave(
    const unsigned short* __restrict__ Y1,   // [BN_TOTAL][C1] bf16
    const float* __restrict__ scale1, const float* __restrict__ shift1,
    const unsigned short* __restrict__ W2h,  // [C2][C1] bf16
    const float* __restrict__ bias,
    unsigned short* __restrict__ Y2,         // [BN_TOTAL][C2] bf16
    float* __restrict__ part_s,              // [C2][NRB]
    float* __restrict__ part_q) {
  __shared__ __align__(16) unsigned short As[WM * WK];
  __shared__ __align__(16) unsigned short Bs[WN * WK];
  __shared__ float scs[C1], shs[C1];
  int lane = threadIdx.x;
  int m16 = lane & 15, quad = lane >> 4;
  int rb = blockIdx.x, cb = blockIdx.y;
  int row0 = rb * WM, col0 = cb * WN;
  int row16 = lane >> 2, col8 = (lane & 3) * 8;

  for (int t = lane; t < C1; t += 64) { scs[t] = scale1[t]; shs[t] = shift1[t]; }

  f32x4 acc[8][4];
#pragma unroll
  for (int j = 0; j < 4; j++) {
    float bj = bias[col0 + j * 16 + m16];
#pragma unroll
    for (int i = 0; i < 8; i++) acc[i][j] = f32x4{bj, bj, bj, bj};
  }
  __syncthreads();  // scs/shs visible (single wave: cheap)

  for (int k0 = 0; k0 < C1; k0 += WK) {
#pragma unroll
    for (int c = 0; c < 4; c++)
      gld_lds16(&W2h[(size_t)(col0 + c * 16 + row16) * C1 + k0 + col8],
                &Bs[c * 16 * WK]);
    // A tile: load Y1, apply BN1+ReLU, write LDS
#pragma unroll
    for (int c = 0; c < 8; c++) {
      int row = c * 16 + row16;
      s16x8 v = *(const s16x8*)&Y1[(size_t)(row0 + row) * C1 + k0 + col8];
      unsigned short ov[8];
#pragma unroll
      for (int e = 0; e < 8; e++) {
        float x = bf2f((unsigned short)v[e]);
        float y = fmaxf(fmaf(x, scs[k0 + col8 + e], shs[k0 + col8 + e]), 0.f);
        ov[e] = f2bf(y);
      }
      *(s16x8*)&As[row * WK + col8] = *(const s16x8*)ov;
    }
    __syncthreads();

    bf16x8 a[8], bf[4];
#pragma unroll
    for (int i = 0; i < 8; i++)
      a[i] = __builtin_bit_cast(bf16x8, *(const s16x8*)&As[(i * 16 + m16) * WK + quad * 8]);
#pragma unroll
    for (int j = 0; j < 4; j++)
      bf[j] = __builtin_bit_cast(bf16x8, *(const s16x8*)&Bs[(j * 16 + m16) * WK + quad * 8]);
#pragma unroll
    for (int i = 0; i < 8; i++)
#pragma unroll
      for (int j = 0; j < 4; j++)
        acc[i][j] = __builtin_amdgcn_mfma_f32_16x16x32_bf16(a[i], bf[j], acc[i][j], 0, 0, 0);
    __syncthreads();
  }

#pragma unroll
  for (int j = 0; j < 4; j++) {
    int col = col0 + j * 16 + m16;
    float s = 0.f, q = 0.f;
#pragma unroll
    for (int i = 0; i < 8; i++)
#pragma unroll
      for (int r = 0; r < 4; r++) {
        float v = acc[i][j][r];
        Y2[(size_t)(row0 + i * 16 + quad * 4 + r) * C2 + col] = f2bf(v);
        s += v; q = fmaf(v, v, q);
      }
    s += __shfl_xor(s, 16, 64); s += __shfl_xor(s, 32, 64);
    q += __shfl_xor(q, 16, 64); q += __shfl_xor(q, 32, 64);
    if (quad == 0) {
      part_s[(size_t)col * NRB + rb] = s;
      part_q[(size_t)col * NRB + rb] = q;
    }
  }
}

// ---------------------------------------------------------------------------
// Reduce partials [C][NRB] + compute BN scale/shift. grid = C, block = 256.
// ---------------------------------------------------------------------------
__global__ __launch_bounds__(256) void bn_reduce_coef(
    const float* __restrict__ part_s, const float* __restrict__ part_q, int nrb,
    const float* __restrict__ g, const float* __restrict__ beta,
    float* __restrict__ scale, float* __restrict__ shift) {
  int ch = blockIdx.x;
  int tid = threadIdx.x;
  float s = 0.f, q = 0.f;
  for (int t = tid; t < nrb; t += 256) {
    s += part_s[(size_t)ch * nrb + t];
    q += part_q[(size_t)ch * nrb + t];
  }
#pragma unroll
  for (int m = 1; m < 64; m <<= 1) {
    s += __shfl_xor(s, m, 64);
    q += __shfl_xor(q, m, 64);
  }
  __shared__ float ls[4], lq[4];
  int wave = tid >> 6;
  if ((tid & 63) == 0) { ls[wave] = s; lq[wave] = q; }
  __syncthreads();
  if (tid == 0) {
    s = ls[0] + ls[1] + ls[2] + ls[3];
    q = lq[0] + lq[1] + lq[2] + lq[3];
    const float invBN = 1.0f / (float)BN_TOTAL;
    float mean = s * invBN;
    float var = q * invBN - mean * mean;
    float sc = g[ch] / sqrtf(var + 1e-5f);
    scale[ch] = sc;
    shift[ch] = beta[ch] - mean * sc;
  }
}

// ---------------------------------------------------------------------------
// Final: out[b][c][n] = relu(bn2(Y2)) transposed, fp32 out.
// ---------------------------------------------------------------------------
__global__ void final_kernel(const unsigned short* __restrict__ Y2,
                             const float* __restrict__ scale, const float* __restrict__ shift,
                             float* __restrict__ out) {
  __shared__ float tile[32][33];
  int b = blockIdx.z;
  int n0 = blockIdx.x * 32;
  int c0 = blockIdx.y * 32;
  int tx = threadIdx.x, ty = threadIdx.y;
  float sc = scale[c0 + tx];
  float sh = shift[c0 + tx];
#pragma unroll
  for (int i = 0; i < 32; i += 8) {
    int n = n0 + ty + i;
    float v = bf2f(Y2[((size_t)b * NPT + n) * C2 + c0 + tx]);
    tile[ty + i][tx] = fmaxf(fmaf(v, sc, sh), 0.f);
  }
  __syncthreads();
#pragma unroll
  for (int i = 0; i < 32; i += 8) {
    int c = c0 + ty + i;
    out[((size_t)b * C2 + c) * NPT + n0 + tx] = tile[tx][ty + i];
  }
}

// ---------------------------------------------------------------------------
extern "C" void kernel_launch(void* const* d_in, const int* in_sizes, int n_in,
                              void* d_out, int out_size, void* d_ws, size_t ws_size,
                              hipStream_t stream) {
  (void)in_sizes; (void)n_in; (void)out_size; (void)ws_size;
  const float* pos   = (const float*)d_in[0];
  const float* spos  = (const float*)d_in[1];
  const float* skip  = (const float*)d_in[2];
  const float* sfeat = (const float*)d_in[3];
  const float* W1    = (const float*)d_in[4];
  const float* b1    = (const float*)d_in[5];
  const float* g1    = (const float*)d_in[6];
  const float* beta1 = (const float*)d_in[7];
  const float* W2    = (const float*)d_in[8];
  const float* b2    = (const float*)d_in[9];
  const float* g2    = (const float*)d_in[10];
  const float* beta2 = (const float*)d_in[11];
  float* out = (float*)d_out;

  float* ws = (float*)d_ws;
  size_t off = 0;
  float* sfeatT  = ws + off; off += (size_t)BATCH * NSMP * D2C;
  unsigned short* featB = (unsigned short*)(ws + off); off += (size_t)BN_TOTAL * CIN / 2;
  unsigned short* Y1    = (unsigned short*)(ws + off); off += (size_t)BN_TOTAL * C1 / 2;
  unsigned short* Y2    = (unsigned short*)(ws + off); off += (size_t)BN_TOTAL * C2 / 2;
  unsigned short* W1h   = (unsigned short*)(ws + off); off += (size_t)C1 * CIN / 2;
  unsigned short* W2h   = (unsigned short*)(ws + off); off += (size_t)C2 * C1 / 2;
  int*   knn_idx = (int*)(ws + off); off += (size_t)BN_TOTAL * 3;
  float* knn_w   = ws + off; off += (size_t)BN_TOTAL * 3;
  float* sposI   = ws + off; off += (size_t)BATCH * NSMP * 3;
  float4* qs4    = (float4*)(ws + off); off += (size_t)BATCH * NSMP * 4;
  int* flag_list = (int*)(ws + off); off += (size_t)BN_TOTAL;
  float* part1_s = ws + off; off += (size_t)C1 * NRB;
  float* part1_q = ws + off; off += (size_t)C1 * NRB;
  float* part2_s = ws + off; off += (size_t)C2 * NRB;
  float* part2_q = ws + off; off += (size_t)C2 * NRB;
  float* stats   = ws + off; off += 2048;
  int*   flag_count = (int*)stats;
  float* scale1 = stats + 256, *shift1 = stats + 512;
  float* scale2 = stats + 768, *shift2 = stats + 1024;

  hipMemsetAsync(flag_count, 0, sizeof(int), stream);

  dim3 tb(32, 8);
  transpose_k<<<dim3(NSMP / 32, D2C / 32, BATCH), tb, 0, stream>>>(
      sfeat, sfeatT, D2C, NSMP, (long)D2C * NSMP, (long)NSMP * D2C);
  wprep<<<(C1 * CIN + 255) / 256, 256, 0, stream>>>(W1, W1h, C1 * CIN);
  wprep<<<(C2 * C1 + 255) / 256, 256, 0, stream>>>(W2, W2h, C2 * C1);
  skip_to_featB<<<dim3(NPT / 32, D1C / 32, BATCH), tb, 0, stream>>>(skip, featB);

  pack_spos<<<BATCH * NSMP / 256, 256, 0, stream>>>(spos, sposI, qs4);
  knn_kernel<<<BN_TOTAL / 64, 256, 0, stream>>>(pos, qs4, sposI, knn_idx, knn_w,
                                                flag_list, flag_count);
  knn_fallback<<<256, 256, 0, stream>>>(pos, sposI, flag_list, flag_count,
                                        knn_idx, knn_w);
  interp_kernel<<<BN_TOTAL, 256, 0, stream>>>(sfeatT, knn_idx, knn_w, featB);

  gemm1_wave<<<dim3(NRB, C1 / WN), 64, 0, stream>>>(
      featB, W1h, b1, Y1, part1_s, part1_q);
  bn_reduce_coef<<<C1, 256, 0, stream>>>(part1_s, part1_q, NRB, g1, beta1, scale1, shift1);

  gemm2_wave<<<dim3(NRB, C2 / WN), 64, 0, stream>>>(
      Y1, scale1, shift1, W2h, b2, Y2, part2_s, part2_q);
  bn_reduce_coef<<<C2, 256, 0, stream>>>(part2_s, part2_q, NRB, g2, beta2, scale2, shift2);

  final_kernel<<<dim3(NPT / 32, C2 / 32, BATCH), tb, 0, stream>>>(Y2, scale2, shift2, out);
}